// Round 3
// baseline (5927.356 us; speedup 1.0000x reference)
//
#include <hip/hip_runtime.h>
#include <hip/hip_bf16.h>
#include <type_traits>

typedef __hip_bfloat16 bf16;

constexpr int N_  = 250000;
constexpr int E_  = 500000;
constexpr int B_  = 10000;
constexpr int H_  = 128;

__device__ __forceinline__ float b2f(bf16 v){ return __bfloat162float(v); }
__device__ __forceinline__ bf16  f2b(float v){ return __float2bfloat16(v); }
__device__ __forceinline__ float to_float(float v){ return v; }
__device__ __forceinline__ float to_float(bf16 v){ return __bfloat162float(v); }
__device__ __forceinline__ float lrelu_f(float v){ return v > 0.f ? v : 0.01f*v; }
__device__ __forceinline__ float elu_f(float v){ return v > 0.f ? v : expm1f(v); }
__device__ __forceinline__ float dot4(float4 a, float4 b){ return a.x*b.x+a.y*b.y+a.z*b.z+a.w*b.w; }
__device__ __forceinline__ unsigned f2b_bits(float f){
  bf16 h=__float2bfloat16(f); unsigned short s; __builtin_memcpy(&s,&h,2); return (unsigned)s;
}
// unpack 8 bf16 (as uint4) -> 8 fp32
__device__ __forceinline__ void unp8(uint4 v, float* o){
  o[0]=__uint_as_float(v.x<<16); o[1]=__uint_as_float(v.x&0xffff0000u);
  o[2]=__uint_as_float(v.y<<16); o[3]=__uint_as_float(v.y&0xffff0000u);
  o[4]=__uint_as_float(v.z<<16); o[5]=__uint_as_float(v.z&0xffff0000u);
  o[6]=__uint_as_float(v.w<<16); o[7]=__uint_as_float(v.w&0xffff0000u);
}

// ---------------- lin1: [N,39] fp32 -> [N,128] bf16, lrelu ----------------
__global__ __launch_bounds__(256) void lin1_k(const float* __restrict__ X0, const float* __restrict__ W,
                       const float* __restrict__ b, bf16* __restrict__ Y, int M){
  __shared__ float sW[128*41];
  __shared__ float sb[128];
  __shared__ float sx[2][41];
  for (int i = threadIdx.x; i < 128*39; i += 256){ int c=i/39, k=i-c*39; sW[c*41+k]=W[i]; }
  if (threadIdx.x < 128) sb[threadIdx.x]=b[threadIdx.x];
  __syncthreads();
  int sub = threadIdx.x>>7, c = threadIdx.x&127;
  for (long r0=(long)blockIdx.x*2; r0<M; r0+=(long)gridDim.x*2){
    __syncthreads();
    for (int i=threadIdx.x;i<2*39;i+=256){ int rr=i/39,k=i-rr*39; long row=r0+rr;
      sx[rr][k]= row<M? X0[row*39+k]:0.f; }
    __syncthreads();
    long row=r0+sub;
    if (row<M){
      float acc=sb[c];
      #pragma unroll
      for (int k=0;k<39;k++) acc += sx[sub][k]*sW[c*41+k];
      Y[row*128+c]=f2b(lrelu_f(acc));
    }
  }
}

// ------- generic linear (K=128): Y[row,c0+c]=act(X[row,:].W[c0+c,:]+bias) ----
template<int ACT>   // 0 none, 2 elu
__global__ __launch_bounds__(256) void lin_single_k(const bf16* __restrict__ X, const float* __restrict__ W, int ldw,
                             const float* __restrict__ bias, bf16* __restrict__ Y, int M){
  __shared__ float sW[64*132];
  __shared__ float sx[4][132];
  __shared__ float sb[64];
  int c0 = blockIdx.y*64;
  for (int i=threadIdx.x; i<64*128; i+=256){ int c=i>>7, k=i&127;
    sW[c*132+k] = W[(size_t)(c0+c)*ldw + k]; }
  if (threadIdx.x<64) sb[threadIdx.x] = bias? bias[c0+threadIdx.x] : 0.f;
  __syncthreads();
  int sub=threadIdx.x>>6, c=threadIdx.x&63;
  for (long r0=(long)blockIdx.x*4; r0<M; r0+=(long)gridDim.x*4){
    __syncthreads();
    for (int i=threadIdx.x;i<4*16;i+=256){ int rr=i>>4,q=i&15; long row=r0+rr;
      uint4 v = row<M? *(const uint4*)(X+row*128+q*8) : make_uint4(0,0,0,0);
      unp8(v,&sx[rr][q*8]); }
    __syncthreads();
    long row=r0+sub;
    if (row<M){
      float acc=sb[c];
      const float4* wr=(const float4*)&sW[c*132];
      const float4* xr=(const float4*)sx[sub];
      #pragma unroll
      for (int k4=0;k4<32;k4++) acc += dot4(wr[k4], xr[k4]);
      float v=acc;
      if (ACT==2) v=elu_f(v);
      Y[row*128+c0+c]=f2b(v);
    }
  }
}

// ------- fully fused GRU: dest = relu((1-z)*n + z*x), 6 dots per (row,col) ----
template<typename T>
__global__ __launch_bounds__(256) void gru_fused_k(const T* __restrict__ A, const T* __restrict__ X,
                            const float* __restrict__ Wih, const float* __restrict__ Whh,
                            const float* __restrict__ bih, const float* __restrict__ bhh,
                            T* __restrict__ dest, int M){
  __shared__ unsigned sW[6][32*66];   // bf16 pairs; [0..2]=ih r,z,n  [3..5]=hh r,z,n
  __shared__ float sA[8][132], sX[8][132];
  __shared__ float sbi[3][32], sbh[3][32];
  int c0 = blockIdx.y*32;
  for (int i=threadIdx.x; i<6*32*64; i+=256){
    int m=i>>11, r=i&2047, c=r>>6, k2=r&63;
    const float* base = (m<3)? Wih : Whh;
    int g = (m<3)? m : m-3;
    const float* wp = base + ((size_t)(g*128 + c0 + c))*128 + 2*k2;
    sW[m][c*66 + k2] = f2b_bits(wp[0]) | (f2b_bits(wp[1])<<16);
  }
  if (threadIdx.x < 96){
    int g=threadIdx.x>>5, c=threadIdx.x&31;
    sbi[g][c]=bih[g*128+c0+c]; sbh[g][c]=bhh[g*128+c0+c];
  }
  __syncthreads();
  int sub=threadIdx.x>>5, c=threadIdx.x&31;
  for (long r0=(long)blockIdx.x*8; r0<M; r0+=(long)gridDim.x*8){
    __syncthreads();
    for (int i=threadIdx.x;i<8*16;i+=256){
      int rr=i>>4, q=i&15; long row=r0+rr;
      if constexpr (std::is_same<T,bf16>::value){
        uint4 va = row<M? *(const uint4*)(A+row*128+q*8) : make_uint4(0,0,0,0);
        uint4 vx = row<M? *(const uint4*)(X+row*128+q*8) : make_uint4(0,0,0,0);
        unp8(va,&sA[rr][q*8]); unp8(vx,&sX[rr][q*8]);
      } else {
        if (row<M){
          *(float4*)&sA[rr][q*8]   = *(const float4*)(A+row*128+q*8);
          *(float4*)&sA[rr][q*8+4] = *(const float4*)(A+row*128+q*8+4);
          *(float4*)&sX[rr][q*8]   = *(const float4*)(X+row*128+q*8);
          *(float4*)&sX[rr][q*8+4] = *(const float4*)(X+row*128+q*8+4);
        } else {
          float4 z=make_float4(0,0,0,0);
          *(float4*)&sA[rr][q*8]=z; *(float4*)&sA[rr][q*8+4]=z;
          *(float4*)&sX[rr][q*8]=z; *(float4*)&sX[rr][q*8+4]=z;
        }
      }
    }
    __syncthreads();
    long row=r0+sub;
    if (row<M){
      const unsigned* wri=&sW[0][c*66]; const unsigned* wzi=&sW[1][c*66]; const unsigned* wni=&sW[2][c*66];
      const unsigned* wrh=&sW[3][c*66]; const unsigned* wzh=&sW[4][c*66]; const unsigned* wnh=&sW[5][c*66];
      const float2* xa=(const float2*)sA[sub]; const float2* xb=(const float2*)sX[sub];
      float ari=0,azi=0,ani=0,arh=0,azh=0,anh=0;
      #pragma unroll 8
      for (int k2=0;k2<64;k2++){
        float2 av=xa[k2], bv=xb[k2];
        unsigned u;
        u=wri[k2]; ari += av.x*__uint_as_float(u<<16) + av.y*__uint_as_float(u&0xffff0000u);
        u=wzi[k2]; azi += av.x*__uint_as_float(u<<16) + av.y*__uint_as_float(u&0xffff0000u);
        u=wni[k2]; ani += av.x*__uint_as_float(u<<16) + av.y*__uint_as_float(u&0xffff0000u);
        u=wrh[k2]; arh += bv.x*__uint_as_float(u<<16) + bv.y*__uint_as_float(u&0xffff0000u);
        u=wzh[k2]; azh += bv.x*__uint_as_float(u<<16) + bv.y*__uint_as_float(u&0xffff0000u);
        u=wnh[k2]; anh += bv.x*__uint_as_float(u<<16) + bv.y*__uint_as_float(u&0xffff0000u);
      }
      float rg = 1.f/(1.f+expf(-(ari+arh+sbi[0][c]+sbh[0][c])));
      float zg = 1.f/(1.f+expf(-(azi+azh+sbi[1][c]+sbh[1][c])));
      float nn = tanhf(ani+sbi[2][c] + rg*(anh+sbh[2][c]));
      float xv = sX[sub][c0+c];
      float o  = (1.f-zg)*nn + zg*xv;
      float res = fmaxf(o,0.f);
      if constexpr (std::is_same<T,bf16>::value) dest[row*128+c0+c] = f2b(res);
      else dest[row*128+c0+c] = res;
    }
  }
}

// ---------------- row dot: d[row] = Y[row,:] . v ----------------
template<typename TY>
__global__ void rowdot_k(const TY* __restrict__ Y, const float* __restrict__ v,
                         float* __restrict__ d, int M){
  __shared__ float sv[128];
  if (threadIdx.x<128) sv[threadIdx.x]=v[threadIdx.x];
  __syncthreads();
  int wv=threadIdx.x>>6, lane=threadIdx.x&63;
  long row=(long)blockIdx.x*4+wv;
  if (row>=M) return;
  float a=to_float(Y[row*128+lane])*sv[lane]+to_float(Y[row*128+64+lane])*sv[64+lane];
  #pragma unroll
  for (int o=32;o;o>>=1) a+=__shfl_xor(a,o);
  if (!lane) d[row]=a;
}

// ---------------- GATE edge logits ----------------
__global__ __launch_bounds__(256) void gate_edge_logits_k(const bf16* __restrict__ u, const float* __restrict__ ea,
                                   const float* __restrict__ gW1, const float* __restrict__ att_l,
                                   const float* __restrict__ ddst, const int* __restrict__ src,
                                   const int* __restrict__ dst, float* __restrict__ elog, int E){
  __shared__ float sWb[10][128];
  __shared__ float sal[128];
  for (int i=threadIdx.x;i<10*128;i+=256){ int k=i>>7,c=i&127; sWb[k][c]=gW1[(size_t)c*138+128+k]; }
  if (threadIdx.x<128) sal[threadIdx.x]=att_l[threadIdx.x];
  __syncthreads();
  int wv=threadIdx.x>>6, lane=threadIdx.x&63;
  for (long e=(long)blockIdx.x*4+wv; e<E; e+=(long)gridDim.x*4){
    int sj=src[e], di=dst[e];
    float eal[10];
    #pragma unroll
    for (int k=0;k<10;k++) eal[k]=ea[(size_t)e*10+k];
    float acc=0.f;
    #pragma unroll
    for (int j=0;j<2;j++){
      int cc=lane+64*j;
      float v=0.f;
      #pragma unroll
      for (int k=0;k<10;k++) v+=eal[k]*sWb[k][cc];
      v+=b2f(u[(size_t)sj*128+cc]);
      acc+=lrelu_f(v)*sal[cc];
    }
    #pragma unroll
    for (int o=32;o;o>>=1) acc+=__shfl_xor(acc,o);
    if (!lane) elog[e]=lrelu_f(acc+ddst[di]);
  }
}

// ---------------- conv edge logits ----------------
__global__ void conv_logit_k(const float* __restrict__ dsrc, const float* __restrict__ ddst,
                             const int* __restrict__ src, const int* __restrict__ dst,
                             float* __restrict__ elog, int n){
  int e=blockIdx.x*256+threadIdx.x; if (e<n) elog[e]=lrelu_f(dsrc[src[e]]+ddst[dst[e]]);
}

// ------- per-node softmax over incoming edges + weighted sum of V[src] -------
__global__ void node_gather_k(const float* __restrict__ elog, const int* __restrict__ eids,
                              const int* __restrict__ ptr, const int* __restrict__ src,
                              const bf16* __restrict__ V, bf16* __restrict__ S, int M){
  int wv=threadIdx.x>>6, lane=threadIdx.x&63;
  int node=blockIdx.x*4+wv; if (node>=M) return;
  int p0=ptr[node], p1=ptr[node+1];
  float m=-INFINITY;
  for (int p=p0+lane;p<p1;p+=64) m=fmaxf(m,elog[eids[p]]);
  #pragma unroll
  for (int o=32;o;o>>=1) m=fmaxf(m,__shfl_xor(m,o));
  float ssum=0.f;
  for (int p=p0+lane;p<p1;p+=64) ssum+=expf(elog[eids[p]]-m);
  #pragma unroll
  for (int o=32;o;o>>=1) ssum+=__shfl_xor(ssum,o);
  float inv=1.f/(ssum+1e-16f);
  float a0=0.f,a1=0.f;
  for (int p=p0;p<p1;p++){
    int e=eids[p];
    float al=expf(elog[e]-m)*inv;
    const bf16* vr=&V[(size_t)src[e]*128];
    a0+=al*b2f(vr[lane]); a1+=al*b2f(vr[64+lane]);
  }
  S[(size_t)node*128+lane]=f2b(a0); S[(size_t)node*128+64+lane]=f2b(a1);
}

// ---------------- elementwise h = relu(s + bias) (in place) ----------------
__global__ void bias_relu_k(bf16* __restrict__ X, const float* __restrict__ b, long n){
  long i=(long)blockIdx.x*256+threadIdx.x;
  if (i<n){ float v=b2f(X[i])+b[i&127]; X[i]=f2b(fmaxf(v,0.f)); }
}

// ---------------- molecule kernels ----------------
__global__ void mol_ptr_k(const int* __restrict__ batch, int* __restrict__ mptr, int n, int Bn){
  int b=blockIdx.x*256+threadIdx.x; if (b>Bn) return;
  if (b==Bn){ mptr[Bn]=n; return; }
  int lo=0, hi=n;
  while (lo<hi){ int mid=(lo+hi)>>1; if (batch[mid]<b) lo=mid+1; else hi=mid; }
  mptr[b]=lo;
}

__global__ void mol_sum_k(const bf16* __restrict__ x, const int* __restrict__ mptr,
                          float* __restrict__ out, int Bn){
  int wv=threadIdx.x>>6, lane=threadIdx.x&63;
  int b=blockIdx.x*4+wv; if (b>=Bn) return;
  int p0=mptr[b], p1=mptr[b+1];
  float a0=0.f,a1=0.f;
  for (int i=p0;i<p1;i++){ a0+=b2f(x[(size_t)i*128+lane]); a1+=b2f(x[(size_t)i*128+64+lane]); }
  out[(size_t)b*128+lane]=fmaxf(a0,0.f); out[(size_t)b*128+64+lane]=fmaxf(a1,0.f);
}

__global__ void fold_att_k(const float* __restrict__ W, const float* __restrict__ att,
                           float* __restrict__ wdd){
  int k=threadIdx.x; float a=0.f;
  for (int c=0;c<128;c++) a+=att[c]*W[(size_t)c*128+k];
  wdd[k]=a;
}

__global__ void mol_logit_k(const float* __restrict__ dsrc, const float* __restrict__ dd,
                            const int* __restrict__ batch, float* __restrict__ alog, int n){
  int i=blockIdx.x*256+threadIdx.x; if (i<n) alog[i]=lrelu_f(dsrc[i]+dd[batch[i]]);
}

__global__ void mol_gather_k(const float* __restrict__ alog, const int* __restrict__ mptr,
                             const bf16* __restrict__ xs, const float* __restrict__ bias,
                             float* __restrict__ hb, int Bn){
  int wv=threadIdx.x>>6, lane=threadIdx.x&63;
  int b=blockIdx.x*4+wv; if (b>=Bn) return;
  int p0=mptr[b], p1=mptr[b+1];
  float m=-INFINITY;
  for (int i=p0+lane;i<p1;i+=64) m=fmaxf(m,alog[i]);
  #pragma unroll
  for (int o=32;o;o>>=1) m=fmaxf(m,__shfl_xor(m,o));
  float ssum=0.f;
  for (int i=p0+lane;i<p1;i+=64) ssum+=expf(alog[i]-m);
  #pragma unroll
  for (int o=32;o;o>>=1) ssum+=__shfl_xor(ssum,o);
  float inv=1.f/(ssum+1e-16f);
  float a0=0.f,a1=0.f;
  for (int i=p0;i<p1;i++){
    float al=expf(alog[i]-m)*inv;
    a0+=al*b2f(xs[(size_t)i*128+lane]); a1+=al*b2f(xs[(size_t)i*128+64+lane]);
  }
  hb[(size_t)b*128+lane]=elu_f(a0+bias[lane]);
  hb[(size_t)b*128+64+lane]=elu_f(a1+bias[64+lane]);
}

// ---------------- final head ----------------
__global__ void final_head_k(const float* __restrict__ out, const float* __restrict__ W2,
                             const float* __restrict__ b2, const float* __restrict__ Wh,
                             const float* __restrict__ bh, float* __restrict__ y, int Bn){
  __shared__ float srow[128]; __shared__ float sred[128];
  int b=blockIdx.x, c=threadIdx.x;
  srow[c]=out[(size_t)b*128+c]; __syncthreads();
  float acc=b2[c];
  const float* wr=&W2[(size_t)c*128];
  #pragma unroll 8
  for (int k=0;k<128;k++) acc+=srow[k]*wr[k];
  sred[c]=acc*Wh[c]; __syncthreads();
  for (int o=64;o;o>>=1){ if (c<o) sred[c]+=sred[c+o]; __syncthreads(); }
  if (c==0) y[b]=sred[0]+bh[0];
}

// ---------------- CSR build ----------------
__global__ void zero_i32_k(int* p, int n){ int i=blockIdx.x*256+threadIdx.x; if (i<n) p[i]=0; }
__global__ void hist_k(const int* __restrict__ dst, int* __restrict__ deg, int n){
  int e=blockIdx.x*256+threadIdx.x; if (e<n) atomicAdd(&deg[dst[e]],1);
}
__global__ void scan1_k(const int* __restrict__ deg, int* __restrict__ ptr,
                        int* __restrict__ part, int n){
  __shared__ int sd[256];
  int base=blockIdx.x*1024, tid=threadIdx.x;
  int v[4]; int ssum=0;
  #pragma unroll
  for (int j=0;j<4;j++){ int idx=base+tid*4+j; v[j]= idx<n? deg[idx]:0; ssum+=v[j]; }
  sd[tid]=ssum; __syncthreads();
  for (int o=1;o<256;o<<=1){ int t = tid>=o? sd[tid-o]:0; __syncthreads(); sd[tid]+=t; __syncthreads(); }
  int excl=sd[tid]-ssum;
  #pragma unroll
  for (int j=0;j<4;j++){ int idx=base+tid*4+j; if (idx<n) ptr[idx]=excl; excl+=v[j]; }
  if (tid==255) part[blockIdx.x]=sd[255];
}
__global__ void scan2_k(int* part, int nb){
  __shared__ int sd[512];
  int tid=threadIdx.x;
  int v= tid<nb? part[tid]:0; sd[tid]=v; __syncthreads();
  for (int o=1;o<512;o<<=1){ int t = tid>=o? sd[tid-o]:0; __syncthreads(); sd[tid]+=t; __syncthreads(); }
  if (tid<nb) part[tid]=sd[tid]-v;
}
__global__ void scan3_k(int* __restrict__ ptr, const int* __restrict__ part,
                        int* __restrict__ wofs, int n, int total){
  int i=blockIdx.x*256+threadIdx.x;
  if (i<n){ int val=ptr[i]+part[i>>10]; ptr[i]=val; wofs[i]=val; }
  if (i==0) ptr[n]=total;
}
__global__ void fill_csr_k(const int* __restrict__ dst, int* __restrict__ wofs,
                           int* __restrict__ eids, int n){
  int e=blockIdx.x*256+threadIdx.x;
  if (e<n){ int p=atomicAdd(&wofs[dst[e]],1); eids[p]=e; }
}

// =====================================================================
extern "C" void kernel_launch(void* const* d_in, const int* in_sizes, int n_in,
                              void* d_out, int out_size, void* d_ws, size_t ws_size,
                              hipStream_t stream){
  (void)in_sizes; (void)n_in; (void)out_size; (void)ws_size;
  const float* x0        =(const float*)d_in[0];
  const float* edge_attr =(const float*)d_in[1];
  const float* W_lin1    =(const float*)d_in[2];
  const float* b_lin1    =(const float*)d_in[3];
  const float* gate_W1   =(const float*)d_in[4];
  const float* gate_W2   =(const float*)d_in[5];
  const float* gate_att_l=(const float*)d_in[6];
  const float* gate_att_r=(const float*)d_in[7];
  const float* gate_bias =(const float*)d_in[8];
  const float* g1_Wih=(const float*)d_in[9];  const float* g1_Whh=(const float*)d_in[10];
  const float* g1_bih=(const float*)d_in[11]; const float* g1_bhh=(const float*)d_in[12];
  const float* conv_W=(const float*)d_in[13];
  const float* conv_att_src=(const float*)d_in[14];
  const float* conv_att_dst=(const float*)d_in[15];
  const float* conv_bias   =(const float*)d_in[16];
  const float* g2_Wih=(const float*)d_in[17]; const float* g2_Whh=(const float*)d_in[18];
  const float* g2_bih=(const float*)d_in[19]; const float* g2_bhh=(const float*)d_in[20];
  const float* mol_W=(const float*)d_in[21];
  const float* mol_att_src=(const float*)d_in[22];
  const float* mol_att_dst=(const float*)d_in[23];
  const float* mol_bias   =(const float*)d_in[24];
  const float* gm_Wih=(const float*)d_in[25]; const float* gm_Whh=(const float*)d_in[26];
  const float* gm_bih=(const float*)d_in[27]; const float* gm_bhh=(const float*)d_in[28];
  const float* W_lin2=(const float*)d_in[29]; const float* b_lin2=(const float*)d_in[30];
  const float* W_head=(const float*)d_in[31]; const float* b_head=(const float*)d_in[32];
  const int* ei   =(const int*)d_in[33];
  const int* batch=(const int*)d_in[34];
  const int* src=ei; const int* dst=ei+E_;
  float* y=(float*)d_out;

  // ---- workspace layout (~217 MiB total) ----
  const size_t NH=(size_t)N_*H_, BH=(size_t)B_*H_;
  bf16* b0  =(bf16*)d_ws;           // N*H bf16
  bf16* b1  =b0+NH;                 // N*H bf16
  bf16* b2v =b1+NH;                 // N*H bf16
  float* outA=(float*)(b2v+NH);     // B*H fp32
  float* outB=outA+BH;
  float* hb  =outB+BH;
  float* elog=hb+BH;                // E
  float* dsrc=elog+E_;              // N
  float* ddst=dsrc+N_;              // N
  float* alog=ddst+N_;              // N
  float* wdd =alog+N_;              // 128
  float* dd  =wdd+128;              // B
  int* deg =(int*)(dd+B_);          // N
  int* ptr =deg+N_;                 // N+1
  int* wofs=ptr+N_+1;               // N
  int* eids=wofs+N_;                // E
  int* part=eids+E_;                // 512
  int* mptr=part+512;               // B+1

  // ---- CSR by dst + molecule ranges ----
  zero_i32_k<<<(N_+255)/256,256,0,stream>>>(deg,N_);
  hist_k<<<(E_+255)/256,256,0,stream>>>(dst,deg,E_);
  int nb=(N_+1023)/1024;
  scan1_k<<<nb,256,0,stream>>>(deg,ptr,part,N_);
  scan2_k<<<1,512,0,stream>>>(part,nb);
  scan3_k<<<(N_+255)/256,256,0,stream>>>(ptr,part,wofs,N_,E_);
  fill_csr_k<<<(E_+255)/256,256,0,stream>>>(dst,wofs,eids,E_);
  mol_ptr_k<<<(B_+1+255)/256,256,0,stream>>>(batch,mptr,N_,B_);

  // ---- lin1: X -> b0 ----
  lin1_k<<<4096,256,0,stream>>>(x0,W_lin1,b_lin1,b0,N_);

  dim3 gl(1024,2), ga(512,4);
  // ---- GATEConv ----
  lin_single_k<0><<<gl,256,0,stream>>>(b0,gate_W1,138,nullptr,b1,N_);      // u -> b1
  rowdot_k<bf16><<<(N_+3)/4,256,0,stream>>>(b0,gate_att_r,ddst,N_);
  gate_edge_logits_k<<<4096,256,0,stream>>>(b1,edge_attr,gate_W1,gate_att_l,ddst,src,dst,elog,E_);
  node_gather_k<<<(N_+3)/4,256,0,stream>>>(elog,eids,ptr,src,b0,b2v,N_);   // S -> b2
  lin_single_k<2><<<gl,256,0,stream>>>(b2v,gate_W2,128,gate_bias,b1,N_);   // h=elu -> b1
  // ---- GRU1: x=relu(gru(h=b1, x=b0)) -> b2 ----
  gru_fused_k<bf16><<<ga,256,0,stream>>>(b1,b0,g1_Wih,g1_Whh,g1_bih,g1_bhh,b2v,N_);
  // ---- atom GATConv (x lives in b2) ----
  lin_single_k<0><<<gl,256,0,stream>>>(b2v,conv_W,128,nullptr,b0,N_);      // xl -> b0
  rowdot_k<bf16><<<(N_+3)/4,256,0,stream>>>(b0,conv_att_src,dsrc,N_);
  rowdot_k<bf16><<<(N_+3)/4,256,0,stream>>>(b0,conv_att_dst,ddst,N_);
  conv_logit_k<<<(E_+255)/256,256,0,stream>>>(dsrc,ddst,src,dst,elog,E_);
  node_gather_k<<<(N_+3)/4,256,0,stream>>>(elog,eids,ptr,src,b0,b1,N_);    // S -> b1
  bias_relu_k<<<(int)((NH+255)/256),256,0,stream>>>(b1,conv_bias,(long)NH);// h=relu -> b1 (in place)
  // ---- GRU2: x=relu(gru(h=b1, x=b2)) -> b0 ----
  gru_fused_k<bf16><<<ga,256,0,stream>>>(b1,b2v,g2_Wih,g2_Whh,g2_bih,g2_bhh,b0,N_);
  // ---- readout (x lives in b0) ----
  mol_sum_k<<<(B_+3)/4,256,0,stream>>>(b0,mptr,outA,B_);
  lin_single_k<0><<<gl,256,0,stream>>>(b0,mol_W,128,nullptr,b1,N_);        // xs -> b1
  rowdot_k<bf16><<<(N_+3)/4,256,0,stream>>>(b1,mol_att_src,dsrc,N_);
  fold_att_k<<<1,128,0,stream>>>(mol_W,mol_att_dst,wdd);
  float* out_cur=outA; float* out_nxt=outB;
  dim3 gm(157,4);
  for (int ts=0; ts<2; ts++){
    rowdot_k<float><<<(B_+3)/4,256,0,stream>>>(out_cur,wdd,dd,B_);
    mol_logit_k<<<(N_+255)/256,256,0,stream>>>(dsrc,dd,batch,alog,N_);
    mol_gather_k<<<(B_+3)/4,256,0,stream>>>(alog,mptr,b1,mol_bias,hb,B_);
    gru_fused_k<float><<<gm,256,0,stream>>>(hb,out_cur,gm_Wih,gm_Whh,gm_bih,gm_bhh,out_nxt,B_);
    float* tmp=out_cur; out_cur=out_nxt; out_nxt=tmp;
  }
  final_head_k<<<B_,128,0,stream>>>(out_cur,W_lin2,b_lin2,W_head,b_head,y,B_);
}

// Round 4
// 2175.572 us; speedup vs baseline: 2.7245x; 2.7245x over previous
//
#include <hip/hip_runtime.h>
#include <hip/hip_bf16.h>
#include <type_traits>

typedef __hip_bfloat16 bf16;

constexpr int N_  = 250000;
constexpr int E_  = 500000;
constexpr int B_  = 10000;
constexpr int H_  = 128;

typedef short s8v __attribute__((ext_vector_type(8)));   // 8 bf16 in 4 VGPRs
typedef float f4v __attribute__((ext_vector_type(4)));

__device__ __forceinline__ float b2f(bf16 v){ return __bfloat162float(v); }
__device__ __forceinline__ bf16  f2b(float v){ return __float2bfloat16(v); }
__device__ __forceinline__ float to_float(float v){ return v; }
__device__ __forceinline__ float to_float(bf16 v){ return __bfloat162float(v); }
__device__ __forceinline__ float lrelu_f(float v){ return v > 0.f ? v : 0.01f*v; }
__device__ __forceinline__ float elu_f(float v){ return v > 0.f ? v : expm1f(v); }
__device__ __forceinline__ unsigned f2b_bits(float f){
  bf16 h=__float2bfloat16(f); unsigned short s; __builtin_memcpy(&s,&h,2); return (unsigned)s;
}
// unpack 8 bf16 (as uint4) -> 8 fp32
__device__ __forceinline__ void unp8(uint4 v, float* o){
  o[0]=__uint_as_float(v.x<<16); o[1]=__uint_as_float(v.x&0xffff0000u);
  o[2]=__uint_as_float(v.y<<16); o[3]=__uint_as_float(v.y&0xffff0000u);
  o[4]=__uint_as_float(v.z<<16); o[5]=__uint_as_float(v.z&0xffff0000u);
  o[6]=__uint_as_float(v.w<<16); o[7]=__uint_as_float(v.w&0xffff0000u);
}

// ---------------- fp32 weight -> bf16 copy (first 128 cols of each row) -----
__global__ void w2b_k(const float* __restrict__ W, int ld, bf16* __restrict__ O, int rows){
  int i=blockIdx.x*256+threadIdx.x;
  if (i<rows*128){ int r=i>>7,k=i&127; O[i]=f2b(W[(size_t)r*ld+k]); }
}

// ---------------- lin1: [N,39] fp32 -> [N,128] bf16, lrelu ----------------
__global__ __launch_bounds__(256) void lin1_k(const float* __restrict__ X0, const float* __restrict__ W,
                       const float* __restrict__ b, bf16* __restrict__ Y, int M){
  __shared__ float sW[128*41];
  __shared__ float sb[128];
  __shared__ float sx[2][41];
  for (int i = threadIdx.x; i < 128*39; i += 256){ int c=i/39, k=i-c*39; sW[c*41+k]=W[i]; }
  if (threadIdx.x < 128) sb[threadIdx.x]=b[threadIdx.x];
  __syncthreads();
  int sub = threadIdx.x>>7, c = threadIdx.x&127;
  for (long r0=(long)blockIdx.x*2; r0<M; r0+=(long)gridDim.x*2){
    __syncthreads();
    for (int i=threadIdx.x;i<2*39;i+=256){ int rr=i/39,k=i-rr*39; long row=r0+rr;
      sx[rr][k]= row<M? X0[row*39+k]:0.f; }
    __syncthreads();
    long row=r0+sub;
    if (row<M){
      float acc=sb[c];
      #pragma unroll
      for (int k=0;k<39;k++) acc += sx[sub][k]*sW[c*41+k];
      Y[row*128+c]=f2b(lrelu_f(acc));
    }
  }
}

// ---- MFMA linear: Y[M,128] = act(X[M,128] @ Wb^T + bias), bf16 io ----
// Wb is bf16 [128 out][128 in] row-major. Block: 64 rows x 128 cols, 4 waves.
template<int ACT>   // 0 none, 2 elu
__global__ __launch_bounds__(256) void lin_mfma_k(const bf16* __restrict__ X, const bf16* __restrict__ Wb,
                            const float* __restrict__ bias, bf16* __restrict__ Y, int M){
  int wv=threadIdx.x>>6, lane=threadIdx.x&63;
  int n=lane&15, q=lane>>4;
  long r0=(long)blockIdx.x*64;
  int c0=wv*32;
  f4v acc[4][2];
  #pragma unroll
  for (int rt=0;rt<4;rt++)
    #pragma unroll
    for (int ct=0;ct<2;ct++) acc[rt][ct]=(f4v){0.f,0.f,0.f,0.f};
  #pragma unroll
  for (int kk=0;kk<4;kk++){
    int k0=kk*32 + q*8;
    s8v a[4], b[2];
    #pragma unroll
    for (int rt=0;rt<4;rt++){
      long row=r0+rt*16+n; if (row>=M) row=M-1;   // clamp: dup row, stores guarded
      a[rt]=*(const s8v*)(X+row*128+k0);
    }
    #pragma unroll
    for (int ct=0;ct<2;ct++)
      b[ct]=*(const s8v*)(Wb+(size_t)(c0+ct*16+n)*128+k0);
    #pragma unroll
    for (int rt=0;rt<4;rt++)
      #pragma unroll
      for (int ct=0;ct<2;ct++)
        acc[rt][ct]=__builtin_amdgcn_mfma_f32_16x16x32_bf16(a[rt],b[ct],acc[rt][ct],0,0,0);
  }
  #pragma unroll
  for (int ct=0;ct<2;ct++){
    int col=c0+ct*16+n;
    float bb=bias? bias[col]:0.f;
    #pragma unroll
    for (int rt=0;rt<4;rt++){
      #pragma unroll
      for (int rg=0;rg<4;rg++){
        long row=r0+rt*16+q*4+rg;
        if (row<M){
          float v=acc[rt][ct][rg]+bb;
          if (ACT==2) v=elu_f(v);
          Y[row*128+col]=f2b(v);
        }
      }
    }
  }
}

// ---- MFMA fused GRU (atoms): dest = relu((1-z)*n + z*x), 6 GEMMs ----
// A,X bf16 [M,128]; Wih,Whh bf16 [384][128]; bih,bhh fp32 [384].
// Block: 32 rows; wave w owns cols [w*32,w*32+32) for all 6 gates.
__global__ __launch_bounds__(256) void gru_mfma_k(const bf16* __restrict__ A, const bf16* __restrict__ X,
                            const bf16* __restrict__ Wih, const bf16* __restrict__ Whh,
                            const float* __restrict__ bih, const float* __restrict__ bhh,
                            bf16* __restrict__ dest, int M){
  int wv=threadIdx.x>>6, lane=threadIdx.x&63;
  int n=lane&15, q=lane>>4;
  long r0=(long)blockIdx.x*32;
  int c0=wv*32;
  f4v acc[6][2][2];
  #pragma unroll
  for (int g=0;g<6;g++)
    #pragma unroll
    for (int rt=0;rt<2;rt++)
      #pragma unroll
      for (int ct=0;ct<2;ct++) acc[g][rt][ct]=(f4v){0.f,0.f,0.f,0.f};
  #pragma unroll
  for (int kk=0;kk<4;kk++){
    int k0=kk*32 + q*8;
    s8v aA[2], aX[2];
    #pragma unroll
    for (int rt=0;rt<2;rt++){
      long row=r0+rt*16+n; if (row>=M) row=M-1;
      aA[rt]=*(const s8v*)(A+row*128+k0);
      aX[rt]=*(const s8v*)(X+row*128+k0);
    }
    #pragma unroll
    for (int g=0;g<3;g++){
      #pragma unroll
      for (int ct=0;ct<2;ct++){
        s8v bi=*(const s8v*)(Wih+(size_t)(g*128+c0+ct*16+n)*128+k0);
        s8v bh=*(const s8v*)(Whh+(size_t)(g*128+c0+ct*16+n)*128+k0);
        #pragma unroll
        for (int rt=0;rt<2;rt++){
          acc[g  ][rt][ct]=__builtin_amdgcn_mfma_f32_16x16x32_bf16(aA[rt],bi,acc[g  ][rt][ct],0,0,0);
          acc[3+g][rt][ct]=__builtin_amdgcn_mfma_f32_16x16x32_bf16(aX[rt],bh,acc[3+g][rt][ct],0,0,0);
        }
      }
    }
  }
  #pragma unroll
  for (int ct=0;ct<2;ct++){
    int col=c0+ct*16+n;
    float br =bih[col]+bhh[col];
    float bz =bih[128+col]+bhh[128+col];
    float bni=bih[256+col], bnh=bhh[256+col];
    #pragma unroll
    for (int rt=0;rt<2;rt++){
      #pragma unroll
      for (int rg=0;rg<4;rg++){
        long row=r0+rt*16+q*4+rg;
        if (row<M){
          float ri=acc[0][rt][ct][rg], zi=acc[1][rt][ct][rg], ni=acc[2][rt][ct][rg];
          float rh=acc[3][rt][ct][rg], zh=acc[4][rt][ct][rg], nh=acc[5][rt][ct][rg];
          float rgate=1.f/(1.f+expf(-(ri+rh+br)));
          float zgate=1.f/(1.f+expf(-(zi+zh+bz)));
          float nn=tanhf(ni+bni + rgate*(nh+bnh));
          float xv=b2f(X[row*128+col]);
          float o=(1.f-zgate)*nn + zgate*xv;
          dest[row*128+col]=f2b(fmaxf(o,0.f));
        }
      }
    }
  }
}

// ------- scalar fused GRU (molecules, fp32 state) ----
template<typename T>
__global__ __launch_bounds__(256) void gru_fused_k(const T* __restrict__ A, const T* __restrict__ X,
                            const float* __restrict__ Wih, const float* __restrict__ Whh,
                            const float* __restrict__ bih, const float* __restrict__ bhh,
                            T* __restrict__ dest, int M){
  __shared__ unsigned sW[6][32*66];
  __shared__ float sA[8][132], sX[8][132];
  __shared__ float sbi[3][32], sbh[3][32];
  int c0 = blockIdx.y*32;
  for (int i=threadIdx.x; i<6*32*64; i+=256){
    int m=i>>11, r=i&2047, c=r>>6, k2=r&63;
    const float* base = (m<3)? Wih : Whh;
    int g = (m<3)? m : m-3;
    const float* wp = base + ((size_t)(g*128 + c0 + c))*128 + 2*k2;
    sW[m][c*66 + k2] = f2b_bits(wp[0]) | (f2b_bits(wp[1])<<16);
  }
  if (threadIdx.x < 96){
    int g=threadIdx.x>>5, c=threadIdx.x&31;
    sbi[g][c]=bih[g*128+c0+c]; sbh[g][c]=bhh[g*128+c0+c];
  }
  __syncthreads();
  int sub=threadIdx.x>>5, c=threadIdx.x&31;
  for (long r0=(long)blockIdx.x*8; r0<M; r0+=(long)gridDim.x*8){
    __syncthreads();
    for (int i=threadIdx.x;i<8*16;i+=256){
      int rr=i>>4, q=i&15; long row=r0+rr;
      if constexpr (std::is_same<T,bf16>::value){
        uint4 va = row<M? *(const uint4*)(A+row*128+q*8) : make_uint4(0,0,0,0);
        uint4 vx = row<M? *(const uint4*)(X+row*128+q*8) : make_uint4(0,0,0,0);
        unp8(va,&sA[rr][q*8]); unp8(vx,&sX[rr][q*8]);
      } else {
        if (row<M){
          *(float4*)&sA[rr][q*8]   = *(const float4*)(A+row*128+q*8);
          *(float4*)&sA[rr][q*8+4] = *(const float4*)(A+row*128+q*8+4);
          *(float4*)&sX[rr][q*8]   = *(const float4*)(X+row*128+q*8);
          *(float4*)&sX[rr][q*8+4] = *(const float4*)(X+row*128+q*8+4);
        } else {
          float4 z=make_float4(0,0,0,0);
          *(float4*)&sA[rr][q*8]=z; *(float4*)&sA[rr][q*8+4]=z;
          *(float4*)&sX[rr][q*8]=z; *(float4*)&sX[rr][q*8+4]=z;
        }
      }
    }
    __syncthreads();
    long row=r0+sub;
    if (row<M){
      const unsigned* wri=&sW[0][c*66]; const unsigned* wzi=&sW[1][c*66]; const unsigned* wni=&sW[2][c*66];
      const unsigned* wrh=&sW[3][c*66]; const unsigned* wzh=&sW[4][c*66]; const unsigned* wnh=&sW[5][c*66];
      const float2* xa=(const float2*)sA[sub]; const float2* xb=(const float2*)sX[sub];
      float ari=0,azi=0,ani=0,arh=0,azh=0,anh=0;
      #pragma unroll 8
      for (int k2=0;k2<64;k2++){
        float2 av=xa[k2], bv=xb[k2];
        unsigned u;
        u=wri[k2]; ari += av.x*__uint_as_float(u<<16) + av.y*__uint_as_float(u&0xffff0000u);
        u=wzi[k2]; azi += av.x*__uint_as_float(u<<16) + av.y*__uint_as_float(u&0xffff0000u);
        u=wni[k2]; ani += av.x*__uint_as_float(u<<16) + av.y*__uint_as_float(u&0xffff0000u);
        u=wrh[k2]; arh += bv.x*__uint_as_float(u<<16) + bv.y*__uint_as_float(u&0xffff0000u);
        u=wzh[k2]; azh += bv.x*__uint_as_float(u<<16) + bv.y*__uint_as_float(u&0xffff0000u);
        u=wnh[k2]; anh += bv.x*__uint_as_float(u<<16) + bv.y*__uint_as_float(u&0xffff0000u);
      }
      float rg = 1.f/(1.f+expf(-(ari+arh+sbi[0][c]+sbh[0][c])));
      float zg = 1.f/(1.f+expf(-(azi+azh+sbi[1][c]+sbh[1][c])));
      float nn = tanhf(ani+sbi[2][c] + rg*(anh+sbh[2][c]));
      float xv = sX[sub][c0+c];
      float o  = (1.f-zg)*nn + zg*xv;
      float res = fmaxf(o,0.f);
      if constexpr (std::is_same<T,bf16>::value) dest[row*128+c0+c] = f2b(res);
      else dest[row*128+c0+c] = res;
    }
  }
}

// ---------------- row dot: d[row] = Y[row,:] . v ----------------
template<typename TY>
__global__ void rowdot_k(const TY* __restrict__ Y, const float* __restrict__ v,
                         float* __restrict__ d, int M){
  __shared__ float sv[128];
  if (threadIdx.x<128) sv[threadIdx.x]=v[threadIdx.x];
  __syncthreads();
  int wv=threadIdx.x>>6, lane=threadIdx.x&63;
  long row=(long)blockIdx.x*4+wv;
  if (row>=M) return;
  float a=to_float(Y[row*128+lane])*sv[lane]+to_float(Y[row*128+64+lane])*sv[64+lane];
  #pragma unroll
  for (int o=32;o;o>>=1) a+=__shfl_xor(a,o);
  if (!lane) d[row]=a;
}

// ---------------- GATE edge logits ----------------
__global__ __launch_bounds__(256) void gate_edge_logits_k(const bf16* __restrict__ u, const float* __restrict__ ea,
                                   const float* __restrict__ gW1, const float* __restrict__ att_l,
                                   const float* __restrict__ ddst, const int* __restrict__ src,
                                   const int* __restrict__ dst, float* __restrict__ elog, int E){
  __shared__ float sWb[10][128];
  __shared__ float sal[128];
  for (int i=threadIdx.x;i<10*128;i+=256){ int k=i>>7,c=i&127; sWb[k][c]=gW1[(size_t)c*138+128+k]; }
  if (threadIdx.x<128) sal[threadIdx.x]=att_l[threadIdx.x];
  __syncthreads();
  int wv=threadIdx.x>>6, lane=threadIdx.x&63;
  for (long e=(long)blockIdx.x*4+wv; e<E; e+=(long)gridDim.x*4){
    int sj=src[e], di=dst[e];
    float eal[10];
    #pragma unroll
    for (int k=0;k<10;k++) eal[k]=ea[(size_t)e*10+k];
    float acc=0.f;
    #pragma unroll
    for (int j=0;j<2;j++){
      int cc=lane+64*j;
      float v=0.f;
      #pragma unroll
      for (int k=0;k<10;k++) v+=eal[k]*sWb[k][cc];
      v+=b2f(u[(size_t)sj*128+cc]);
      acc+=lrelu_f(v)*sal[cc];
    }
    #pragma unroll
    for (int o=32;o;o>>=1) acc+=__shfl_xor(acc,o);
    if (!lane) elog[e]=lrelu_f(acc+ddst[di]);
  }
}

// ---------------- conv edge logits ----------------
__global__ void conv_logit_k(const float* __restrict__ dsrc, const float* __restrict__ ddst,
                             const int* __restrict__ src, const int* __restrict__ dst,
                             float* __restrict__ elog, int n){
  int e=blockIdx.x*256+threadIdx.x; if (e<n) elog[e]=lrelu_f(dsrc[src[e]]+ddst[dst[e]]);
}

// ------- per-node softmax over incoming edges + weighted sum of V[src] -------
__global__ void node_gather_k(const float* __restrict__ elog, const int* __restrict__ eids,
                              const int* __restrict__ ptr, const int* __restrict__ src,
                              const bf16* __restrict__ V, bf16* __restrict__ S, int M){
  int wv=threadIdx.x>>6, lane=threadIdx.x&63;
  int node=blockIdx.x*4+wv; if (node>=M) return;
  int p0=ptr[node], p1=ptr[node+1];
  float m=-INFINITY;
  for (int p=p0+lane;p<p1;p+=64) m=fmaxf(m,elog[eids[p]]);
  #pragma unroll
  for (int o=32;o;o>>=1) m=fmaxf(m,__shfl_xor(m,o));
  float ssum=0.f;
  for (int p=p0+lane;p<p1;p+=64) ssum+=expf(elog[eids[p]]-m);
  #pragma unroll
  for (int o=32;o;o>>=1) ssum+=__shfl_xor(ssum,o);
  float inv=1.f/(ssum+1e-16f);
  float a0=0.f,a1=0.f;
  for (int p=p0;p<p1;p++){
    int e=eids[p];
    float al=expf(elog[e]-m)*inv;
    const bf16* vr=&V[(size_t)src[e]*128];
    a0+=al*b2f(vr[lane]); a1+=al*b2f(vr[64+lane]);
  }
  S[(size_t)node*128+lane]=f2b(a0); S[(size_t)node*128+64+lane]=f2b(a1);
}

// ---------------- elementwise h = relu(s + bias) (in place) ----------------
__global__ void bias_relu_k(bf16* __restrict__ X, const float* __restrict__ b, long n){
  long i=(long)blockIdx.x*256+threadIdx.x;
  if (i<n){ float v=b2f(X[i])+b[i&127]; X[i]=f2b(fmaxf(v,0.f)); }
}

// ---------------- molecule kernels ----------------
__global__ void mol_ptr_k(const int* __restrict__ batch, int* __restrict__ mptr, int n, int Bn){
  int b=blockIdx.x*256+threadIdx.x; if (b>Bn) return;
  if (b==Bn){ mptr[Bn]=n; return; }
  int lo=0, hi=n;
  while (lo<hi){ int mid=(lo+hi)>>1; if (batch[mid]<b) lo=mid+1; else hi=mid; }
  mptr[b]=lo;
}

__global__ void mol_sum_k(const bf16* __restrict__ x, const int* __restrict__ mptr,
                          float* __restrict__ out, int Bn){
  int wv=threadIdx.x>>6, lane=threadIdx.x&63;
  int b=blockIdx.x*4+wv; if (b>=Bn) return;
  int p0=mptr[b], p1=mptr[b+1];
  float a0=0.f,a1=0.f;
  for (int i=p0;i<p1;i++){ a0+=b2f(x[(size_t)i*128+lane]); a1+=b2f(x[(size_t)i*128+64+lane]); }
  out[(size_t)b*128+lane]=fmaxf(a0,0.f); out[(size_t)b*128+64+lane]=fmaxf(a1,0.f);
}

__global__ void fold_att_k(const float* __restrict__ W, const float* __restrict__ att,
                           float* __restrict__ wdd){
  int k=threadIdx.x; float a=0.f;
  for (int c=0;c<128;c++) a+=att[c]*W[(size_t)c*128+k];
  wdd[k]=a;
}

__global__ void mol_logit_k(const float* __restrict__ dsrc, const float* __restrict__ dd,
                            const int* __restrict__ batch, float* __restrict__ alog, int n){
  int i=blockIdx.x*256+threadIdx.x; if (i<n) alog[i]=lrelu_f(dsrc[i]+dd[batch[i]]);
}

__global__ void mol_gather_k(const float* __restrict__ alog, const int* __restrict__ mptr,
                             const bf16* __restrict__ xs, const float* __restrict__ bias,
                             float* __restrict__ hb, int Bn){
  int wv=threadIdx.x>>6, lane=threadIdx.x&63;
  int b=blockIdx.x*4+wv; if (b>=Bn) return;
  int p0=mptr[b], p1=mptr[b+1];
  float m=-INFINITY;
  for (int i=p0+lane;i<p1;i+=64) m=fmaxf(m,alog[i]);
  #pragma unroll
  for (int o=32;o;o>>=1) m=fmaxf(m,__shfl_xor(m,o));
  float ssum=0.f;
  for (int i=p0+lane;i<p1;i+=64) ssum+=expf(alog[i]-m);
  #pragma unroll
  for (int o=32;o;o>>=1) ssum+=__shfl_xor(ssum,o);
  float inv=1.f/(ssum+1e-16f);
  float a0=0.f,a1=0.f;
  for (int i=p0;i<p1;i++){
    float al=expf(alog[i]-m)*inv;
    a0+=al*b2f(xs[(size_t)i*128+lane]); a1+=al*b2f(xs[(size_t)i*128+64+lane]);
  }
  hb[(size_t)b*128+lane]=elu_f(a0+bias[lane]);
  hb[(size_t)b*128+64+lane]=elu_f(a1+bias[64+lane]);
}

// ---------------- final head ----------------
__global__ void final_head_k(const float* __restrict__ out, const float* __restrict__ W2,
                             const float* __restrict__ b2, const float* __restrict__ Wh,
                             const float* __restrict__ bh, float* __restrict__ y, int Bn){
  __shared__ float srow[128]; __shared__ float sred[128];
  int b=blockIdx.x, c=threadIdx.x;
  srow[c]=out[(size_t)b*128+c]; __syncthreads();
  float acc=b2[c];
  const float* wr=&W2[(size_t)c*128];
  #pragma unroll 8
  for (int k=0;k<128;k++) acc+=srow[k]*wr[k];
  sred[c]=acc*Wh[c]; __syncthreads();
  for (int o=64;o;o>>=1){ if (c<o) sred[c]+=sred[c+o]; __syncthreads(); }
  if (c==0) y[b]=sred[0]+bh[0];
}

// ---------------- CSR build ----------------
__global__ void zero_i32_k(int* p, int n){ int i=blockIdx.x*256+threadIdx.x; if (i<n) p[i]=0; }
__global__ void hist_k(const int* __restrict__ dst, int* __restrict__ deg, int n){
  int e=blockIdx.x*256+threadIdx.x; if (e<n) atomicAdd(&deg[dst[e]],1);
}
__global__ void scan1_k(const int* __restrict__ deg, int* __restrict__ ptr,
                        int* __restrict__ part, int n){
  __shared__ int sd[256];
  int base=blockIdx.x*1024, tid=threadIdx.x;
  int v[4]; int ssum=0;
  #pragma unroll
  for (int j=0;j<4;j++){ int idx=base+tid*4+j; v[j]= idx<n? deg[idx]:0; ssum+=v[j]; }
  sd[tid]=ssum; __syncthreads();
  for (int o=1;o<256;o<<=1){ int t = tid>=o? sd[tid-o]:0; __syncthreads(); sd[tid]+=t; __syncthreads(); }
  int excl=sd[tid]-ssum;
  #pragma unroll
  for (int j=0;j<4;j++){ int idx=base+tid*4+j; if (idx<n) ptr[idx]=excl; excl+=v[j]; }
  if (tid==255) part[blockIdx.x]=sd[255];
}
__global__ void scan2_k(int* part, int nb){
  __shared__ int sd[512];
  int tid=threadIdx.x;
  int v= tid<nb? part[tid]:0; sd[tid]=v; __syncthreads();
  for (int o=1;o<512;o<<=1){ int t = tid>=o? sd[tid-o]:0; __syncthreads(); sd[tid]+=t; __syncthreads(); }
  if (tid<nb) part[tid]=sd[tid]-v;
}
__global__ void scan3_k(int* __restrict__ ptr, const int* __restrict__ part,
                        int* __restrict__ wofs, int n, int total){
  int i=blockIdx.x*256+threadIdx.x;
  if (i<n){ int val=ptr[i]+part[i>>10]; ptr[i]=val; wofs[i]=val; }
  if (i==0) ptr[n]=total;
}
__global__ void fill_csr_k(const int* __restrict__ dst, int* __restrict__ wofs,
                           int* __restrict__ eids, int n){
  int e=blockIdx.x*256+threadIdx.x;
  if (e<n){ int p=atomicAdd(&wofs[dst[e]],1); eids[p]=e; }
}

// =====================================================================
extern "C" void kernel_launch(void* const* d_in, const int* in_sizes, int n_in,
                              void* d_out, int out_size, void* d_ws, size_t ws_size,
                              hipStream_t stream){
  (void)in_sizes; (void)n_in; (void)out_size; (void)ws_size;
  const float* x0        =(const float*)d_in[0];
  const float* edge_attr =(const float*)d_in[1];
  const float* W_lin1    =(const float*)d_in[2];
  const float* b_lin1    =(const float*)d_in[3];
  const float* gate_W1   =(const float*)d_in[4];
  const float* gate_W2   =(const float*)d_in[5];
  const float* gate_att_l=(const float*)d_in[6];
  const float* gate_att_r=(const float*)d_in[7];
  const float* gate_bias =(const float*)d_in[8];
  const float* g1_Wih=(const float*)d_in[9];  const float* g1_Whh=(const float*)d_in[10];
  const float* g1_bih=(const float*)d_in[11]; const float* g1_bhh=(const float*)d_in[12];
  const float* conv_W=(const float*)d_in[13];
  const float* conv_att_src=(const float*)d_in[14];
  const float* conv_att_dst=(const float*)d_in[15];
  const float* conv_bias   =(const float*)d_in[16];
  const float* g2_Wih=(const float*)d_in[17]; const float* g2_Whh=(const float*)d_in[18];
  const float* g2_bih=(const float*)d_in[19]; const float* g2_bhh=(const float*)d_in[20];
  const float* mol_W=(const float*)d_in[21];
  const float* mol_att_src=(const float*)d_in[22];
  const float* mol_att_dst=(const float*)d_in[23];
  const float* mol_bias   =(const float*)d_in[24];
  const float* gm_Wih=(const float*)d_in[25]; const float* gm_Whh=(const float*)d_in[26];
  const float* gm_bih=(const float*)d_in[27]; const float* gm_bhh=(const float*)d_in[28];
  const float* W_lin2=(const float*)d_in[29]; const float* b_lin2=(const float*)d_in[30];
  const float* W_head=(const float*)d_in[31]; const float* b_head=(const float*)d_in[32];
  const int* ei   =(const int*)d_in[33];
  const int* batch=(const int*)d_in[34];
  const int* src=ei; const int* dst=ei+E_;
  float* y=(float*)d_out;

  // ---- workspace layout (~218 MiB total) ----
  const size_t NH=(size_t)N_*H_, BH=(size_t)B_*H_;
  bf16* b0  =(bf16*)d_ws;           // N*H bf16
  bf16* b1  =b0+NH;                 // N*H bf16
  bf16* b2v =b1+NH;                 // N*H bf16
  float* outA=(float*)(b2v+NH);     // B*H fp32
  float* outB=outA+BH;
  float* hb  =outB+BH;
  float* elog=hb+BH;                // E
  float* dsrc=elog+E_;              // N
  float* ddst=dsrc+N_;              // N
  float* alog=ddst+N_;              // N
  float* wdd =alog+N_;              // 128
  float* dd  =wdd+128;              // B
  int* deg =(int*)(dd+B_);          // N
  int* ptr =deg+N_;                 // N+1
  int* wofs=ptr+N_+1;               // N
  int* eids=wofs+N_;                // E
  int* part=eids+E_;                // 512
  int* mptr=part+512;               // B+1
  // bf16 weight copies (16B-aligned)
  uintptr_t wbase=((uintptr_t)(mptr+B_+1)+255)&~(uintptr_t)255;
  bf16* wb_gw1 =(bf16*)wbase;        // 128*128
  bf16* wb_gw2 =wb_gw1 +128*128;
  bf16* wb_conv=wb_gw2 +128*128;
  bf16* wb_mol =wb_conv+128*128;
  bf16* wb_g1i =wb_mol +128*128;     // 384*128
  bf16* wb_g1h =wb_g1i +384*128;
  bf16* wb_g2i =wb_g1h +384*128;
  bf16* wb_g2h =wb_g2i +384*128;

  // ---- weight conversions ----
  w2b_k<<<64,256,0,stream>>>(gate_W1,138,wb_gw1,128);
  w2b_k<<<64,256,0,stream>>>(gate_W2,128,wb_gw2,128);
  w2b_k<<<64,256,0,stream>>>(conv_W ,128,wb_conv,128);
  w2b_k<<<64,256,0,stream>>>(mol_W  ,128,wb_mol ,128);
  w2b_k<<<192,256,0,stream>>>(g1_Wih,128,wb_g1i,384);
  w2b_k<<<192,256,0,stream>>>(g1_Whh,128,wb_g1h,384);
  w2b_k<<<192,256,0,stream>>>(g2_Wih,128,wb_g2i,384);
  w2b_k<<<192,256,0,stream>>>(g2_Whh,128,wb_g2h,384);

  // ---- CSR by dst + molecule ranges ----
  zero_i32_k<<<(N_+255)/256,256,0,stream>>>(deg,N_);
  hist_k<<<(E_+255)/256,256,0,stream>>>(dst,deg,E_);
  int nb=(N_+1023)/1024;
  scan1_k<<<nb,256,0,stream>>>(deg,ptr,part,N_);
  scan2_k<<<1,512,0,stream>>>(part,nb);
  scan3_k<<<(N_+255)/256,256,0,stream>>>(ptr,part,wofs,N_,E_);
  fill_csr_k<<<(E_+255)/256,256,0,stream>>>(dst,wofs,eids,E_);
  mol_ptr_k<<<(B_+1+255)/256,256,0,stream>>>(batch,mptr,N_,B_);

  // ---- lin1: X -> b0 ----
  lin1_k<<<4096,256,0,stream>>>(x0,W_lin1,b_lin1,b0,N_);

  const int GL=(N_+63)/64, GG=(N_+31)/32;
  // ---- GATEConv ----
  lin_mfma_k<0><<<GL,256,0,stream>>>(b0,wb_gw1,nullptr,b1,N_);             // u -> b1
  rowdot_k<bf16><<<(N_+3)/4,256,0,stream>>>(b0,gate_att_r,ddst,N_);
  gate_edge_logits_k<<<4096,256,0,stream>>>(b1,edge_attr,gate_W1,gate_att_l,ddst,src,dst,elog,E_);
  node_gather_k<<<(N_+3)/4,256,0,stream>>>(elog,eids,ptr,src,b0,b2v,N_);   // S -> b2
  lin_mfma_k<2><<<GL,256,0,stream>>>(b2v,wb_gw2,gate_bias,b1,N_);          // h=elu -> b1
  // ---- GRU1: x=relu(gru(h=b1, x=b0)) -> b2 ----
  gru_mfma_k<<<GG,256,0,stream>>>(b1,b0,wb_g1i,wb_g1h,g1_bih,g1_bhh,b2v,N_);
  // ---- atom GATConv (x lives in b2) ----
  lin_mfma_k<0><<<GL,256,0,stream>>>(b2v,wb_conv,nullptr,b0,N_);           // xl -> b0
  rowdot_k<bf16><<<(N_+3)/4,256,0,stream>>>(b0,conv_att_src,dsrc,N_);
  rowdot_k<bf16><<<(N_+3)/4,256,0,stream>>>(b0,conv_att_dst,ddst,N_);
  conv_logit_k<<<(E_+255)/256,256,0,stream>>>(dsrc,ddst,src,dst,elog,E_);
  node_gather_k<<<(N_+3)/4,256,0,stream>>>(elog,eids,ptr,src,b0,b1,N_);    // S -> b1
  bias_relu_k<<<(int)((NH+255)/256),256,0,stream>>>(b1,conv_bias,(long)NH);// h=relu (in place)
  // ---- GRU2: x=relu(gru(h=b1, x=b2)) -> b0 ----
  gru_mfma_k<<<GG,256,0,stream>>>(b1,b2v,wb_g2i,wb_g2h,g2_bih,g2_bhh,b0,N_);
  // ---- readout (x lives in b0) ----
  mol_sum_k<<<(B_+3)/4,256,0,stream>>>(b0,mptr,outA,B_);
  lin_mfma_k<0><<<GL,256,0,stream>>>(b0,wb_mol,nullptr,b1,N_);             // xs -> b1
  rowdot_k<bf16><<<(N_+3)/4,256,0,stream>>>(b1,mol_att_src,dsrc,N_);
  fold_att_k<<<1,128,0,stream>>>(mol_W,mol_att_dst,wdd);
  float* out_cur=outA; float* out_nxt=outB;
  dim3 gm(157,4);
  for (int ts=0; ts<2; ts++){
    rowdot_k<float><<<(B_+3)/4,256,0,stream>>>(out_cur,wdd,dd,B_);
    mol_logit_k<<<(N_+255)/256,256,0,stream>>>(dsrc,dd,batch,alog,N_);
    mol_gather_k<<<(B_+3)/4,256,0,stream>>>(alog,mptr,b1,mol_bias,hb,B_);
    gru_fused_k<float><<<gm,256,0,stream>>>(hb,out_cur,gm_Wih,gm_Whh,gm_bih,gm_bhh,out_nxt,B_);
    float* tmp=out_cur; out_cur=out_nxt; out_nxt=tmp;
  }
  final_head_k<<<B_,256? 128:128,0,stream>>>(out_cur,W_lin2,b_lin2,W_head,b_head,y,B_);
}

// Round 5
// 1736.889 us; speedup vs baseline: 3.4126x; 1.2526x over previous
//
#include <hip/hip_runtime.h>
#include <hip/hip_bf16.h>
#include <type_traits>

typedef __hip_bfloat16 bf16;

constexpr int N_  = 250000;
constexpr int E_  = 500000;
constexpr int B_  = 10000;
constexpr int H_  = 128;

typedef short s8v __attribute__((ext_vector_type(8)));   // 8 bf16 in 4 VGPRs
typedef float f4v __attribute__((ext_vector_type(4)));

__device__ __forceinline__ float b2f(bf16 v){ return __bfloat162float(v); }
__device__ __forceinline__ bf16  f2b(float v){ return __float2bfloat16(v); }
__device__ __forceinline__ float to_float(float v){ return v; }
__device__ __forceinline__ float to_float(bf16 v){ return __bfloat162float(v); }
__device__ __forceinline__ float lrelu_f(float v){ return v > 0.f ? v : 0.01f*v; }
// fast transcendentals (v_exp_f32 / v_rcp_f32 based)
__device__ __forceinline__ float sigmoid_f(float x){ return __builtin_amdgcn_rcpf(1.f+__expf(-x)); }
__device__ __forceinline__ float tanh_f(float x){ return 1.f - 2.f*__builtin_amdgcn_rcpf(__expf(2.f*x)+1.f); }
__device__ __forceinline__ float elu_f(float v){ return v > 0.f ? v : __expf(v)-1.f; }
__device__ __forceinline__ unsigned f2b_bits(float f){
  bf16 h=__float2bfloat16(f); unsigned short s; __builtin_memcpy(&s,&h,2); return (unsigned)s;
}
__device__ __forceinline__ void unp8(uint4 v, float* o){
  o[0]=__uint_as_float(v.x<<16); o[1]=__uint_as_float(v.x&0xffff0000u);
  o[2]=__uint_as_float(v.y<<16); o[3]=__uint_as_float(v.y&0xffff0000u);
  o[4]=__uint_as_float(v.z<<16); o[5]=__uint_as_float(v.z&0xffff0000u);
  o[6]=__uint_as_float(v.w<<16); o[7]=__uint_as_float(v.w&0xffff0000u);
}

// ---------------- fp32 weight -> bf16 copy (first 128 cols of each row) -----
__global__ void w2b_k(const float* __restrict__ W, int ld, bf16* __restrict__ O, int rows){
  int i=blockIdx.x*256+threadIdx.x;
  if (i<rows*128){ int r=i>>7,k=i&127; O[i]=f2b(W[(size_t)r*ld+k]); }
}

// ---------------- lin1: [N,39] fp32 -> [N,128] bf16, lrelu ----------------
__global__ __launch_bounds__(256) void lin1_k(const float* __restrict__ X0, const float* __restrict__ W,
                       const float* __restrict__ b, bf16* __restrict__ Y, int M){
  __shared__ float sW[128*41];
  __shared__ float sb[128];
  __shared__ float sx[2][41];
  for (int i = threadIdx.x; i < 128*39; i += 256){ int c=i/39, k=i-c*39; sW[c*41+k]=W[i]; }
  if (threadIdx.x < 128) sb[threadIdx.x]=b[threadIdx.x];
  __syncthreads();
  int sub = threadIdx.x>>7, c = threadIdx.x&127;
  for (long r0=(long)blockIdx.x*2; r0<M; r0+=(long)gridDim.x*2){
    __syncthreads();
    for (int i=threadIdx.x;i<2*39;i+=256){ int rr=i/39,k=i-rr*39; long row=r0+rr;
      sx[rr][k]= row<M? X0[row*39+k]:0.f; }
    __syncthreads();
    long row=r0+sub;
    if (row<M){
      float acc=sb[c];
      #pragma unroll
      for (int k=0;k<39;k++) acc += sx[sub][k]*sW[c*41+k];
      Y[row*128+c]=f2b(lrelu_f(acc));
    }
  }
}

// ---- MFMA linear, weights in registers, grid-stride over 64-row tiles ----
template<int ACT>   // 0 none, 2 elu
__global__ __launch_bounds__(256) void lin_mfma_k(const bf16* __restrict__ X, const bf16* __restrict__ Wb,
                            const float* __restrict__ bias, bf16* __restrict__ Y, int M){
  int wv=threadIdx.x>>6, lane=threadIdx.x&63;
  int n=lane&15, q=lane>>4;
  int c0=wv*32;
  s8v wB[2][4];
  #pragma unroll
  for (int ct=0;ct<2;ct++)
    #pragma unroll
    for (int kk=0;kk<4;kk++)
      wB[ct][kk]=*(const s8v*)(Wb+(size_t)(c0+ct*16+n)*128+kk*32+q*8);
  float bb[2];
  #pragma unroll
  for (int ct=0;ct<2;ct++) bb[ct]=bias? bias[c0+ct*16+n]:0.f;
  for (long r0=(long)blockIdx.x*64; r0<M; r0+=(long)gridDim.x*64){
    s8v a[4][4];
    #pragma unroll
    for (int rt=0;rt<4;rt++){
      long row=r0+rt*16+n; if (row>=M) row=M-1;
      #pragma unroll
      for (int kk=0;kk<4;kk++) a[rt][kk]=*(const s8v*)(X+row*128+kk*32+q*8);
    }
    f4v acc[4][2];
    #pragma unroll
    for (int rt=0;rt<4;rt++)
      #pragma unroll
      for (int ct=0;ct<2;ct++) acc[rt][ct]=(f4v){0.f,0.f,0.f,0.f};
    #pragma unroll
    for (int kk=0;kk<4;kk++)
      #pragma unroll
      for (int rt=0;rt<4;rt++)
        #pragma unroll
        for (int ct=0;ct<2;ct++)
          acc[rt][ct]=__builtin_amdgcn_mfma_f32_16x16x32_bf16(a[rt][kk],wB[ct][kk],acc[rt][ct],0,0,0);
    #pragma unroll
    for (int ct=0;ct<2;ct++){
      int col=c0+ct*16+n;
      #pragma unroll
      for (int rt=0;rt<4;rt++){
        #pragma unroll
        for (int rg=0;rg<4;rg++){
          long row=r0+rt*16+q*4+rg;
          if (row<M){
            float v=acc[rt][ct][rg]+bb[ct];
            if (ACT==2) v=elu_f(v);
            Y[row*128+col]=f2b(v);
          }
        }
      }
    }
  }
}

// ---- MFMA fused GRU (atoms), all 6 weight slices in registers ----
__global__ __launch_bounds__(256,1) void gru_mfma_k(const bf16* __restrict__ A, const bf16* __restrict__ X,
                            const bf16* __restrict__ Wih, const bf16* __restrict__ Whh,
                            const float* __restrict__ bih, const float* __restrict__ bhh,
                            bf16* __restrict__ dest, int M){
  int wv=threadIdx.x>>6, lane=threadIdx.x&63;
  int n=lane&15, q=lane>>4;
  int c0=wv*32;
  s8v wI[3][2][4], wH[3][2][4];
  #pragma unroll
  for (int g=0;g<3;g++)
    #pragma unroll
    for (int ct=0;ct<2;ct++)
      #pragma unroll
      for (int kk=0;kk<4;kk++){
        size_t off=((size_t)(g*128+c0+ct*16+n))*128+kk*32+q*8;
        wI[g][ct][kk]=*(const s8v*)(Wih+off);
        wH[g][ct][kk]=*(const s8v*)(Whh+off);
      }
  float br[2],bz[2],bni[2],bnh[2];
  #pragma unroll
  for (int ct=0;ct<2;ct++){
    int col=c0+ct*16+n;
    br[ct]=bih[col]+bhh[col];
    bz[ct]=bih[128+col]+bhh[128+col];
    bni[ct]=bih[256+col]; bnh[ct]=bhh[256+col];
  }
  for (long r0=(long)blockIdx.x*32; r0<M; r0+=(long)gridDim.x*32){
    s8v aA[2][4], aX[2][4];
    #pragma unroll
    for (int rt=0;rt<2;rt++){
      long row=r0+rt*16+n; if (row>=M) row=M-1;
      #pragma unroll
      for (int kk=0;kk<4;kk++){
        aA[rt][kk]=*(const s8v*)(A+row*128+kk*32+q*8);
        aX[rt][kk]=*(const s8v*)(X+row*128+kk*32+q*8);
      }
    }
    f4v acc[6][2][2];
    #pragma unroll
    for (int g=0;g<6;g++)
      #pragma unroll
      for (int rt=0;rt<2;rt++)
        #pragma unroll
        for (int ct=0;ct<2;ct++) acc[g][rt][ct]=(f4v){0.f,0.f,0.f,0.f};
    #pragma unroll
    for (int kk=0;kk<4;kk++)
      #pragma unroll
      for (int g=0;g<3;g++)
        #pragma unroll
        for (int ct=0;ct<2;ct++)
          #pragma unroll
          for (int rt=0;rt<2;rt++){
            acc[g  ][rt][ct]=__builtin_amdgcn_mfma_f32_16x16x32_bf16(aA[rt][kk],wI[g][ct][kk],acc[g  ][rt][ct],0,0,0);
            acc[3+g][rt][ct]=__builtin_amdgcn_mfma_f32_16x16x32_bf16(aX[rt][kk],wH[g][ct][kk],acc[3+g][rt][ct],0,0,0);
          }
    #pragma unroll
    for (int ct=0;ct<2;ct++){
      int col=c0+ct*16+n;
      #pragma unroll
      for (int rt=0;rt<2;rt++){
        #pragma unroll
        for (int rg=0;rg<4;rg++){
          long row=r0+rt*16+q*4+rg;
          if (row<M){
            float rgate=sigmoid_f(acc[0][rt][ct][rg]+acc[3][rt][ct][rg]+br[ct]);
            float zgate=sigmoid_f(acc[1][rt][ct][rg]+acc[4][rt][ct][rg]+bz[ct]);
            float nn=tanh_f(acc[2][rt][ct][rg]+bni[ct] + rgate*(acc[5][rt][ct][rg]+bnh[ct]));
            float xv=b2f(X[row*128+col]);
            float o=(1.f-zgate)*nn + zgate*xv;
            dest[row*128+col]=f2b(fmaxf(o,0.f));
          }
        }
      }
    }
  }
}

// ------- scalar fused GRU (molecules, fp32 state) ----
__global__ __launch_bounds__(256) void gru_scalar_k(const float* __restrict__ A, const float* __restrict__ X,
                            const float* __restrict__ Wih, const float* __restrict__ Whh,
                            const float* __restrict__ bih, const float* __restrict__ bhh,
                            float* __restrict__ dest, int M){
  __shared__ unsigned sW[6][32*66];
  __shared__ float sA[8][132], sX[8][132];
  __shared__ float sbi[3][32], sbh[3][32];
  int c0 = blockIdx.y*32;
  for (int i=threadIdx.x; i<6*32*64; i+=256){
    int m=i>>11, r=i&2047, c=r>>6, k2=r&63;
    const float* base = (m<3)? Wih : Whh;
    int g = (m<3)? m : m-3;
    const float* wp = base + ((size_t)(g*128 + c0 + c))*128 + 2*k2;
    sW[m][c*66 + k2] = f2b_bits(wp[0]) | (f2b_bits(wp[1])<<16);
  }
  if (threadIdx.x < 96){
    int g=threadIdx.x>>5, c=threadIdx.x&31;
    sbi[g][c]=bih[g*128+c0+c]; sbh[g][c]=bhh[g*128+c0+c];
  }
  __syncthreads();
  int sub=threadIdx.x>>5, c=threadIdx.x&31;
  for (long r0=(long)blockIdx.x*8; r0<M; r0+=(long)gridDim.x*8){
    __syncthreads();
    for (int i=threadIdx.x;i<8*16;i+=256){
      int rr=i>>4, q=i&15; long row=r0+rr;
      if (row<M){
        *(float4*)&sA[rr][q*8]   = *(const float4*)(A+row*128+q*8);
        *(float4*)&sA[rr][q*8+4] = *(const float4*)(A+row*128+q*8+4);
        *(float4*)&sX[rr][q*8]   = *(const float4*)(X+row*128+q*8);
        *(float4*)&sX[rr][q*8+4] = *(const float4*)(X+row*128+q*8+4);
      } else {
        float4 z=make_float4(0,0,0,0);
        *(float4*)&sA[rr][q*8]=z; *(float4*)&sA[rr][q*8+4]=z;
        *(float4*)&sX[rr][q*8]=z; *(float4*)&sX[rr][q*8+4]=z;
      }
    }
    __syncthreads();
    long row=r0+sub;
    if (row<M){
      const unsigned* wri=&sW[0][c*66]; const unsigned* wzi=&sW[1][c*66]; const unsigned* wni=&sW[2][c*66];
      const unsigned* wrh=&sW[3][c*66]; const unsigned* wzh=&sW[4][c*66]; const unsigned* wnh=&sW[5][c*66];
      const float2* xa=(const float2*)sA[sub]; const float2* xb=(const float2*)sX[sub];
      float ari=0,azi=0,ani=0,arh=0,azh=0,anh=0;
      #pragma unroll 8
      for (int k2=0;k2<64;k2++){
        float2 av=xa[k2], bv=xb[k2];
        unsigned u;
        u=wri[k2]; ari += av.x*__uint_as_float(u<<16) + av.y*__uint_as_float(u&0xffff0000u);
        u=wzi[k2]; azi += av.x*__uint_as_float(u<<16) + av.y*__uint_as_float(u&0xffff0000u);
        u=wni[k2]; ani += av.x*__uint_as_float(u<<16) + av.y*__uint_as_float(u&0xffff0000u);
        u=wrh[k2]; arh += bv.x*__uint_as_float(u<<16) + bv.y*__uint_as_float(u&0xffff0000u);
        u=wzh[k2]; azh += bv.x*__uint_as_float(u<<16) + bv.y*__uint_as_float(u&0xffff0000u);
        u=wnh[k2]; anh += bv.x*__uint_as_float(u<<16) + bv.y*__uint_as_float(u&0xffff0000u);
      }
      float rg = sigmoid_f(ari+arh+sbi[0][c]+sbh[0][c]);
      float zg = sigmoid_f(azi+azh+sbi[1][c]+sbh[1][c]);
      float nn = tanh_f(ani+sbi[2][c] + rg*(anh+sbh[2][c]));
      float xv = sX[sub][c0+c];
      float o  = (1.f-zg)*nn + zg*xv;
      dest[row*128+c0+c] = fmaxf(o,0.f);
    }
  }
}

// ---------------- row dot(s) ----------------
template<typename TY>
__global__ void rowdot_k(const TY* __restrict__ Y, const float* __restrict__ v,
                         float* __restrict__ d, int M){
  __shared__ float sv[128];
  if (threadIdx.x<128) sv[threadIdx.x]=v[threadIdx.x];
  __syncthreads();
  int wv=threadIdx.x>>6, lane=threadIdx.x&63;
  long row=(long)blockIdx.x*4+wv;
  if (row>=M) return;
  float a=to_float(Y[row*128+lane])*sv[lane]+to_float(Y[row*128+64+lane])*sv[64+lane];
  #pragma unroll
  for (int o=32;o;o>>=1) a+=__shfl_xor(a,o);
  if (!lane) d[row]=a;
}

__global__ void rowdot2_k(const bf16* __restrict__ Y, const float* __restrict__ v1,
                          const float* __restrict__ v2, float* __restrict__ d1,
                          float* __restrict__ d2, int M){
  __shared__ float sv1[128], sv2[128];
  if (threadIdx.x<128){ sv1[threadIdx.x]=v1[threadIdx.x]; sv2[threadIdx.x]=v2[threadIdx.x]; }
  __syncthreads();
  int wv=threadIdx.x>>6, lane=threadIdx.x&63;
  long row=(long)blockIdx.x*4+wv;
  if (row>=M) return;
  float x0=b2f(Y[row*128+lane]), x1=b2f(Y[row*128+64+lane]);
  float a=x0*sv1[lane]+x1*sv1[64+lane];
  float b=x0*sv2[lane]+x1*sv2[64+lane];
  #pragma unroll
  for (int o=32;o;o>>=1){ a+=__shfl_xor(a,o); b+=__shfl_xor(b,o); }
  if (!lane){ d1[row]=a; d2[row]=b; }
}

// ---------------- GATE edge logits ----------------
__global__ __launch_bounds__(256) void gate_edge_logits_k(const bf16* __restrict__ u, const float* __restrict__ ea,
                                   const float* __restrict__ gW1, const float* __restrict__ att_l,
                                   const float* __restrict__ ddst, const int* __restrict__ src,
                                   const int* __restrict__ dst, float* __restrict__ elog, int E){
  __shared__ float sWb[10][128];
  __shared__ float sal[128];
  for (int i=threadIdx.x;i<10*128;i+=256){ int k=i>>7,c=i&127; sWb[k][c]=gW1[(size_t)c*138+128+k]; }
  if (threadIdx.x<128) sal[threadIdx.x]=att_l[threadIdx.x];
  __syncthreads();
  int wv=threadIdx.x>>6, lane=threadIdx.x&63;
  for (long e=(long)blockIdx.x*4+wv; e<E; e+=(long)gridDim.x*4){
    int sj=src[e], di=dst[e];
    float eal[10];
    #pragma unroll
    for (int k=0;k<10;k++) eal[k]=ea[(size_t)e*10+k];
    float acc=0.f;
    #pragma unroll
    for (int j=0;j<2;j++){
      int cc=lane+64*j;
      float v=0.f;
      #pragma unroll
      for (int k=0;k<10;k++) v+=eal[k]*sWb[k][cc];
      v+=b2f(u[(size_t)sj*128+cc]);
      acc+=lrelu_f(v)*sal[cc];
    }
    #pragma unroll
    for (int o=32;o;o>>=1) acc+=__shfl_xor(acc,o);
    if (!lane) elog[e]=lrelu_f(acc+ddst[di]);
  }
}

// ---------------- conv edge logits ----------------
__global__ void conv_logit_k(const float* __restrict__ dsrc, const float* __restrict__ ddst,
                             const int* __restrict__ src, const int* __restrict__ dst,
                             float* __restrict__ elog, int n){
  int e=blockIdx.x*256+threadIdx.x; if (e<n) elog[e]=lrelu_f(dsrc[src[e]]+ddst[dst[e]]);
}

// ------- per-node softmax over incoming edges + weighted sum; ACT1 = relu(S+bias)
template<int ACT>
__global__ void node_gather_k(const float* __restrict__ elog, const int* __restrict__ eids,
                              const int* __restrict__ ptr, const int* __restrict__ src,
                              const bf16* __restrict__ V, const float* __restrict__ bias,
                              bf16* __restrict__ S, int M){
  int wv=threadIdx.x>>6, lane=threadIdx.x&63;
  int node=blockIdx.x*4+wv; if (node>=M) return;
  int p0=ptr[node], p1=ptr[node+1];
  float m=-INFINITY;
  for (int p=p0+lane;p<p1;p+=64) m=fmaxf(m,elog[eids[p]]);
  #pragma unroll
  for (int o=32;o;o>>=1) m=fmaxf(m,__shfl_xor(m,o));
  float ssum=0.f;
  for (int p=p0+lane;p<p1;p+=64) ssum+=__expf(elog[eids[p]]-m);
  #pragma unroll
  for (int o=32;o;o>>=1) ssum+=__shfl_xor(ssum,o);
  float inv=1.f/(ssum+1e-16f);
  float a0=0.f,a1=0.f;
  for (int p=p0;p<p1;p++){
    int e=eids[p];
    float al=__expf(elog[e]-m)*inv;
    const bf16* vr=&V[(size_t)src[e]*128];
    a0+=al*b2f(vr[lane]); a1+=al*b2f(vr[64+lane]);
  }
  if (ACT==1){
    a0=fmaxf(a0+bias[lane],0.f); a1=fmaxf(a1+bias[64+lane],0.f);
  }
  S[(size_t)node*128+lane]=f2b(a0); S[(size_t)node*128+64+lane]=f2b(a1);
}

// ---------------- molecule kernels ----------------
__global__ void mol_ptr_k(const int* __restrict__ batch, int* __restrict__ mptr, int n, int Bn){
  int b=blockIdx.x*256+threadIdx.x; if (b>Bn) return;
  if (b==Bn){ mptr[Bn]=n; return; }
  int lo=0, hi=n;
  while (lo<hi){ int mid=(lo+hi)>>1; if (batch[mid]<b) lo=mid+1; else hi=mid; }
  mptr[b]=lo;
}

__global__ void mol_sum_k(const bf16* __restrict__ x, const int* __restrict__ mptr,
                          float* __restrict__ out, int Bn){
  int wv=threadIdx.x>>6, lane=threadIdx.x&63;
  int b=blockIdx.x*4+wv; if (b>=Bn) return;
  int p0=mptr[b], p1=mptr[b+1];
  float a0=0.f,a1=0.f;
  for (int i=p0;i<p1;i++){ a0+=b2f(x[(size_t)i*128+lane]); a1+=b2f(x[(size_t)i*128+64+lane]); }
  out[(size_t)b*128+lane]=fmaxf(a0,0.f); out[(size_t)b*128+64+lane]=fmaxf(a1,0.f);
}

__global__ void fold_att_k(const float* __restrict__ W, const float* __restrict__ att,
                           float* __restrict__ wdd){
  int k=threadIdx.x; float a=0.f;
  for (int c=0;c<128;c++) a+=att[c]*W[(size_t)c*128+k];
  wdd[k]=a;
}

__global__ void mol_logit_k(const float* __restrict__ dsrc, const float* __restrict__ dd,
                            const int* __restrict__ batch, float* __restrict__ alog, int n){
  int i=blockIdx.x*256+threadIdx.x; if (i<n) alog[i]=lrelu_f(dsrc[i]+dd[batch[i]]);
}

__global__ void mol_gather_k(const float* __restrict__ alog, const int* __restrict__ mptr,
                             const bf16* __restrict__ xs, const float* __restrict__ bias,
                             float* __restrict__ hb, int Bn){
  int wv=threadIdx.x>>6, lane=threadIdx.x&63;
  int b=blockIdx.x*4+wv; if (b>=Bn) return;
  int p0=mptr[b], p1=mptr[b+1];
  float m=-INFINITY;
  for (int i=p0+lane;i<p1;i+=64) m=fmaxf(m,alog[i]);
  #pragma unroll
  for (int o=32;o;o>>=1) m=fmaxf(m,__shfl_xor(m,o));
  float ssum=0.f;
  for (int i=p0+lane;i<p1;i+=64) ssum+=__expf(alog[i]-m);
  #pragma unroll
  for (int o=32;o;o>>=1) ssum+=__shfl_xor(ssum,o);
  float inv=1.f/(ssum+1e-16f);
  float a0=0.f,a1=0.f;
  for (int i=p0;i<p1;i++){
    float al=__expf(alog[i]-m)*inv;
    a0+=al*b2f(xs[(size_t)i*128+lane]); a1+=al*b2f(xs[(size_t)i*128+64+lane]);
  }
  hb[(size_t)b*128+lane]=elu_f(a0+bias[lane]);
  hb[(size_t)b*128+64+lane]=elu_f(a1+bias[64+lane]);
}

// ---------------- final head ----------------
__global__ void final_head_k(const float* __restrict__ out, const float* __restrict__ W2,
                             const float* __restrict__ b2, const float* __restrict__ Wh,
                             const float* __restrict__ bh, float* __restrict__ y, int Bn){
  __shared__ float srow[128]; __shared__ float sred[128];
  int b=blockIdx.x, c=threadIdx.x;
  srow[c]=out[(size_t)b*128+c]; __syncthreads();
  float acc=b2[c];
  const float* wr=&W2[(size_t)c*128];
  #pragma unroll 8
  for (int k=0;k<128;k++) acc+=srow[k]*wr[k];
  sred[c]=acc*Wh[c]; __syncthreads();
  for (int o=64;o;o>>=1){ if (c<o) sred[c]+=sred[c+o]; __syncthreads(); }
  if (c==0) y[b]=sred[0]+bh[0];
}

// ---------------- CSR build ----------------
__global__ void zero_i32_k(int* p, int n){ int i=blockIdx.x*256+threadIdx.x; if (i<n) p[i]=0; }
__global__ void hist_k(const int* __restrict__ dst, int* __restrict__ deg, int n){
  int e=blockIdx.x*256+threadIdx.x; if (e<n) atomicAdd(&deg[dst[e]],1);
}
__global__ void scan1_k(const int* __restrict__ deg, int* __restrict__ ptr,
                        int* __restrict__ part, int n){
  __shared__ int sd[256];
  int base=blockIdx.x*1024, tid=threadIdx.x;
  int v[4]; int ssum=0;
  #pragma unroll
  for (int j=0;j<4;j++){ int idx=base+tid*4+j; v[j]= idx<n? deg[idx]:0; ssum+=v[j]; }
  sd[tid]=ssum; __syncthreads();
  for (int o=1;o<256;o<<=1){ int t = tid>=o? sd[tid-o]:0; __syncthreads(); sd[tid]+=t; __syncthreads(); }
  int excl=sd[tid]-ssum;
  #pragma unroll
  for (int j=0;j<4;j++){ int idx=base+tid*4+j; if (idx<n) ptr[idx]=excl; excl+=v[j]; }
  if (tid==255) part[blockIdx.x]=sd[255];
}
__global__ void scan2_k(int* part, int nb){
  __shared__ int sd[512];
  int tid=threadIdx.x;
  int v= tid<nb? part[tid]:0; sd[tid]=v; __syncthreads();
  for (int o=1;o<512;o<<=1){ int t = tid>=o? sd[tid-o]:0; __syncthreads(); sd[tid]+=t; __syncthreads(); }
  if (tid<nb) part[tid]=sd[tid]-v;
}
__global__ void scan3_k(int* __restrict__ ptr, const int* __restrict__ part,
                        int* __restrict__ wofs, int n, int total){
  int i=blockIdx.x*256+threadIdx.x;
  if (i<n){ int val=ptr[i]+part[i>>10]; ptr[i]=val; wofs[i]=val; }
  if (i==0) ptr[n]=total;
}
__global__ void fill_csr_k(const int* __restrict__ dst, int* __restrict__ wofs,
                           int* __restrict__ eids, int n){
  int e=blockIdx.x*256+threadIdx.x;
  if (e<n){ int p=atomicAdd(&wofs[dst[e]],1); eids[p]=e; }
}

// =====================================================================
extern "C" void kernel_launch(void* const* d_in, const int* in_sizes, int n_in,
                              void* d_out, int out_size, void* d_ws, size_t ws_size,
                              hipStream_t stream){
  (void)in_sizes; (void)n_in; (void)out_size; (void)ws_size;
  const float* x0        =(const float*)d_in[0];
  const float* edge_attr =(const float*)d_in[1];
  const float* W_lin1    =(const float*)d_in[2];
  const float* b_lin1    =(const float*)d_in[3];
  const float* gate_W1   =(const float*)d_in[4];
  const float* gate_W2   =(const float*)d_in[5];
  const float* gate_att_l=(const float*)d_in[6];
  const float* gate_att_r=(const float*)d_in[7];
  const float* gate_bias =(const float*)d_in[8];
  const float* g1_Wih=(const float*)d_in[9];  const float* g1_Whh=(const float*)d_in[10];
  const float* g1_bih=(const float*)d_in[11]; const float* g1_bhh=(const float*)d_in[12];
  const float* conv_W=(const float*)d_in[13];
  const float* conv_att_src=(const float*)d_in[14];
  const float* conv_att_dst=(const float*)d_in[15];
  const float* conv_bias   =(const float*)d_in[16];
  const float* g2_Wih=(const float*)d_in[17]; const float* g2_Whh=(const float*)d_in[18];
  const float* g2_bih=(const float*)d_in[19]; const float* g2_bhh=(const float*)d_in[20];
  const float* mol_W=(const float*)d_in[21];
  const float* mol_att_src=(const float*)d_in[22];
  const float* mol_att_dst=(const float*)d_in[23];
  const float* mol_bias   =(const float*)d_in[24];
  const float* gm_Wih=(const float*)d_in[25]; const float* gm_Whh=(const float*)d_in[26];
  const float* gm_bih=(const float*)d_in[27]; const float* gm_bhh=(const float*)d_in[28];
  const float* W_lin2=(const float*)d_in[29]; const float* b_lin2=(const float*)d_in[30];
  const float* W_head=(const float*)d_in[31]; const float* b_head=(const float*)d_in[32];
  const int* ei   =(const int*)d_in[33];
  const int* batch=(const int*)d_in[34];
  const int* src=ei; const int* dst=ei+E_;
  float* y=(float*)d_out;

  // ---- workspace layout (~218 MiB total) ----
  const size_t NH=(size_t)N_*H_, BH=(size_t)B_*H_;
  bf16* b0  =(bf16*)d_ws;           // N*H bf16
  bf16* b1  =b0+NH;                 // N*H bf16
  bf16* b2v =b1+NH;                 // N*H bf16
  float* outA=(float*)(b2v+NH);     // B*H fp32
  float* outB=outA+BH;
  float* hb  =outB+BH;
  float* elog=hb+BH;                // E
  float* dsrc=elog+E_;              // N
  float* ddst=dsrc+N_;              // N
  float* alog=ddst+N_;              // N
  float* wdd =alog+N_;              // 128
  float* dd  =wdd+128;              // B
  int* deg =(int*)(dd+B_);          // N
  int* ptr =deg+N_;                 // N+1
  int* wofs=ptr+N_+1;               // N
  int* eids=wofs+N_;                // E
  int* part=eids+E_;                // 512
  int* mptr=part+512;               // B+1
  uintptr_t wbase=((uintptr_t)(mptr+B_+1)+255)&~(uintptr_t)255;
  bf16* wb_gw1 =(bf16*)wbase;        // 128*128
  bf16* wb_gw2 =wb_gw1 +128*128;
  bf16* wb_conv=wb_gw2 +128*128;
  bf16* wb_mol =wb_conv+128*128;
  bf16* wb_g1i =wb_mol +128*128;     // 384*128
  bf16* wb_g1h =wb_g1i +384*128;
  bf16* wb_g2i =wb_g1h +384*128;
  bf16* wb_g2h =wb_g2i +384*128;

  // ---- weight conversions ----
  w2b_k<<<64,256,0,stream>>>(gate_W1,138,wb_gw1,128);
  w2b_k<<<64,256,0,stream>>>(gate_W2,128,wb_gw2,128);
  w2b_k<<<64,256,0,stream>>>(conv_W ,128,wb_conv,128);
  w2b_k<<<64,256,0,stream>>>(mol_W  ,128,wb_mol ,128);
  w2b_k<<<192,256,0,stream>>>(g1_Wih,128,wb_g1i,384);
  w2b_k<<<192,256,0,stream>>>(g1_Whh,128,wb_g1h,384);
  w2b_k<<<192,256,0,stream>>>(g2_Wih,128,wb_g2i,384);
  w2b_k<<<192,256,0,stream>>>(g2_Whh,128,wb_g2h,384);

  // ---- CSR by dst + molecule ranges ----
  zero_i32_k<<<(N_+255)/256,256,0,stream>>>(deg,N_);
  hist_k<<<(E_+255)/256,256,0,stream>>>(dst,deg,E_);
  int nb=(N_+1023)/1024;
  scan1_k<<<nb,256,0,stream>>>(deg,ptr,part,N_);
  scan2_k<<<1,512,0,stream>>>(part,nb);
  scan3_k<<<(N_+255)/256,256,0,stream>>>(ptr,part,wofs,N_,E_);
  fill_csr_k<<<(E_+255)/256,256,0,stream>>>(dst,wofs,eids,E_);
  mol_ptr_k<<<(B_+1+255)/256,256,0,stream>>>(batch,mptr,N_,B_);

  // ---- lin1: X -> b0 ----
  lin1_k<<<4096,256,0,stream>>>(x0,W_lin1,b_lin1,b0,N_);

  const int GL=768, GG=512;
  // ---- GATEConv ----
  lin_mfma_k<0><<<GL,256,0,stream>>>(b0,wb_gw1,nullptr,b1,N_);             // u -> b1
  rowdot_k<bf16><<<(N_+3)/4,256,0,stream>>>(b0,gate_att_r,ddst,N_);
  gate_edge_logits_k<<<4096,256,0,stream>>>(b1,edge_attr,gate_W1,gate_att_l,ddst,src,dst,elog,E_);
  node_gather_k<0><<<(N_+3)/4,256,0,stream>>>(elog,eids,ptr,src,b0,nullptr,b2v,N_);  // S -> b2
  lin_mfma_k<2><<<GL,256,0,stream>>>(b2v,wb_gw2,gate_bias,b1,N_);          // h=elu -> b1
  // ---- GRU1: x=relu(gru(h=b1, x=b0)) -> b2 ----
  gru_mfma_k<<<GG,256,0,stream>>>(b1,b0,wb_g1i,wb_g1h,g1_bih,g1_bhh,b2v,N_);
  // ---- atom GATConv (x lives in b2) ----
  lin_mfma_k<0><<<GL,256,0,stream>>>(b2v,wb_conv,nullptr,b0,N_);           // xl -> b0
  rowdot2_k<<<(N_+3)/4,256,0,stream>>>(b0,conv_att_src,conv_att_dst,dsrc,ddst,N_);
  conv_logit_k<<<(E_+255)/256,256,0,stream>>>(dsrc,ddst,src,dst,elog,E_);
  node_gather_k<1><<<(N_+3)/4,256,0,stream>>>(elog,eids,ptr,src,b0,conv_bias,b1,N_); // h=relu(S+bias) -> b1
  // ---- GRU2: x=relu(gru(h=b1, x=b2)) -> b0 ----
  gru_mfma_k<<<GG,256,0,stream>>>(b1,b2v,wb_g2i,wb_g2h,g2_bih,g2_bhh,b0,N_);
  // ---- readout (x lives in b0) ----
  mol_sum_k<<<(B_+3)/4,256,0,stream>>>(b0,mptr,outA,B_);
  lin_mfma_k<0><<<GL,256,0,stream>>>(b0,wb_mol,nullptr,b1,N_);             // xs -> b1
  rowdot_k<bf16><<<(N_+3)/4,256,0,stream>>>(b1,mol_att_src,dsrc,N_);
  fold_att_k<<<1,128,0,stream>>>(mol_W,mol_att_dst,wdd);
  float* out_cur=outA; float* out_nxt=outB;
  dim3 gm(157,4);
  for (int ts=0; ts<2; ts++){
    rowdot_k<float><<<(B_+3)/4,256,0,stream>>>(out_cur,wdd,dd,B_);
    mol_logit_k<<<(N_+255)/256,256,0,stream>>>(dsrc,dd,batch,alog,N_);
    mol_gather_k<<<(B_+3)/4,256,0,stream>>>(alog,mptr,b1,mol_bias,hb,B_);
    gru_scalar_k<<<gm,256,0,stream>>>(hb,out_cur,gm_Wih,gm_Whh,gm_bih,gm_bhh,out_nxt,B_);
    float* tmp=out_cur; out_cur=out_nxt; out_nxt=tmp;
  }
  final_head_k<<<B_,128,0,stream>>>(out_cur,W_lin2,b_lin2,W_head,b_head,y,B_);
}

// Round 6
// 1724.809 us; speedup vs baseline: 3.4365x; 1.0070x over previous
//
#include <hip/hip_runtime.h>
#include <hip/hip_bf16.h>
#include <type_traits>

typedef __hip_bfloat16 bf16;

constexpr int N_  = 250000;
constexpr int E_  = 500000;
constexpr int B_  = 10000;
constexpr int H_  = 128;

typedef short s8v __attribute__((ext_vector_type(8)));   // 8 bf16 in 4 VGPRs
typedef float f4v __attribute__((ext_vector_type(4)));

__device__ __forceinline__ float b2f(bf16 v){ return __bfloat162float(v); }
__device__ __forceinline__ bf16  f2b(float v){ return __float2bfloat16(v); }
__device__ __forceinline__ float to_float(float v){ return v; }
__device__ __forceinline__ float to_float(bf16 v){ return __bfloat162float(v); }
__device__ __forceinline__ float lrelu_f(float v){ return v > 0.f ? v : 0.01f*v; }
__device__ __forceinline__ float sigmoid_f(float x){ return __builtin_amdgcn_rcpf(1.f+__expf(-x)); }
__device__ __forceinline__ float tanh_f(float x){ return 1.f - 2.f*__builtin_amdgcn_rcpf(__expf(2.f*x)+1.f); }
__device__ __forceinline__ float elu_f(float v){ return v > 0.f ? v : __expf(v)-1.f; }
__device__ __forceinline__ unsigned f2b_bits(float f){
  bf16 h=__float2bfloat16(f); unsigned short s; __builtin_memcpy(&s,&h,2); return (unsigned)s;
}

// ---------------- consolidated fp32->bf16 weight copies (9 segments) -------
struct W2B { const float* s; bf16* d; int rows, ld, ow, cw; };
struct W2B9 { W2B seg[9]; };
__global__ void w2ball_k(W2B9 p){
  W2B g=p.seg[blockIdx.y];
  int i=blockIdx.x*256+threadIdx.x;
  if (i>=g.rows*g.ow) return;
  int r=i/g.ow, k=i-r*g.ow;
  g.d[i] = f2b(k<g.cw ? g.s[(size_t)r*g.ld+k] : 0.f);
}

// ---------------- lin1 via MFMA: [N,39] fp32 -> [N,128] bf16, lrelu --------
// Wb: [128][64] bf16 (cols 39..63 zero). LDS-staged x tile, K=64.
__global__ __launch_bounds__(256) void lin1_mfma_k(const float* __restrict__ X0, const bf16* __restrict__ Wb,
                            const float* __restrict__ bias, bf16* __restrict__ Y, int M){
  __shared__ __align__(16) bf16 sx[64][72];
  int wv=threadIdx.x>>6, lane=threadIdx.x&63;
  int n=lane&15, q=lane>>4;
  int c0=wv*32;
  s8v wB[2][2];
  #pragma unroll
  for (int ct=0;ct<2;ct++)
    #pragma unroll
    for (int kk=0;kk<2;kk++)
      wB[ct][kk]=*(const s8v*)(Wb+(size_t)(c0+ct*16+n)*64+kk*32+q*8);
  float bb[2];
  #pragma unroll
  for (int ct=0;ct<2;ct++) bb[ct]=bias[c0+ct*16+n];
  // zero the K-pad columns once (39..63); they are never overwritten
  for (int i=threadIdx.x;i<64*25;i+=256){ int r=i/25,k=39+(i-(i/25)*25); sx[r][k]=f2b(0.f); }
  for (long r0=(long)blockIdx.x*64; r0<M; r0+=(long)gridDim.x*64){
    __syncthreads();
    for (int f=threadIdx.x; f<64*39; f+=256){
      int r=f/39, k=f-(f/39)*39; long row=r0+r;
      sx[r][k]= f2b(row<M ? X0[row*39+k] : 0.f);
    }
    __syncthreads();
    s8v a[4][2];
    #pragma unroll
    for (int rt=0;rt<4;rt++)
      #pragma unroll
      for (int kk=0;kk<2;kk++)
        a[rt][kk]=*(const s8v*)&sx[rt*16+n][kk*32+q*8];
    f4v acc[4][2];
    #pragma unroll
    for (int rt=0;rt<4;rt++)
      #pragma unroll
      for (int ct=0;ct<2;ct++) acc[rt][ct]=(f4v){0.f,0.f,0.f,0.f};
    #pragma unroll
    for (int kk=0;kk<2;kk++)
      #pragma unroll
      for (int rt=0;rt<4;rt++)
        #pragma unroll
        for (int ct=0;ct<2;ct++)
          acc[rt][ct]=__builtin_amdgcn_mfma_f32_16x16x32_bf16(a[rt][kk],wB[ct][kk],acc[rt][ct],0,0,0);
    #pragma unroll
    for (int ct=0;ct<2;ct++){
      int col=c0+ct*16+n;
      #pragma unroll
      for (int rt=0;rt<4;rt++){
        #pragma unroll
        for (int rg=0;rg<4;rg++){
          long row=r0+rt*16+q*4+rg;
          if (row<M) Y[row*128+col]=f2b(lrelu_f(acc[rt][ct][rg]+bb[ct]));
        }
      }
    }
  }
}

// ---- MFMA linear, weights in registers, grid-stride over 64-row tiles ----
template<int ACT>   // 0 none, 2 elu
__global__ __launch_bounds__(256) void lin_mfma_k(const bf16* __restrict__ X, const bf16* __restrict__ Wb,
                            const float* __restrict__ bias, bf16* __restrict__ Y, int M){
  int wv=threadIdx.x>>6, lane=threadIdx.x&63;
  int n=lane&15, q=lane>>4;
  int c0=wv*32;
  s8v wB[2][4];
  #pragma unroll
  for (int ct=0;ct<2;ct++)
    #pragma unroll
    for (int kk=0;kk<4;kk++)
      wB[ct][kk]=*(const s8v*)(Wb+(size_t)(c0+ct*16+n)*128+kk*32+q*8);
  float bb[2];
  #pragma unroll
  for (int ct=0;ct<2;ct++) bb[ct]=bias? bias[c0+ct*16+n]:0.f;
  for (long r0=(long)blockIdx.x*64; r0<M; r0+=(long)gridDim.x*64){
    s8v a[4][4];
    #pragma unroll
    for (int rt=0;rt<4;rt++){
      long row=r0+rt*16+n; if (row>=M) row=M-1;
      #pragma unroll
      for (int kk=0;kk<4;kk++) a[rt][kk]=*(const s8v*)(X+row*128+kk*32+q*8);
    }
    f4v acc[4][2];
    #pragma unroll
    for (int rt=0;rt<4;rt++)
      #pragma unroll
      for (int ct=0;ct<2;ct++) acc[rt][ct]=(f4v){0.f,0.f,0.f,0.f};
    #pragma unroll
    for (int kk=0;kk<4;kk++)
      #pragma unroll
      for (int rt=0;rt<4;rt++)
        #pragma unroll
        for (int ct=0;ct<2;ct++)
          acc[rt][ct]=__builtin_amdgcn_mfma_f32_16x16x32_bf16(a[rt][kk],wB[ct][kk],acc[rt][ct],0,0,0);
    #pragma unroll
    for (int ct=0;ct<2;ct++){
      int col=c0+ct*16+n;
      #pragma unroll
      for (int rt=0;rt<4;rt++){
        #pragma unroll
        for (int rg=0;rg<4;rg++){
          long row=r0+rt*16+q*4+rg;
          if (row<M){
            float v=acc[rt][ct][rg]+bb[ct];
            if (ACT==2) v=elu_f(v);
            Y[row*128+col]=f2b(v);
          }
        }
      }
    }
  }
}

// ---- MFMA fused GRU (atoms), weights in registers, double-buffered A/X ----
struct Frags { s8v aA[2][4]; s8v aX[2][4]; };

__device__ __forceinline__ void gru_load(const bf16* __restrict__ A, const bf16* __restrict__ X,
                                         long r0, int n, int q, int M, Frags& f){
  #pragma unroll
  for (int rt=0;rt<2;rt++){
    long row=r0+rt*16+n; if (row>=M) row=M-1;
    #pragma unroll
    for (int kk=0;kk<4;kk++){
      f.aA[rt][kk]=*(const s8v*)(A+row*128+kk*32+q*8);
      f.aX[rt][kk]=*(const s8v*)(X+row*128+kk*32+q*8);
    }
  }
}

__device__ __forceinline__ void gru_tile(const Frags& fr,
    const s8v (&wI)[3][2][4], const s8v (&wH)[3][2][4],
    const float (&br)[2], const float (&bz)[2], const float (&bni)[2], const float (&bnh)[2],
    const bf16* __restrict__ A, const bf16* __restrict__ X, bf16* __restrict__ dest,
    long r0, long rnext, int n, int q, int c0, int M, Frags& fnext){
  f4v acc[6][2][2];
  #pragma unroll
  for (int g=0;g<6;g++)
    #pragma unroll
    for (int rt=0;rt<2;rt++)
      #pragma unroll
      for (int ct=0;ct<2;ct++) acc[g][rt][ct]=(f4v){0.f,0.f,0.f,0.f};
  #pragma unroll
  for (int kk=0;kk<4;kk++)
    #pragma unroll
    for (int g=0;g<3;g++)
      #pragma unroll
      for (int ct=0;ct<2;ct++)
        #pragma unroll
        for (int rt=0;rt<2;rt++){
          acc[g  ][rt][ct]=__builtin_amdgcn_mfma_f32_16x16x32_bf16(fr.aA[rt][kk],wI[g][ct][kk],acc[g  ][rt][ct],0,0,0);
          acc[3+g][rt][ct]=__builtin_amdgcn_mfma_f32_16x16x32_bf16(fr.aX[rt][kk],wH[g][ct][kk],acc[3+g][rt][ct],0,0,0);
        }
  if (rnext<M) gru_load(A,X,rnext,n,q,M,fnext);   // prefetch overlaps MFMA drain + epilogue
  #pragma unroll
  for (int ct=0;ct<2;ct++){
    int col=c0+ct*16+n;
    #pragma unroll
    for (int rt=0;rt<2;rt++){
      #pragma unroll
      for (int rg=0;rg<4;rg++){
        long row=r0+rt*16+q*4+rg;
        if (row<M){
          float rgate=sigmoid_f(acc[0][rt][ct][rg]+acc[3][rt][ct][rg]+br[ct]);
          float zgate=sigmoid_f(acc[1][rt][ct][rg]+acc[4][rt][ct][rg]+bz[ct]);
          float nn=tanh_f(acc[2][rt][ct][rg]+bni[ct] + rgate*(acc[5][rt][ct][rg]+bnh[ct]));
          float xv=b2f(X[row*128+col]);
          float o=(1.f-zgate)*nn + zgate*xv;
          dest[row*128+col]=f2b(fmaxf(o,0.f));
        }
      }
    }
  }
}

__global__ __launch_bounds__(256,1) void gru_mfma_k(const bf16* __restrict__ A, const bf16* __restrict__ X,
                            const bf16* __restrict__ Wih, const bf16* __restrict__ Whh,
                            const float* __restrict__ bih, const float* __restrict__ bhh,
                            bf16* __restrict__ dest, int M){
  int wv=threadIdx.x>>6, lane=threadIdx.x&63;
  int n=lane&15, q=lane>>4;
  int c0=wv*32;
  s8v wI[3][2][4], wH[3][2][4];
  #pragma unroll
  for (int g=0;g<3;g++)
    #pragma unroll
    for (int ct=0;ct<2;ct++)
      #pragma unroll
      for (int kk=0;kk<4;kk++){
        size_t off=((size_t)(g*128+c0+ct*16+n))*128+kk*32+q*8;
        wI[g][ct][kk]=*(const s8v*)(Wih+off);
        wH[g][ct][kk]=*(const s8v*)(Whh+off);
      }
  float br[2],bz[2],bni[2],bnh[2];
  #pragma unroll
  for (int ct=0;ct<2;ct++){
    int col=c0+ct*16+n;
    br[ct]=bih[col]+bhh[col];
    bz[ct]=bih[128+col]+bhh[128+col];
    bni[ct]=bih[256+col]; bnh[ct]=bhh[256+col];
  }
  long step=(long)gridDim.x*32;
  long r=(long)blockIdx.x*32;
  Frags f0,f1;
  if (r<M) gru_load(A,X,r,n,q,M,f0);
  while (r<M){
    gru_tile(f0,wI,wH,br,bz,bni,bnh,A,X,dest,r,r+step,n,q,c0,M,f1);
    r+=step; if (r>=M) break;
    gru_tile(f1,wI,wH,br,bz,bni,bnh,A,X,dest,r,r+step,n,q,c0,M,f0);
    r+=step;
  }
}

// ------- scalar fused GRU (molecules, fp32 state) ----
__global__ __launch_bounds__(256) void gru_scalar_k(const float* __restrict__ A, const float* __restrict__ X,
                            const float* __restrict__ Wih, const float* __restrict__ Whh,
                            const float* __restrict__ bih, const float* __restrict__ bhh,
                            float* __restrict__ dest, int M){
  __shared__ unsigned sW[6][32*66];
  __shared__ float sA[8][132], sX[8][132];
  __shared__ float sbi[3][32], sbh[3][32];
  int c0 = blockIdx.y*32;
  for (int i=threadIdx.x; i<6*32*64; i+=256){
    int m=i>>11, r=i&2047, c=r>>6, k2=r&63;
    const float* base = (m<3)? Wih : Whh;
    int g = (m<3)? m : m-3;
    const float* wp = base + ((size_t)(g*128 + c0 + c))*128 + 2*k2;
    sW[m][c*66 + k2] = f2b_bits(wp[0]) | (f2b_bits(wp[1])<<16);
  }
  if (threadIdx.x < 96){
    int g=threadIdx.x>>5, c=threadIdx.x&31;
    sbi[g][c]=bih[g*128+c0+c]; sbh[g][c]=bhh[g*128+c0+c];
  }
  __syncthreads();
  int sub=threadIdx.x>>5, c=threadIdx.x&31;
  for (long r0=(long)blockIdx.x*8; r0<M; r0+=(long)gridDim.x*8){
    __syncthreads();
    for (int i=threadIdx.x;i<8*16;i+=256){
      int rr=i>>4, q=i&15; long row=r0+rr;
      if (row<M){
        *(float4*)&sA[rr][q*8]   = *(const float4*)(A+row*128+q*8);
        *(float4*)&sA[rr][q*8+4] = *(const float4*)(A+row*128+q*8+4);
        *(float4*)&sX[rr][q*8]   = *(const float4*)(X+row*128+q*8);
        *(float4*)&sX[rr][q*8+4] = *(const float4*)(X+row*128+q*8+4);
      } else {
        float4 z=make_float4(0,0,0,0);
        *(float4*)&sA[rr][q*8]=z; *(float4*)&sA[rr][q*8+4]=z;
        *(float4*)&sX[rr][q*8]=z; *(float4*)&sX[rr][q*8+4]=z;
      }
    }
    __syncthreads();
    long row=r0+sub;
    if (row<M){
      const unsigned* wri=&sW[0][c*66]; const unsigned* wzi=&sW[1][c*66]; const unsigned* wni=&sW[2][c*66];
      const unsigned* wrh=&sW[3][c*66]; const unsigned* wzh=&sW[4][c*66]; const unsigned* wnh=&sW[5][c*66];
      const float2* xa=(const float2*)sA[sub]; const float2* xb=(const float2*)sX[sub];
      float ari=0,azi=0,ani=0,arh=0,azh=0,anh=0;
      #pragma unroll 8
      for (int k2=0;k2<64;k2++){
        float2 av=xa[k2], bv=xb[k2];
        unsigned u;
        u=wri[k2]; ari += av.x*__uint_as_float(u<<16) + av.y*__uint_as_float(u&0xffff0000u);
        u=wzi[k2]; azi += av.x*__uint_as_float(u<<16) + av.y*__uint_as_float(u&0xffff0000u);
        u=wni[k2]; ani += av.x*__uint_as_float(u<<16) + av.y*__uint_as_float(u&0xffff0000u);
        u=wrh[k2]; arh += bv.x*__uint_as_float(u<<16) + bv.y*__uint_as_float(u&0xffff0000u);
        u=wzh[k2]; azh += bv.x*__uint_as_float(u<<16) + bv.y*__uint_as_float(u&0xffff0000u);
        u=wnh[k2]; anh += bv.x*__uint_as_float(u<<16) + bv.y*__uint_as_float(u&0xffff0000u);
      }
      float rg = sigmoid_f(ari+arh+sbi[0][c]+sbh[0][c]);
      float zg = sigmoid_f(azi+azh+sbi[1][c]+sbh[1][c]);
      float nn = tanh_f(ani+sbi[2][c] + rg*(anh+sbh[2][c]));
      float xv = sX[sub][c0+c];
      float o  = (1.f-zg)*nn + zg*xv;
      dest[row*128+c0+c] = fmaxf(o,0.f);
    }
  }
}

// ---------------- row dot(s) ----------------
template<typename TY>
__global__ void rowdot_k(const TY* __restrict__ Y, const float* __restrict__ v,
                         float* __restrict__ d, int M){
  __shared__ float sv[128];
  if (threadIdx.x<128) sv[threadIdx.x]=v[threadIdx.x];
  __syncthreads();
  int wv=threadIdx.x>>6, lane=threadIdx.x&63;
  long row=(long)blockIdx.x*4+wv;
  if (row>=M) return;
  float a=to_float(Y[row*128+lane])*sv[lane]+to_float(Y[row*128+64+lane])*sv[64+lane];
  #pragma unroll
  for (int o=32;o;o>>=1) a+=__shfl_xor(a,o);
  if (!lane) d[row]=a;
}

__global__ void rowdot2_k(const bf16* __restrict__ Y, const float* __restrict__ v1,
                          const float* __restrict__ v2, float* __restrict__ d1,
                          float* __restrict__ d2, int M){
  __shared__ float sv1[128], sv2[128];
  if (threadIdx.x<128){ sv1[threadIdx.x]=v1[threadIdx.x]; sv2[threadIdx.x]=v2[threadIdx.x]; }
  __syncthreads();
  int wv=threadIdx.x>>6, lane=threadIdx.x&63;
  long row=(long)blockIdx.x*4+wv;
  if (row>=M) return;
  float x0=b2f(Y[row*128+lane]), x1=b2f(Y[row*128+64+lane]);
  float a=x0*sv1[lane]+x1*sv1[64+lane];
  float b=x0*sv2[lane]+x1*sv2[64+lane];
  #pragma unroll
  for (int o=32;o;o>>=1){ a+=__shfl_xor(a,o); b+=__shfl_xor(b,o); }
  if (!lane){ d1[row]=a; d2[row]=b; }
}

// ---------------- GATE edge logits ----------------
__global__ __launch_bounds__(256) void gate_edge_logits_k(const bf16* __restrict__ u, const float* __restrict__ ea,
                                   const float* __restrict__ gW1, const float* __restrict__ att_l,
                                   const float* __restrict__ ddst, const int* __restrict__ src,
                                   const int* __restrict__ dst, float* __restrict__ elog, int E){
  __shared__ float sWb[10][128];
  __shared__ float sal[128];
  for (int i=threadIdx.x;i<10*128;i+=256){ int k=i>>7,c=i&127; sWb[k][c]=gW1[(size_t)c*138+128+k]; }
  if (threadIdx.x<128) sal[threadIdx.x]=att_l[threadIdx.x];
  __syncthreads();
  int wv=threadIdx.x>>6, lane=threadIdx.x&63;
  for (long e=(long)blockIdx.x*4+wv; e<E; e+=(long)gridDim.x*4){
    int sj=src[e], di=dst[e];
    float eal[10];
    #pragma unroll
    for (int k=0;k<10;k++) eal[k]=ea[(size_t)e*10+k];
    float acc=0.f;
    #pragma unroll
    for (int j=0;j<2;j++){
      int cc=lane+64*j;
      float v=0.f;
      #pragma unroll
      for (int k=0;k<10;k++) v+=eal[k]*sWb[k][cc];
      v+=b2f(u[(size_t)sj*128+cc]);
      acc+=lrelu_f(v)*sal[cc];
    }
    #pragma unroll
    for (int o=32;o;o>>=1) acc+=__shfl_xor(acc,o);
    if (!lane) elog[e]=lrelu_f(acc+ddst[di]);
  }
}

// ---------------- conv edge logits ----------------
__global__ void conv_logit_k(const float* __restrict__ dsrc, const float* __restrict__ ddst,
                             const int* __restrict__ src, const int* __restrict__ dst,
                             float* __restrict__ elog, int n){
  int e=blockIdx.x*256+threadIdx.x; if (e<n) elog[e]=lrelu_f(dsrc[src[e]]+ddst[dst[e]]);
}

// ------- per-node softmax over incoming edges + weighted sum; ACT1 = relu(S+bias)
template<int ACT>
__global__ void node_gather_k(const float* __restrict__ elog, const int* __restrict__ eids,
                              const int* __restrict__ ptr, const int* __restrict__ src,
                              const bf16* __restrict__ V, const float* __restrict__ bias,
                              bf16* __restrict__ S, int M){
  int wv=threadIdx.x>>6, lane=threadIdx.x&63;
  int node=blockIdx.x*4+wv; if (node>=M) return;
  int p0=ptr[node], p1=ptr[node+1];
  float m=-INFINITY;
  for (int p=p0+lane;p<p1;p+=64) m=fmaxf(m,elog[eids[p]]);
  #pragma unroll
  for (int o=32;o;o>>=1) m=fmaxf(m,__shfl_xor(m,o));
  float ssum=0.f;
  for (int p=p0+lane;p<p1;p+=64) ssum+=__expf(elog[eids[p]]-m);
  #pragma unroll
  for (int o=32;o;o>>=1) ssum+=__shfl_xor(ssum,o);
  float inv=1.f/(ssum+1e-16f);
  float a0=0.f,a1=0.f;
  for (int p=p0;p<p1;p++){
    int e=eids[p];
    float al=__expf(elog[e]-m)*inv;
    const bf16* vr=&V[(size_t)src[e]*128];
    a0+=al*b2f(vr[lane]); a1+=al*b2f(vr[64+lane]);
  }
  if (ACT==1){
    a0=fmaxf(a0+bias[lane],0.f); a1=fmaxf(a1+bias[64+lane],0.f);
  }
  S[(size_t)node*128+lane]=f2b(a0); S[(size_t)node*128+64+lane]=f2b(a1);
}

// ---------------- molecule kernels ----------------
__global__ void mol_ptr_k(const int* __restrict__ batch, int* __restrict__ mptr, int n, int Bn){
  int b=blockIdx.x*256+threadIdx.x; if (b>Bn) return;
  if (b==Bn){ mptr[Bn]=n; return; }
  int lo=0, hi=n;
  while (lo<hi){ int mid=(lo+hi)>>1; if (batch[mid]<b) lo=mid+1; else hi=mid; }
  mptr[b]=lo;
}

__global__ void mol_sum_k(const bf16* __restrict__ x, const int* __restrict__ mptr,
                          float* __restrict__ out, int Bn){
  int wv=threadIdx.x>>6, lane=threadIdx.x&63;
  int b=blockIdx.x*4+wv; if (b>=Bn) return;
  int p0=mptr[b], p1=mptr[b+1];
  float a0=0.f,a1=0.f;
  for (int i=p0;i<p1;i++){ a0+=b2f(x[(size_t)i*128+lane]); a1+=b2f(x[(size_t)i*128+64+lane]); }
  out[(size_t)b*128+lane]=fmaxf(a0,0.f); out[(size_t)b*128+64+lane]=fmaxf(a1,0.f);
}

__global__ void fold_att_k(const float* __restrict__ W, const float* __restrict__ att,
                           float* __restrict__ wdd){
  int k=threadIdx.x; float a=0.f;
  for (int c=0;c<128;c++) a+=att[c]*W[(size_t)c*128+k];
  wdd[k]=a;
}

__global__ void mol_logit_k(const float* __restrict__ dsrc, const float* __restrict__ dd,
                            const int* __restrict__ batch, float* __restrict__ alog, int n){
  int i=blockIdx.x*256+threadIdx.x; if (i<n) alog[i]=lrelu_f(dsrc[i]+dd[batch[i]]);
}

__global__ void mol_gather_k(const float* __restrict__ alog, const int* __restrict__ mptr,
                             const bf16* __restrict__ xs, const float* __restrict__ bias,
                             float* __restrict__ hb, int Bn){
  int wv=threadIdx.x>>6, lane=threadIdx.x&63;
  int b=blockIdx.x*4+wv; if (b>=Bn) return;
  int p0=mptr[b], p1=mptr[b+1];
  float m=-INFINITY;
  for (int i=p0+lane;i<p1;i+=64) m=fmaxf(m,alog[i]);
  #pragma unroll
  for (int o=32;o;o>>=1) m=fmaxf(m,__shfl_xor(m,o));
  float ssum=0.f;
  for (int i=p0+lane;i<p1;i+=64) ssum+=__expf(alog[i]-m);
  #pragma unroll
  for (int o=32;o;o>>=1) ssum+=__shfl_xor(ssum,o);
  float inv=1.f/(ssum+1e-16f);
  float a0=0.f,a1=0.f;
  for (int i=p0;i<p1;i++){
    float al=__expf(alog[i]-m)*inv;
    a0+=al*b2f(xs[(size_t)i*128+lane]); a1+=al*b2f(xs[(size_t)i*128+64+lane]);
  }
  hb[(size_t)b*128+lane]=elu_f(a0+bias[lane]);
  hb[(size_t)b*128+64+lane]=elu_f(a1+bias[64+lane]);
}

// ---------------- final head ----------------
__global__ void final_head_k(const float* __restrict__ out, const float* __restrict__ W2,
                             const float* __restrict__ b2, const float* __restrict__ Wh,
                             const float* __restrict__ bh, float* __restrict__ y, int Bn){
  __shared__ float srow[128]; __shared__ float sred[128];
  int b=blockIdx.x, c=threadIdx.x;
  srow[c]=out[(size_t)b*128+c]; __syncthreads();
  float acc=b2[c];
  const float* wr=&W2[(size_t)c*128];
  #pragma unroll 8
  for (int k=0;k<128;k++) acc+=srow[k]*wr[k];
  sred[c]=acc*Wh[c]; __syncthreads();
  for (int o=64;o;o>>=1){ if (c<o) sred[c]+=sred[c+o]; __syncthreads(); }
  if (c==0) y[b]=sred[0]+bh[0];
}

// ---------------- CSR build ----------------
__global__ void zero_i32_k(int* p, int n){ int i=blockIdx.x*256+threadIdx.x; if (i<n) p[i]=0; }
__global__ void hist_k(const int* __restrict__ dst, int* __restrict__ deg, int n){
  int e=blockIdx.x*256+threadIdx.x; if (e<n) atomicAdd(&deg[dst[e]],1);
}
__global__ void scan1_k(const int* __restrict__ deg, int* __restrict__ ptr,
                        int* __restrict__ part, int n){
  __shared__ int sd[256];
  int base=blockIdx.x*1024, tid=threadIdx.x;
  int v[4]; int ssum=0;
  #pragma unroll
  for (int j=0;j<4;j++){ int idx=base+tid*4+j; v[j]= idx<n? deg[idx]:0; ssum+=v[j]; }
  sd[tid]=ssum; __syncthreads();
  for (int o=1;o<256;o<<=1){ int t = tid>=o? sd[tid-o]:0; __syncthreads(); sd[tid]+=t; __syncthreads(); }
  int excl=sd[tid]-ssum;
  #pragma unroll
  for (int j=0;j<4;j++){ int idx=base+tid*4+j; if (idx<n) ptr[idx]=excl; excl+=v[j]; }
  if (tid==255) part[blockIdx.x]=sd[255];
}
__global__ void scan2_k(int* part, int nb){
  __shared__ int sd[512];
  int tid=threadIdx.x;
  int v= tid<nb? part[tid]:0; sd[tid]=v; __syncthreads();
  for (int o=1;o<512;o<<=1){ int t = tid>=o? sd[tid-o]:0; __syncthreads(); sd[tid]+=t; __syncthreads(); }
  if (tid<nb) part[tid]=sd[tid]-v;
}
__global__ void scan3_k(int* __restrict__ ptr, const int* __restrict__ part,
                        int* __restrict__ wofs, int n, int total){
  int i=blockIdx.x*256+threadIdx.x;
  if (i<n){ int val=ptr[i]+part[i>>10]; ptr[i]=val; wofs[i]=val; }
  if (i==0) ptr[n]=total;
}
__global__ void fill_csr_k(const int* __restrict__ dst, int* __restrict__ wofs,
                           int* __restrict__ eids, int n){
  int e=blockIdx.x*256+threadIdx.x;
  if (e<n){ int p=atomicAdd(&wofs[dst[e]],1); eids[p]=e; }
}

// =====================================================================
extern "C" void kernel_launch(void* const* d_in, const int* in_sizes, int n_in,
                              void* d_out, int out_size, void* d_ws, size_t ws_size,
                              hipStream_t stream){
  (void)in_sizes; (void)n_in; (void)out_size; (void)ws_size;
  const float* x0        =(const float*)d_in[0];
  const float* edge_attr =(const float*)d_in[1];
  const float* W_lin1    =(const float*)d_in[2];
  const float* b_lin1    =(const float*)d_in[3];
  const float* gate_W1   =(const float*)d_in[4];
  const float* gate_W2   =(const float*)d_in[5];
  const float* gate_att_l=(const float*)d_in[6];
  const float* gate_att_r=(const float*)d_in[7];
  const float* gate_bias =(const float*)d_in[8];
  const float* g1_Wih=(const float*)d_in[9];  const float* g1_Whh=(const float*)d_in[10];
  const float* g1_bih=(const float*)d_in[11]; const float* g1_bhh=(const float*)d_in[12];
  const float* conv_W=(const float*)d_in[13];
  const float* conv_att_src=(const float*)d_in[14];
  const float* conv_att_dst=(const float*)d_in[15];
  const float* conv_bias   =(const float*)d_in[16];
  const float* g2_Wih=(const float*)d_in[17]; const float* g2_Whh=(const float*)d_in[18];
  const float* g2_bih=(const float*)d_in[19]; const float* g2_bhh=(const float*)d_in[20];
  const float* mol_W=(const float*)d_in[21];
  const float* mol_att_src=(const float*)d_in[22];
  const float* mol_att_dst=(const float*)d_in[23];
  const float* mol_bias   =(const float*)d_in[24];
  const float* gm_Wih=(const float*)d_in[25]; const float* gm_Whh=(const float*)d_in[26];
  const float* gm_bih=(const float*)d_in[27]; const float* gm_bhh=(const float*)d_in[28];
  const float* W_lin2=(const float*)d_in[29]; const float* b_lin2=(const float*)d_in[30];
  const float* W_head=(const float*)d_in[31]; const float* b_head=(const float*)d_in[32];
  const int* ei   =(const int*)d_in[33];
  const int* batch=(const int*)d_in[34];
  const int* src=ei; const int* dst=ei+E_;
  float* y=(float*)d_out;

  // ---- workspace layout (~218 MiB total) ----
  const size_t NH=(size_t)N_*H_, BH=(size_t)B_*H_;
  bf16* b0  =(bf16*)d_ws;           // N*H bf16
  bf16* b1  =b0+NH;                 // N*H bf16
  bf16* b2v =b1+NH;                 // N*H bf16
  float* outA=(float*)(b2v+NH);     // B*H fp32
  float* outB=outA+BH;
  float* hb  =outB+BH;
  float* elog=hb+BH;                // E
  float* dsrc=elog+E_;              // N
  float* ddst=dsrc+N_;              // N
  float* alog=ddst+N_;              // N
  float* wdd =alog+N_;              // 128
  float* dd  =wdd+128;              // B
  int* deg =(int*)(dd+B_);          // N
  int* ptr =deg+N_;                 // N+1
  int* wofs=ptr+N_+1;               // N
  int* eids=wofs+N_;                // E
  int* part=eids+E_;                // 512
  int* mptr=part+512;               // B+1
  uintptr_t wbase=((uintptr_t)(mptr+B_+1)+255)&~(uintptr_t)255;
  bf16* wb_gw1 =(bf16*)wbase;        // 128*128
  bf16* wb_gw2 =wb_gw1 +128*128;
  bf16* wb_conv=wb_gw2 +128*128;
  bf16* wb_mol =wb_conv+128*128;
  bf16* wb_g1i =wb_mol +128*128;     // 384*128
  bf16* wb_g1h =wb_g1i +384*128;
  bf16* wb_g2i =wb_g1h +384*128;
  bf16* wb_g2h =wb_g2i +384*128;
  bf16* wb_l1  =wb_g2h +384*128;     // 128*64 (lin1, K padded 39->64)

  // ---- weight conversions (one dispatch, 9 segments) ----
  W2B9 wp;
  wp.seg[0]={gate_W1,wb_gw1,128,138,128,128};
  wp.seg[1]={gate_W2,wb_gw2,128,128,128,128};
  wp.seg[2]={conv_W ,wb_conv,128,128,128,128};
  wp.seg[3]={mol_W  ,wb_mol ,128,128,128,128};
  wp.seg[4]={g1_Wih,wb_g1i,384,128,128,128};
  wp.seg[5]={g1_Whh,wb_g1h,384,128,128,128};
  wp.seg[6]={g2_Wih,wb_g2i,384,128,128,128};
  wp.seg[7]={g2_Whh,wb_g2h,384,128,128,128};
  wp.seg[8]={W_lin1,wb_l1 ,128, 39, 64, 39};
  w2ball_k<<<dim3(192,9),256,0,stream>>>(wp);

  // ---- CSR by dst + molecule ranges ----
  zero_i32_k<<<(N_+255)/256,256,0,stream>>>(deg,N_);
  hist_k<<<(E_+255)/256,256,0,stream>>>(dst,deg,E_);
  int nb=(N_+1023)/1024;
  scan1_k<<<nb,256,0,stream>>>(deg,ptr,part,N_);
  scan2_k<<<1,512,0,stream>>>(part,nb);
  scan3_k<<<(N_+255)/256,256,0,stream>>>(ptr,part,wofs,N_,E_);
  fill_csr_k<<<(E_+255)/256,256,0,stream>>>(dst,wofs,eids,E_);
  mol_ptr_k<<<(B_+1+255)/256,256,0,stream>>>(batch,mptr,N_,B_);

  // ---- lin1: X -> b0 (MFMA) ----
  lin1_mfma_k<<<1024,256,0,stream>>>(x0,wb_l1,b_lin1,b0,N_);

  const int GL=768, GG=512;
  // ---- GATEConv ----
  lin_mfma_k<0><<<GL,256,0,stream>>>(b0,wb_gw1,nullptr,b1,N_);             // u -> b1
  rowdot_k<bf16><<<(N_+3)/4,256,0,stream>>>(b0,gate_att_r,ddst,N_);
  gate_edge_logits_k<<<4096,256,0,stream>>>(b1,edge_attr,gate_W1,gate_att_l,ddst,src,dst,elog,E_);
  node_gather_k<0><<<(N_+3)/4,256,0,stream>>>(elog,eids,ptr,src,b0,nullptr,b2v,N_);  // S -> b2
  lin_mfma_k<2><<<GL,256,0,stream>>>(b2v,wb_gw2,gate_bias,b1,N_);          // h=elu -> b1
  // ---- GRU1: x=relu(gru(h=b1, x=b0)) -> b2 ----
  gru_mfma_k<<<GG,256,0,stream>>>(b1,b0,wb_g1i,wb_g1h,g1_bih,g1_bhh,b2v,N_);
  // ---- atom GATConv (x lives in b2) ----
  lin_mfma_k<0><<<GL,256,0,stream>>>(b2v,wb_conv,nullptr,b0,N_);           // xl -> b0
  rowdot2_k<<<(N_+3)/4,256,0,stream>>>(b0,conv_att_src,conv_att_dst,dsrc,ddst,N_);
  conv_logit_k<<<(E_+255)/256,256,0,stream>>>(dsrc,ddst,src,dst,elog,E_);
  node_gather_k<1><<<(N_+3)/4,256,0,stream>>>(elog,eids,ptr,src,b0,conv_bias,b1,N_); // h=relu(S+bias) -> b1
  // ---- GRU2: x=relu(gru(h=b1, x=b2)) -> b0 ----
  gru_mfma_k<<<GG,256,0,stream>>>(b1,b2v,wb_g2i,wb_g2h,g2_bih,g2_bhh,b0,N_);
  // ---- readout (x lives in b0) ----
  mol_sum_k<<<(B_+3)/4,256,0,stream>>>(b0,mptr,outA,B_);
  lin_mfma_k<0><<<GL,256,0,stream>>>(b0,wb_mol,nullptr,b1,N_);             // xs -> b1
  rowdot_k<bf16><<<(N_+3)/4,256,0,stream>>>(b1,mol_att_src,dsrc,N_);
  fold_att_k<<<1,128,0,stream>>>(mol_W,mol_att_dst,wdd);
  float* out_cur=outA; float* out_nxt=outB;
  dim3 gm(157,4);
  for (int ts=0; ts<2; ts++){
    rowdot_k<float><<<(B_+3)/4,256,0,stream>>>(out_cur,wdd,dd,B_);
    mol_logit_k<<<(N_+255)/256,256,0,stream>>>(dsrc,dd,batch,alog,N_);
    mol_gather_k<<<(B_+3)/4,256,0,stream>>>(alog,mptr,b1,mol_bias,hb,B_);
    gru_scalar_k<<<gm,256,0,stream>>>(hb,out_cur,gm_Wih,gm_Whh,gm_bih,gm_bhh,out_nxt,B_);
    float* tmp=out_cur; out_cur=out_nxt; out_nxt=tmp;
  }
  final_head_k<<<B_,128,0,stream>>>(out_cur,W_lin2,b_lin2,W_head,b_head,y,B_);
}

// Round 7
// 1407.564 us; speedup vs baseline: 4.2111x; 1.2254x over previous
//
#include <hip/hip_runtime.h>
#include <hip/hip_bf16.h>
#include <type_traits>

typedef __hip_bfloat16 bf16;

constexpr int N_  = 250000;
constexpr int E_  = 500000;
constexpr int B_  = 10000;
constexpr int H_  = 128;

typedef short s8v __attribute__((ext_vector_type(8)));   // 8 bf16 in 4 VGPRs
typedef float f4v __attribute__((ext_vector_type(4)));

__device__ __forceinline__ float b2f(bf16 v){ return __bfloat162float(v); }
__device__ __forceinline__ bf16  f2b(float v){ return __float2bfloat16(v); }
__device__ __forceinline__ float to_float(float v){ return v; }
__device__ __forceinline__ float to_float(bf16 v){ return __bfloat162float(v); }
__device__ __forceinline__ float lrelu_f(float v){ return v > 0.f ? v : 0.01f*v; }
__device__ __forceinline__ float sigmoid_f(float x){ return __builtin_amdgcn_rcpf(1.f+__expf(-x)); }
__device__ __forceinline__ float tanh_f(float x){ return 1.f - 2.f*__builtin_amdgcn_rcpf(__expf(2.f*x)+1.f); }
__device__ __forceinline__ float elu_f(float v){ return v > 0.f ? v : __expf(v)-1.f; }
__device__ __forceinline__ unsigned f2b_bits(float f){
  bf16 h=__float2bfloat16(f); unsigned short s; __builtin_memcpy(&s,&h,2); return (unsigned)s;
}
__device__ __forceinline__ void unp8(uint4 v, float* o){
  o[0]=__uint_as_float(v.x<<16); o[1]=__uint_as_float(v.x&0xffff0000u);
  o[2]=__uint_as_float(v.y<<16); o[3]=__uint_as_float(v.y&0xffff0000u);
  o[4]=__uint_as_float(v.z<<16); o[5]=__uint_as_float(v.z&0xffff0000u);
  o[6]=__uint_as_float(v.w<<16); o[7]=__uint_as_float(v.w&0xffff0000u);
}

// ---------------- consolidated fp32->bf16 weight copies (9 segments) -------
struct W2B { const float* s; bf16* d; int rows, ld, ow, cw; };
struct W2B9 { W2B seg[9]; };
__global__ void w2ball_k(W2B9 p){
  W2B g=p.seg[blockIdx.y];
  int i=blockIdx.x*256+threadIdx.x;
  if (i>=g.rows*g.ow) return;
  int r=i/g.ow, k=i-r*g.ow;
  g.d[i] = f2b(k<g.cw ? g.s[(size_t)r*g.ld+k] : 0.f);
}

// ---------------- lin1 via MFMA: [N,39] fp32 -> [N,128] bf16, lrelu --------
__global__ __launch_bounds__(256) void lin1_mfma_k(const float* __restrict__ X0, const bf16* __restrict__ Wb,
                            const float* __restrict__ bias, bf16* __restrict__ Y, int M){
  __shared__ __align__(16) bf16 sx[64][72];
  int wv=threadIdx.x>>6, lane=threadIdx.x&63;
  int n=lane&15, q=lane>>4;
  int c0=wv*32;
  s8v wB[2][2];
  #pragma unroll
  for (int ct=0;ct<2;ct++)
    #pragma unroll
    for (int kk=0;kk<2;kk++)
      wB[ct][kk]=*(const s8v*)(Wb+(size_t)(c0+ct*16+n)*64+kk*32+q*8);
  float bb[2];
  #pragma unroll
  for (int ct=0;ct<2;ct++) bb[ct]=bias[c0+ct*16+n];
  for (int i=threadIdx.x;i<64*25;i+=256){ int r=i/25,k=39+(i-(i/25)*25); sx[r][k]=f2b(0.f); }
  for (long r0=(long)blockIdx.x*64; r0<M; r0+=(long)gridDim.x*64){
    __syncthreads();
    for (int f=threadIdx.x; f<64*39; f+=256){
      int r=f/39, k=f-(f/39)*39; long row=r0+r;
      sx[r][k]= f2b(row<M ? X0[row*39+k] : 0.f);
    }
    __syncthreads();
    s8v a[4][2];
    #pragma unroll
    for (int rt=0;rt<4;rt++)
      #pragma unroll
      for (int kk=0;kk<2;kk++)
        a[rt][kk]=*(const s8v*)&sx[rt*16+n][kk*32+q*8];
    f4v acc[4][2];
    #pragma unroll
    for (int rt=0;rt<4;rt++)
      #pragma unroll
      for (int ct=0;ct<2;ct++) acc[rt][ct]=(f4v){0.f,0.f,0.f,0.f};
    #pragma unroll
    for (int kk=0;kk<2;kk++)
      #pragma unroll
      for (int rt=0;rt<4;rt++)
        #pragma unroll
        for (int ct=0;ct<2;ct++)
          acc[rt][ct]=__builtin_amdgcn_mfma_f32_16x16x32_bf16(a[rt][kk],wB[ct][kk],acc[rt][ct],0,0,0);
    #pragma unroll
    for (int ct=0;ct<2;ct++){
      int col=c0+ct*16+n;
      #pragma unroll
      for (int rt=0;rt<4;rt++){
        #pragma unroll
        for (int rg=0;rg<4;rg++){
          long row=r0+rt*16+q*4+rg;
          if (row<M) Y[row*128+col]=f2b(lrelu_f(acc[rt][ct][rg]+bb[ct]));
        }
      }
    }
  }
}

// ---- MFMA linear, weights in registers, grid-stride over 64-row tiles ----
template<int ACT>   // 0 none, 2 elu
__global__ __launch_bounds__(256) void lin_mfma_k(const bf16* __restrict__ X, const bf16* __restrict__ Wb,
                            const float* __restrict__ bias, bf16* __restrict__ Y, int M){
  int wv=threadIdx.x>>6, lane=threadIdx.x&63;
  int n=lane&15, q=lane>>4;
  int c0=wv*32;
  s8v wB[2][4];
  #pragma unroll
  for (int ct=0;ct<2;ct++)
    #pragma unroll
    for (int kk=0;kk<4;kk++)
      wB[ct][kk]=*(const s8v*)(Wb+(size_t)(c0+ct*16+n)*128+kk*32+q*8);
  float bb[2];
  #pragma unroll
  for (int ct=0;ct<2;ct++) bb[ct]=bias? bias[c0+ct*16+n]:0.f;
  for (long r0=(long)blockIdx.x*64; r0<M; r0+=(long)gridDim.x*64){
    s8v a[4][4];
    #pragma unroll
    for (int rt=0;rt<4;rt++){
      long row=r0+rt*16+n; if (row>=M) row=M-1;
      #pragma unroll
      for (int kk=0;kk<4;kk++) a[rt][kk]=*(const s8v*)(X+row*128+kk*32+q*8);
    }
    f4v acc[4][2];
    #pragma unroll
    for (int rt=0;rt<4;rt++)
      #pragma unroll
      for (int ct=0;ct<2;ct++) acc[rt][ct]=(f4v){0.f,0.f,0.f,0.f};
    #pragma unroll
    for (int kk=0;kk<4;kk++)
      #pragma unroll
      for (int rt=0;rt<4;rt++)
        #pragma unroll
        for (int ct=0;ct<2;ct++)
          acc[rt][ct]=__builtin_amdgcn_mfma_f32_16x16x32_bf16(a[rt][kk],wB[ct][kk],acc[rt][ct],0,0,0);
    #pragma unroll
    for (int ct=0;ct<2;ct++){
      int col=c0+ct*16+n;
      #pragma unroll
      for (int rt=0;rt<4;rt++){
        #pragma unroll
        for (int rg=0;rg<4;rg++){
          long row=r0+rt*16+q*4+rg;
          if (row<M){
            float v=acc[rt][ct][rg]+bb[ct];
            if (ACT==2) v=elu_f(v);
            Y[row*128+col]=f2b(v);
          }
        }
      }
    }
  }
}

// ---- MFMA fused GRU (atoms): 512 threads, 8 waves x 16-col slices ----
// Per wave: 96 VGPR weights + 48 acc + 64 frags + 8 xv -> ~2 waves/SIMD.
__global__ __launch_bounds__(512,1) void gru_mfma_k(const bf16* __restrict__ A, const bf16* __restrict__ X,
                            const bf16* __restrict__ Wih, const bf16* __restrict__ Whh,
                            const float* __restrict__ bih, const float* __restrict__ bhh,
                            bf16* __restrict__ dest, int M){
  int wv=threadIdx.x>>6, lane=threadIdx.x&63;
  int n=lane&15, q=lane>>4;
  int c0=wv*16;
  s8v wI[3][4], wH[3][4];
  #pragma unroll
  for (int g=0;g<3;g++)
    #pragma unroll
    for (int kk=0;kk<4;kk++){
      size_t off=((size_t)(g*128+c0+n))*128+kk*32+q*8;
      wI[g][kk]=*(const s8v*)(Wih+off);
      wH[g][kk]=*(const s8v*)(Whh+off);
    }
  int col=c0+n;
  float br =bih[col]+bhh[col];
  float bz =bih[128+col]+bhh[128+col];
  float bni=bih[256+col], bnh=bhh[256+col];
  for (long r0=(long)blockIdx.x*32; r0<M; r0+=(long)gridDim.x*32){
    s8v aA[2][4], aX[2][4];
    #pragma unroll
    for (int rt=0;rt<2;rt++){
      long row=r0+rt*16+n; if (row>=M) row=M-1;
      #pragma unroll
      for (int kk=0;kk<4;kk++){
        aA[rt][kk]=*(const s8v*)(A+row*128+kk*32+q*8);
        aX[rt][kk]=*(const s8v*)(X+row*128+kk*32+q*8);
      }
    }
    // hoist xv loads (C-layout) so they overlap the MFMA block
    float xv[2][4];
    #pragma unroll
    for (int rt=0;rt<2;rt++)
      #pragma unroll
      for (int rg=0;rg<4;rg++){
        long row=r0+rt*16+q*4+rg; if (row>=M) row=M-1;
        xv[rt][rg]=b2f(X[row*128+col]);
      }
    f4v acc[6][2];
    #pragma unroll
    for (int g=0;g<6;g++)
      #pragma unroll
      for (int rt=0;rt<2;rt++) acc[g][rt]=(f4v){0.f,0.f,0.f,0.f};
    #pragma unroll
    for (int kk=0;kk<4;kk++)
      #pragma unroll
      for (int g=0;g<3;g++)
        #pragma unroll
        for (int rt=0;rt<2;rt++){
          acc[g  ][rt]=__builtin_amdgcn_mfma_f32_16x16x32_bf16(aA[rt][kk],wI[g][kk],acc[g  ][rt],0,0,0);
          acc[3+g][rt]=__builtin_amdgcn_mfma_f32_16x16x32_bf16(aX[rt][kk],wH[g][kk],acc[3+g][rt],0,0,0);
        }
    #pragma unroll
    for (int rt=0;rt<2;rt++){
      #pragma unroll
      for (int rg=0;rg<4;rg++){
        long row=r0+rt*16+q*4+rg;
        if (row<M){
          float rgate=sigmoid_f(acc[0][rt][rg]+acc[3][rt][rg]+br);
          float zgate=sigmoid_f(acc[1][rt][rg]+acc[4][rt][rg]+bz);
          float nn=tanh_f(acc[2][rt][rg]+bni + rgate*(acc[5][rt][rg]+bnh));
          float o=(1.f-zgate)*nn + zgate*xv[rt][rg];
          dest[row*128+col]=f2b(fmaxf(o,0.f));
        }
      }
    }
  }
}

// ------- scalar fused GRU (molecules, fp32 state) ----
__global__ __launch_bounds__(256) void gru_scalar_k(const float* __restrict__ A, const float* __restrict__ X,
                            const float* __restrict__ Wih, const float* __restrict__ Whh,
                            const float* __restrict__ bih, const float* __restrict__ bhh,
                            float* __restrict__ dest, int M){
  __shared__ unsigned sW[6][32*66];
  __shared__ float sA[8][132], sX[8][132];
  __shared__ float sbi[3][32], sbh[3][32];
  int c0 = blockIdx.y*32;
  for (int i=threadIdx.x; i<6*32*64; i+=256){
    int m=i>>11, r=i&2047, c=r>>6, k2=r&63;
    const float* base = (m<3)? Wih : Whh;
    int g = (m<3)? m : m-3;
    const float* wp = base + ((size_t)(g*128 + c0 + c))*128 + 2*k2;
    sW[m][c*66 + k2] = f2b_bits(wp[0]) | (f2b_bits(wp[1])<<16);
  }
  if (threadIdx.x < 96){
    int g=threadIdx.x>>5, c=threadIdx.x&31;
    sbi[g][c]=bih[g*128+c0+c]; sbh[g][c]=bhh[g*128+c0+c];
  }
  __syncthreads();
  int sub=threadIdx.x>>5, c=threadIdx.x&31;
  for (long r0=(long)blockIdx.x*8; r0<M; r0+=(long)gridDim.x*8){
    __syncthreads();
    for (int i=threadIdx.x;i<8*16;i+=256){
      int rr=i>>4, q=i&15; long row=r0+rr;
      if (row<M){
        *(float4*)&sA[rr][q*8]   = *(const float4*)(A+row*128+q*8);
        *(float4*)&sA[rr][q*8+4] = *(const float4*)(A+row*128+q*8+4);
        *(float4*)&sX[rr][q*8]   = *(const float4*)(X+row*128+q*8);
        *(float4*)&sX[rr][q*8+4] = *(const float4*)(X+row*128+q*8+4);
      } else {
        float4 z=make_float4(0,0,0,0);
        *(float4*)&sA[rr][q*8]=z; *(float4*)&sA[rr][q*8+4]=z;
        *(float4*)&sX[rr][q*8]=z; *(float4*)&sX[rr][q*8+4]=z;
      }
    }
    __syncthreads();
    long row=r0+sub;
    if (row<M){
      const unsigned* wri=&sW[0][c*66]; const unsigned* wzi=&sW[1][c*66]; const unsigned* wni=&sW[2][c*66];
      const unsigned* wrh=&sW[3][c*66]; const unsigned* wzh=&sW[4][c*66]; const unsigned* wnh=&sW[5][c*66];
      const float2* xa=(const float2*)sA[sub]; const float2* xb=(const float2*)sX[sub];
      float ari=0,azi=0,ani=0,arh=0,azh=0,anh=0;
      #pragma unroll 8
      for (int k2=0;k2<64;k2++){
        float2 av=xa[k2], bv=xb[k2];
        unsigned u;
        u=wri[k2]; ari += av.x*__uint_as_float(u<<16) + av.y*__uint_as_float(u&0xffff0000u);
        u=wzi[k2]; azi += av.x*__uint_as_float(u<<16) + av.y*__uint_as_float(u&0xffff0000u);
        u=wni[k2]; ani += av.x*__uint_as_float(u<<16) + av.y*__uint_as_float(u&0xffff0000u);
        u=wrh[k2]; arh += bv.x*__uint_as_float(u<<16) + bv.y*__uint_as_float(u&0xffff0000u);
        u=wzh[k2]; azh += bv.x*__uint_as_float(u<<16) + bv.y*__uint_as_float(u&0xffff0000u);
        u=wnh[k2]; anh += bv.x*__uint_as_float(u<<16) + bv.y*__uint_as_float(u&0xffff0000u);
      }
      float rg = sigmoid_f(ari+arh+sbi[0][c]+sbh[0][c]);
      float zg = sigmoid_f(azi+azh+sbi[1][c]+sbh[1][c]);
      float nn = tanh_f(ani+sbi[2][c] + rg*(anh+sbh[2][c]));
      float xv = sX[sub][c0+c];
      float o  = (1.f-zg)*nn + zg*xv;
      dest[row*128+c0+c] = fmaxf(o,0.f);
    }
  }
}

// ---------------- row dot(s) ----------------
template<typename TY>
__global__ void rowdot_k(const TY* __restrict__ Y, const float* __restrict__ v,
                         float* __restrict__ d, int M){
  __shared__ float sv[128];
  if (threadIdx.x<128) sv[threadIdx.x]=v[threadIdx.x];
  __syncthreads();
  int wv=threadIdx.x>>6, lane=threadIdx.x&63;
  long row=(long)blockIdx.x*4+wv;
  if (row>=M) return;
  float a=to_float(Y[row*128+lane])*sv[lane]+to_float(Y[row*128+64+lane])*sv[64+lane];
  #pragma unroll
  for (int o=32;o;o>>=1) a+=__shfl_xor(a,o);
  if (!lane) d[row]=a;
}

__global__ void rowdot2_k(const bf16* __restrict__ Y, const float* __restrict__ v1,
                          const float* __restrict__ v2, float* __restrict__ d1,
                          float* __restrict__ d2, int M){
  __shared__ float sv1[128], sv2[128];
  if (threadIdx.x<128){ sv1[threadIdx.x]=v1[threadIdx.x]; sv2[threadIdx.x]=v2[threadIdx.x]; }
  __syncthreads();
  int wv=threadIdx.x>>6, lane=threadIdx.x&63;
  long row=(long)blockIdx.x*4+wv;
  if (row>=M) return;
  float x0=b2f(Y[row*128+lane]), x1=b2f(Y[row*128+64+lane]);
  float a=x0*sv1[lane]+x1*sv1[64+lane];
  float b=x0*sv2[lane]+x1*sv2[64+lane];
  #pragma unroll
  for (int o=32;o;o>>=1){ a+=__shfl_xor(a,o); b+=__shfl_xor(b,o); }
  if (!lane){ d1[row]=a; d2[row]=b; }
}

// ---------------- GATE edge logits (writes CSR-permuted) ----------------
__global__ __launch_bounds__(256) void gate_edge_logits_k(const bf16* __restrict__ u, const float* __restrict__ ea,
                                   const float* __restrict__ gW1, const float* __restrict__ att_l,
                                   const float* __restrict__ ddst, const int* __restrict__ src,
                                   const int* __restrict__ dst, const int* __restrict__ epos,
                                   float* __restrict__ elog, int E){
  __shared__ float sWb[10][128];
  __shared__ float sal[128];
  for (int i=threadIdx.x;i<10*128;i+=256){ int k=i>>7,c=i&127; sWb[k][c]=gW1[(size_t)c*138+128+k]; }
  if (threadIdx.x<128) sal[threadIdx.x]=att_l[threadIdx.x];
  __syncthreads();
  int wv=threadIdx.x>>6, lane=threadIdx.x&63;
  for (long e=(long)blockIdx.x*4+wv; e<E; e+=(long)gridDim.x*4){
    int sj=src[e], di=dst[e];
    float eal[10];
    #pragma unroll
    for (int k=0;k<10;k++) eal[k]=ea[(size_t)e*10+k];
    float acc=0.f;
    #pragma unroll
    for (int j=0;j<2;j++){
      int cc=lane+64*j;
      float v=0.f;
      #pragma unroll
      for (int k=0;k<10;k++) v+=eal[k]*sWb[k][cc];
      v+=b2f(u[(size_t)sj*128+cc]);
      acc+=lrelu_f(v)*sal[cc];
    }
    #pragma unroll
    for (int o=32;o;o>>=1) acc+=__shfl_xor(acc,o);
    if (!lane) elog[epos[e]]=lrelu_f(acc+ddst[di]);
  }
}

// ---------------- conv edge logits (writes CSR-permuted) ----------------
__global__ void conv_logit_k(const float* __restrict__ dsrc, const float* __restrict__ ddst,
                             const int* __restrict__ src, const int* __restrict__ dst,
                             const int* __restrict__ epos, float* __restrict__ elog, int n){
  int e=blockIdx.x*256+threadIdx.x;
  if (e<n) elog[epos[e]]=lrelu_f(dsrc[src[e]]+ddst[dst[e]]);
}

// ------- per-node softmax + weighted sum; 16 lanes per node, contiguous CSR --
template<int ACT>   // 0 none, 1 relu(S+bias)
__global__ void node_gather_k(const float* __restrict__ elog, const int* __restrict__ srcp,
                              const int* __restrict__ ptr, const bf16* __restrict__ V,
                              const float* __restrict__ bias, bf16* __restrict__ S, int M){
  int wv=threadIdx.x>>6, lane=threadIdx.x&63;
  int g=lane>>4, t=lane&15;
  int node=blockIdx.x*16 + wv*4 + g;
  if (node>=M) return;
  int p0=ptr[node], p1=ptr[node+1];
  float m=-INFINITY;
  for (int p=p0+t;p<p1;p+=16) m=fmaxf(m,elog[p]);
  #pragma unroll
  for (int o=8;o;o>>=1) m=fmaxf(m,__shfl_xor(m,o));
  float ssum=0.f;
  for (int p=p0+t;p<p1;p+=16) ssum+=__expf(elog[p]-m);
  #pragma unroll
  for (int o=8;o;o>>=1) ssum+=__shfl_xor(ssum,o);
  float inv=1.f/(ssum+1e-16f);
  float acc[8]={0,0,0,0,0,0,0,0};
  for (int p=p0;p<p1;p++){
    float al=__expf(elog[p]-m)*inv;
    uint4 v=*(const uint4*)(V+(size_t)srcp[p]*128+t*8);
    float xf[8]; unp8(v,xf);
    #pragma unroll
    for (int j=0;j<8;j++) acc[j]+=al*xf[j];
  }
  if (ACT==1){
    #pragma unroll
    for (int j=0;j<8;j++) acc[j]=fmaxf(acc[j]+bias[t*8+j],0.f);
  }
  uint4 o;
  o.x=f2b_bits(acc[0])|(f2b_bits(acc[1])<<16);
  o.y=f2b_bits(acc[2])|(f2b_bits(acc[3])<<16);
  o.z=f2b_bits(acc[4])|(f2b_bits(acc[5])<<16);
  o.w=f2b_bits(acc[6])|(f2b_bits(acc[7])<<16);
  *(uint4*)(S+(size_t)node*128+t*8)=o;
}

// ---------------- molecule kernels ----------------
__global__ void mol_ptr_k(const int* __restrict__ batch, int* __restrict__ mptr, int n, int Bn){
  int b=blockIdx.x*256+threadIdx.x; if (b>Bn) return;
  if (b==Bn){ mptr[Bn]=n; return; }
  int lo=0, hi=n;
  while (lo<hi){ int mid=(lo+hi)>>1; if (batch[mid]<b) lo=mid+1; else hi=mid; }
  mptr[b]=lo;
}

__global__ void mol_sum_k(const bf16* __restrict__ x, const int* __restrict__ mptr,
                          float* __restrict__ out, int Bn){
  int wv=threadIdx.x>>6, lane=threadIdx.x&63;
  int b=blockIdx.x*4+wv; if (b>=Bn) return;
  int p0=mptr[b], p1=mptr[b+1];
  float a0=0.f,a1=0.f;
  for (int i=p0;i<p1;i++){ a0+=b2f(x[(size_t)i*128+lane]); a1+=b2f(x[(size_t)i*128+64+lane]); }
  out[(size_t)b*128+lane]=fmaxf(a0,0.f); out[(size_t)b*128+64+lane]=fmaxf(a1,0.f);
}

__global__ void fold_att_k(const float* __restrict__ W, const float* __restrict__ att,
                           float* __restrict__ wdd){
  int k=threadIdx.x; float a=0.f;
  for (int c=0;c<128;c++) a+=att[c]*W[(size_t)c*128+k];
  wdd[k]=a;
}

__global__ void mol_logit_k(const float* __restrict__ dsrc, const float* __restrict__ dd,
                            const int* __restrict__ batch, float* __restrict__ alog, int n){
  int i=blockIdx.x*256+threadIdx.x; if (i<n) alog[i]=lrelu_f(dsrc[i]+dd[batch[i]]);
}

__global__ void mol_gather_k(const float* __restrict__ alog, const int* __restrict__ mptr,
                             const bf16* __restrict__ xs, const float* __restrict__ bias,
                             float* __restrict__ hb, int Bn){
  int wv=threadIdx.x>>6, lane=threadIdx.x&63;
  int b=blockIdx.x*4+wv; if (b>=Bn) return;
  int p0=mptr[b], p1=mptr[b+1];
  float m=-INFINITY;
  for (int i=p0+lane;i<p1;i+=64) m=fmaxf(m,alog[i]);
  #pragma unroll
  for (int o=32;o;o>>=1) m=fmaxf(m,__shfl_xor(m,o));
  float ssum=0.f;
  for (int i=p0+lane;i<p1;i+=64) ssum+=__expf(alog[i]-m);
  #pragma unroll
  for (int o=32;o;o>>=1) ssum+=__shfl_xor(ssum,o);
  float inv=1.f/(ssum+1e-16f);
  float a0=0.f,a1=0.f;
  for (int i=p0;i<p1;i++){
    float al=__expf(alog[i]-m)*inv;
    a0+=al*b2f(xs[(size_t)i*128+lane]); a1+=al*b2f(xs[(size_t)i*128+64+lane]);
  }
  hb[(size_t)b*128+lane]=elu_f(a0+bias[lane]);
  hb[(size_t)b*128+64+lane]=elu_f(a1+bias[64+lane]);
}

// ---------------- final head ----------------
__global__ void final_head_k(const float* __restrict__ out, const float* __restrict__ W2,
                             const float* __restrict__ b2, const float* __restrict__ Wh,
                             const float* __restrict__ bh, float* __restrict__ y, int Bn){
  __shared__ float srow[128]; __shared__ float sred[128];
  int b=blockIdx.x, c=threadIdx.x;
  srow[c]=out[(size_t)b*128+c]; __syncthreads();
  float acc=b2[c];
  const float* wr=&W2[(size_t)c*128];
  #pragma unroll 8
  for (int k=0;k<128;k++) acc+=srow[k]*wr[k];
  sred[c]=acc*Wh[c]; __syncthreads();
  for (int o=64;o;o>>=1){ if (c<o) sred[c]+=sred[c+o]; __syncthreads(); }
  if (c==0) y[b]=sred[0]+bh[0];
}

// ---------------- CSR build ----------------
__global__ void zero_i32_k(int* p, int n){ int i=blockIdx.x*256+threadIdx.x; if (i<n) p[i]=0; }
__global__ void hist_k(const int* __restrict__ dst, int* __restrict__ deg, int n){
  int e=blockIdx.x*256+threadIdx.x; if (e<n) atomicAdd(&deg[dst[e]],1);
}
__global__ void scan1_k(const int* __restrict__ deg, int* __restrict__ ptr,
                        int* __restrict__ part, int n){
  __shared__ int sd[256];
  int base=blockIdx.x*1024, tid=threadIdx.x;
  int v[4]; int ssum=0;
  #pragma unroll
  for (int j=0;j<4;j++){ int idx=base+tid*4+j; v[j]= idx<n? deg[idx]:0; ssum+=v[j]; }
  sd[tid]=ssum; __syncthreads();
  for (int o=1;o<256;o<<=1){ int t = tid>=o? sd[tid-o]:0; __syncthreads(); sd[tid]+=t; __syncthreads(); }
  int excl=sd[tid]-ssum;
  #pragma unroll
  for (int j=0;j<4;j++){ int idx=base+tid*4+j; if (idx<n) ptr[idx]=excl; excl+=v[j]; }
  if (tid==255) part[blockIdx.x]=sd[255];
}
__global__ void scan2_k(int* part, int nb){
  __shared__ int sd[512];
  int tid=threadIdx.x;
  int v= tid<nb? part[tid]:0; sd[tid]=v; __syncthreads();
  for (int o=1;o<512;o<<=1){ int t = tid>=o? sd[tid-o]:0; __syncthreads(); sd[tid]+=t; __syncthreads(); }
  if (tid<nb) part[tid]=sd[tid]-v;
}
__global__ void scan3_k(int* __restrict__ ptr, const int* __restrict__ part,
                        int* __restrict__ wofs, int n, int total){
  int i=blockIdx.x*256+threadIdx.x;
  if (i<n){ int val=ptr[i]+part[i>>10]; ptr[i]=val; wofs[i]=val; }
  if (i==0) ptr[n]=total;
}
__global__ void fill_csr_k(const int* __restrict__ dst, const int* __restrict__ src,
                           int* __restrict__ wofs, int* __restrict__ srcp,
                           int* __restrict__ epos, int n){
  int e=blockIdx.x*256+threadIdx.x;
  if (e<n){ int p=atomicAdd(&wofs[dst[e]],1); srcp[p]=src[e]; epos[e]=p; }
}

// =====================================================================
extern "C" void kernel_launch(void* const* d_in, const int* in_sizes, int n_in,
                              void* d_out, int out_size, void* d_ws, size_t ws_size,
                              hipStream_t stream){
  (void)in_sizes; (void)n_in; (void)out_size; (void)ws_size;
  const float* x0        =(const float*)d_in[0];
  const float* edge_attr =(const float*)d_in[1];
  const float* W_lin1    =(const float*)d_in[2];
  const float* b_lin1    =(const float*)d_in[3];
  const float* gate_W1   =(const float*)d_in[4];
  const float* gate_W2   =(const float*)d_in[5];
  const float* gate_att_l=(const float*)d_in[6];
  const float* gate_att_r=(const float*)d_in[7];
  const float* gate_bias =(const float*)d_in[8];
  const float* g1_Wih=(const float*)d_in[9];  const float* g1_Whh=(const float*)d_in[10];
  const float* g1_bih=(const float*)d_in[11]; const float* g1_bhh=(const float*)d_in[12];
  const float* conv_W=(const float*)d_in[13];
  const float* conv_att_src=(const float*)d_in[14];
  const float* conv_att_dst=(const float*)d_in[15];
  const float* conv_bias   =(const float*)d_in[16];
  const float* g2_Wih=(const float*)d_in[17]; const float* g2_Whh=(const float*)d_in[18];
  const float* g2_bih=(const float*)d_in[19]; const float* g2_bhh=(const float*)d_in[20];
  const float* mol_W=(const float*)d_in[21];
  const float* mol_att_src=(const float*)d_in[22];
  const float* mol_att_dst=(const float*)d_in[23];
  const float* mol_bias   =(const float*)d_in[24];
  const float* gm_Wih=(const float*)d_in[25]; const float* gm_Whh=(const float*)d_in[26];
  const float* gm_bih=(const float*)d_in[27]; const float* gm_bhh=(const float*)d_in[28];
  const float* W_lin2=(const float*)d_in[29]; const float* b_lin2=(const float*)d_in[30];
  const float* W_head=(const float*)d_in[31]; const float* b_head=(const float*)d_in[32];
  const int* ei   =(const int*)d_in[33];
  const int* batch=(const int*)d_in[34];
  const int* src=ei; const int* dst=ei+E_;
  float* y=(float*)d_out;

  // ---- workspace layout (~222 MiB total) ----
  const size_t NH=(size_t)N_*H_, BH=(size_t)B_*H_;
  bf16* b0  =(bf16*)d_ws;           // N*H bf16
  bf16* b1  =b0+NH;                 // N*H bf16
  bf16* b2v =b1+NH;                 // N*H bf16
  float* outA=(float*)(b2v+NH);     // B*H fp32
  float* outB=outA+BH;
  float* hb  =outB+BH;
  float* elog=hb+BH;                // E
  float* dsrc=elog+E_;              // N
  float* ddst=dsrc+N_;              // N
  float* alog=ddst+N_;              // N
  float* wdd =alog+N_;              // 128
  float* dd  =wdd+128;              // B
  int* deg =(int*)(dd+B_);          // N
  int* ptr =deg+N_;                 // N+1
  int* wofs=ptr+N_+1;               // N
  int* part=wofs+N_;                // 512
  int* mptr=part+512;               // B+1
  int* srcp=mptr+B_+1;              // E
  int* epos=srcp+E_;                // E
  uintptr_t wbase=((uintptr_t)(epos+E_)+255)&~(uintptr_t)255;
  bf16* wb_gw1 =(bf16*)wbase;        // 128*128
  bf16* wb_gw2 =wb_gw1 +128*128;
  bf16* wb_conv=wb_gw2 +128*128;
  bf16* wb_mol =wb_conv+128*128;
  bf16* wb_g1i =wb_mol +128*128;     // 384*128
  bf16* wb_g1h =wb_g1i +384*128;
  bf16* wb_g2i =wb_g1h +384*128;
  bf16* wb_g2h =wb_g2i +384*128;
  bf16* wb_l1  =wb_g2h +384*128;     // 128*64 (lin1, K padded 39->64)

  // ---- weight conversions (one dispatch, 9 segments) ----
  W2B9 wp;
  wp.seg[0]={gate_W1,wb_gw1,128,138,128,128};
  wp.seg[1]={gate_W2,wb_gw2,128,128,128,128};
  wp.seg[2]={conv_W ,wb_conv,128,128,128,128};
  wp.seg[3]={mol_W  ,wb_mol ,128,128,128,128};
  wp.seg[4]={g1_Wih,wb_g1i,384,128,128,128};
  wp.seg[5]={g1_Whh,wb_g1h,384,128,128,128};
  wp.seg[6]={g2_Wih,wb_g2i,384,128,128,128};
  wp.seg[7]={g2_Whh,wb_g2h,384,128,128,128};
  wp.seg[8]={W_lin1,wb_l1 ,128, 39, 64, 39};
  w2ball_k<<<dim3(192,9),256,0,stream>>>(wp);

  // ---- CSR by dst (+ permutation arrays) + molecule ranges ----
  zero_i32_k<<<(N_+255)/256,256,0,stream>>>(deg,N_);
  hist_k<<<(E_+255)/256,256,0,stream>>>(dst,deg,E_);
  int nb=(N_+1023)/1024;
  scan1_k<<<nb,256,0,stream>>>(deg,ptr,part,N_);
  scan2_k<<<1,512,0,stream>>>(part,nb);
  scan3_k<<<(N_+255)/256,256,0,stream>>>(ptr,part,wofs,N_,E_);
  fill_csr_k<<<(E_+255)/256,256,0,stream>>>(dst,src,wofs,srcp,epos,E_);
  mol_ptr_k<<<(B_+1+255)/256,256,0,stream>>>(batch,mptr,N_,B_);

  // ---- lin1: X -> b0 (MFMA) ----
  lin1_mfma_k<<<1024,256,0,stream>>>(x0,wb_l1,b_lin1,b0,N_);

  const int GL=768, GG=512, GN=(N_+15)/16;
  // ---- GATEConv ----
  lin_mfma_k<0><<<GL,256,0,stream>>>(b0,wb_gw1,nullptr,b1,N_);             // u -> b1
  rowdot_k<bf16><<<(N_+3)/4,256,0,stream>>>(b0,gate_att_r,ddst,N_);
  gate_edge_logits_k<<<4096,256,0,stream>>>(b1,edge_attr,gate_W1,gate_att_l,ddst,src,dst,epos,elog,E_);
  node_gather_k<0><<<GN,256,0,stream>>>(elog,srcp,ptr,b0,nullptr,b2v,N_);  // S -> b2
  lin_mfma_k<2><<<GL,256,0,stream>>>(b2v,wb_gw2,gate_bias,b1,N_);          // h=elu -> b1
  // ---- GRU1: x=relu(gru(h=b1, x=b0)) -> b2 ----
  gru_mfma_k<<<GG,512,0,stream>>>(b1,b0,wb_g1i,wb_g1h,g1_bih,g1_bhh,b2v,N_);
  // ---- atom GATConv (x lives in b2) ----
  lin_mfma_k<0><<<GL,256,0,stream>>>(b2v,wb_conv,nullptr,b0,N_);           // xl -> b0
  rowdot2_k<<<(N_+3)/4,256,0,stream>>>(b0,conv_att_src,conv_att_dst,dsrc,ddst,N_);
  conv_logit_k<<<(E_+255)/256,256,0,stream>>>(dsrc,ddst,src,dst,epos,elog,E_);
  node_gather_k<1><<<GN,256,0,stream>>>(elog,srcp,ptr,b0,conv_bias,b1,N_); // h=relu(S+bias) -> b1
  // ---- GRU2: x=relu(gru(h=b1, x=b2)) -> b0 ----
  gru_mfma_k<<<GG,512,0,stream>>>(b1,b2v,wb_g2i,wb_g2h,g2_bih,g2_bhh,b0,N_);
  // ---- readout (x lives in b0) ----
  mol_sum_k<<<(B_+3)/4,256,0,stream>>>(b0,mptr,outA,B_);
  lin_mfma_k<0><<<GL,256,0,stream>>>(b0,wb_mol,nullptr,b1,N_);             // xs -> b1
  rowdot_k<bf16><<<(N_+3)/4,256,0,stream>>>(b1,mol_att_src,dsrc,N_);
  fold_att_k<<<1,128,0,stream>>>(mol_W,mol_att_dst,wdd);
  float* out_cur=outA; float* out_nxt=outB;
  dim3 gm(157,4);
  for (int ts=0; ts<2; ts++){
    rowdot_k<float><<<(B_+3)/4,256,0,stream>>>(out_cur,wdd,dd,B_);
    mol_logit_k<<<(N_+255)/256,256,0,stream>>>(dsrc,dd,batch,alog,N_);
    mol_gather_k<<<(B_+3)/4,256,0,stream>>>(alog,mptr,b1,mol_bias,hb,B_);
    gru_scalar_k<<<gm,256,0,stream>>>(hb,out_cur,gm_Wih,gm_Whh,gm_bih,gm_bhh,out_nxt,B_);
    float* tmp=out_cur; out_cur=out_nxt; out_nxt=tmp;
  }
  final_head_k<<<B_,128,0,stream>>>(out_cur,W_lin2,b_lin2,W_head,b_head,y,B_);
}

// Round 8
// 1302.360 us; speedup vs baseline: 4.5512x; 1.0808x over previous
//
#include <hip/hip_runtime.h>
#include <hip/hip_bf16.h>
#include <type_traits>

typedef __hip_bfloat16 bf16;

constexpr int N_  = 250000;
constexpr int E_  = 500000;
constexpr int B_  = 10000;
constexpr int H_  = 128;

typedef short s8v __attribute__((ext_vector_type(8)));   // 8 bf16 in 4 VGPRs
typedef float f4v __attribute__((ext_vector_type(4)));

__device__ __forceinline__ float b2f(bf16 v){ return __bfloat162float(v); }
__device__ __forceinline__ bf16  f2b(float v){ return __float2bfloat16(v); }
__device__ __forceinline__ float to_float(float v){ return v; }
__device__ __forceinline__ float to_float(bf16 v){ return __bfloat162float(v); }
__device__ __forceinline__ float lrelu_f(float v){ return v > 0.f ? v : 0.01f*v; }
__device__ __forceinline__ float sigmoid_f(float x){ return __builtin_amdgcn_rcpf(1.f+__expf(-x)); }
__device__ __forceinline__ float tanh_f(float x){ return 1.f - 2.f*__builtin_amdgcn_rcpf(__expf(2.f*x)+1.f); }
__device__ __forceinline__ float elu_f(float v){ return v > 0.f ? v : __expf(v)-1.f; }
__device__ __forceinline__ unsigned f2b_bits(float f){
  bf16 h=__float2bfloat16(f); unsigned short s; __builtin_memcpy(&s,&h,2); return (unsigned)s;
}
__device__ __forceinline__ void unp8(uint4 v, float* o){
  o[0]=__uint_as_float(v.x<<16); o[1]=__uint_as_float(v.x&0xffff0000u);
  o[2]=__uint_as_float(v.y<<16); o[3]=__uint_as_float(v.y&0xffff0000u);
  o[4]=__uint_as_float(v.z<<16); o[5]=__uint_as_float(v.z&0xffff0000u);
  o[6]=__uint_as_float(v.w<<16); o[7]=__uint_as_float(v.w&0xffff0000u);
}

// ---------------- consolidated fp32->bf16 weight copies (9 segments) -------
struct W2B { const float* s; bf16* d; int rows, ld, ow, cw; };
struct W2B9 { W2B seg[9]; };
__global__ void w2ball_k(W2B9 p){
  W2B g=p.seg[blockIdx.y];
  int i=blockIdx.x*256+threadIdx.x;
  if (i>=g.rows*g.ow) return;
  int r=i/g.ow, k=i-r*g.ow;
  g.d[i] = f2b(k<g.cw ? g.s[(size_t)r*g.ld+k] : 0.f);
}

// ---------------- lin1 via MFMA: [N,39] fp32 -> [N,128] bf16, lrelu --------
__global__ __launch_bounds__(256) void lin1_mfma_k(const float* __restrict__ X0, const bf16* __restrict__ Wb,
                            const float* __restrict__ bias, bf16* __restrict__ Y, int M){
  __shared__ __align__(16) bf16 sx[64][72];
  int wv=threadIdx.x>>6, lane=threadIdx.x&63;
  int n=lane&15, q=lane>>4;
  int c0=wv*32;
  s8v wB[2][2];
  #pragma unroll
  for (int ct=0;ct<2;ct++)
    #pragma unroll
    for (int kk=0;kk<2;kk++)
      wB[ct][kk]=*(const s8v*)(Wb+(size_t)(c0+ct*16+n)*64+kk*32+q*8);
  float bb[2];
  #pragma unroll
  for (int ct=0;ct<2;ct++) bb[ct]=bias[c0+ct*16+n];
  for (int i=threadIdx.x;i<64*25;i+=256){ int r=i/25,k=39+(i-(i/25)*25); sx[r][k]=f2b(0.f); }
  for (long r0=(long)blockIdx.x*64; r0<M; r0+=(long)gridDim.x*64){
    __syncthreads();
    for (int f=threadIdx.x; f<64*39; f+=256){
      int r=f/39, k=f-(f/39)*39; long row=r0+r;
      sx[r][k]= f2b(row<M ? X0[row*39+k] : 0.f);
    }
    __syncthreads();
    s8v a[4][2];
    #pragma unroll
    for (int rt=0;rt<4;rt++)
      #pragma unroll
      for (int kk=0;kk<2;kk++)
        a[rt][kk]=*(const s8v*)&sx[rt*16+n][kk*32+q*8];
    f4v acc[4][2];
    #pragma unroll
    for (int rt=0;rt<4;rt++)
      #pragma unroll
      for (int ct=0;ct<2;ct++) acc[rt][ct]=(f4v){0.f,0.f,0.f,0.f};
    #pragma unroll
    for (int kk=0;kk<2;kk++)
      #pragma unroll
      for (int rt=0;rt<4;rt++)
        #pragma unroll
        for (int ct=0;ct<2;ct++)
          acc[rt][ct]=__builtin_amdgcn_mfma_f32_16x16x32_bf16(a[rt][kk],wB[ct][kk],acc[rt][ct],0,0,0);
    #pragma unroll
    for (int ct=0;ct<2;ct++){
      int col=c0+ct*16+n;
      #pragma unroll
      for (int rt=0;rt<4;rt++){
        #pragma unroll
        for (int rg=0;rg<4;rg++){
          long row=r0+rt*16+q*4+rg;
          if (row<M) Y[row*128+col]=f2b(lrelu_f(acc[rt][ct][rg]+bb[ct]));
        }
      }
    }
  }
}

// ---- MFMA linear, weights in registers, grid-stride over 64-row tiles ----
template<int ACT>   // 0 none, 2 elu
__global__ __launch_bounds__(256) void lin_mfma_k(const bf16* __restrict__ X, const bf16* __restrict__ Wb,
                            const float* __restrict__ bias, bf16* __restrict__ Y, int M){
  int wv=threadIdx.x>>6, lane=threadIdx.x&63;
  int n=lane&15, q=lane>>4;
  int c0=wv*32;
  s8v wB[2][4];
  #pragma unroll
  for (int ct=0;ct<2;ct++)
    #pragma unroll
    for (int kk=0;kk<4;kk++)
      wB[ct][kk]=*(const s8v*)(Wb+(size_t)(c0+ct*16+n)*128+kk*32+q*8);
  float bb[2];
  #pragma unroll
  for (int ct=0;ct<2;ct++) bb[ct]=bias? bias[c0+ct*16+n]:0.f;
  for (long r0=(long)blockIdx.x*64; r0<M; r0+=(long)gridDim.x*64){
    s8v a[4][4];
    #pragma unroll
    for (int rt=0;rt<4;rt++){
      long row=r0+rt*16+n; if (row>=M) row=M-1;
      #pragma unroll
      for (int kk=0;kk<4;kk++) a[rt][kk]=*(const s8v*)(X+row*128+kk*32+q*8);
    }
    f4v acc[4][2];
    #pragma unroll
    for (int rt=0;rt<4;rt++)
      #pragma unroll
      for (int ct=0;ct<2;ct++) acc[rt][ct]=(f4v){0.f,0.f,0.f,0.f};
    #pragma unroll
    for (int kk=0;kk<4;kk++)
      #pragma unroll
      for (int rt=0;rt<4;rt++)
        #pragma unroll
        for (int ct=0;ct<2;ct++)
          acc[rt][ct]=__builtin_amdgcn_mfma_f32_16x16x32_bf16(a[rt][kk],wB[ct][kk],acc[rt][ct],0,0,0);
    #pragma unroll
    for (int ct=0;ct<2;ct++){
      int col=c0+ct*16+n;
      #pragma unroll
      for (int rt=0;rt<4;rt++){
        #pragma unroll
        for (int rg=0;rg<4;rg++){
          long row=r0+rt*16+q*4+rg;
          if (row<M){
            float v=acc[rt][ct][rg]+bb[ct];
            if (ACT==2) v=elu_f(v);
            Y[row*128+col]=f2b(v);
          }
        }
      }
    }
  }
}

// ---- MFMA fused GRU (atoms): LDS-staged tiles, double-buffered, 512 thr ----
// Block stages 32 rows of A and X once into LDS (padded stride 136);
// 8 waves each own a 16-col slice with all 6 gate weight slices in registers.
__global__ __launch_bounds__(512,1) void gru_mfma_k(const bf16* __restrict__ A, const bf16* __restrict__ X,
                            const bf16* __restrict__ Wih, const bf16* __restrict__ Whh,
                            const float* __restrict__ bih, const float* __restrict__ bhh,
                            bf16* __restrict__ dest, int M){
  __shared__ __align__(16) bf16 sA[2][32][136];
  __shared__ __align__(16) bf16 sX[2][32][136];
  int wv=threadIdx.x>>6, lane=threadIdx.x&63;
  int n=lane&15, q=lane>>4;
  int c0=wv*16;
  s8v wI[3][4], wH[3][4];
  #pragma unroll
  for (int g=0;g<3;g++)
    #pragma unroll
    for (int kk=0;kk<4;kk++){
      size_t off=((size_t)(g*128+c0+n))*128+kk*32+q*8;
      wI[g][kk]=*(const s8v*)(Wih+off);
      wH[g][kk]=*(const s8v*)(Whh+off);
    }
  int col=c0+n;
  float br =bih[col]+bhh[col];
  float bz =bih[128+col]+bhh[128+col];
  float bni=bih[256+col], bnh=bhh[256+col];

  int srow=wv*4+q;          // 0..31 staging row
  int schunk=n;             // 0..15 16B chunk within row
  long step=(long)gridDim.x*32;
  long r0=(long)blockIdx.x*32;
  int buf=0;
  {
    long rowg=r0+srow; if (rowg>=M) rowg=M-1;
    uint4 va=*(const uint4*)(A+rowg*128+schunk*8);
    uint4 vx=*(const uint4*)(X+rowg*128+schunk*8);
    *(uint4*)&sA[0][srow][schunk*8]=va;
    *(uint4*)&sX[0][srow][schunk*8]=vx;
  }
  __syncthreads();
  for (; r0<M; r0+=step){
    long rn=r0+step;
    uint4 va, vx; bool pre = rn<M;
    if (pre){
      long rowg=rn+srow; if (rowg>=M) rowg=M-1;
      va=*(const uint4*)(A+rowg*128+schunk*8);
      vx=*(const uint4*)(X+rowg*128+schunk*8);
    }
    f4v acc[6][2];
    #pragma unroll
    for (int g=0;g<6;g++)
      #pragma unroll
      for (int rt=0;rt<2;rt++) acc[g][rt]=(f4v){0.f,0.f,0.f,0.f};
    #pragma unroll
    for (int kk=0;kk<4;kk++){
      s8v aA[2], aX[2];
      #pragma unroll
      for (int rt=0;rt<2;rt++){
        aA[rt]=*(const s8v*)&sA[buf][rt*16+n][(kk*4+q)*8];
        aX[rt]=*(const s8v*)&sX[buf][rt*16+n][(kk*4+q)*8];
      }
      #pragma unroll
      for (int g=0;g<3;g++)
        #pragma unroll
        for (int rt=0;rt<2;rt++){
          acc[g  ][rt]=__builtin_amdgcn_mfma_f32_16x16x32_bf16(aA[rt],wI[g][kk],acc[g  ][rt],0,0,0);
          acc[3+g][rt]=__builtin_amdgcn_mfma_f32_16x16x32_bf16(aX[rt],wH[g][kk],acc[3+g][rt],0,0,0);
        }
    }
    float xv[2][4];
    #pragma unroll
    for (int rt=0;rt<2;rt++)
      #pragma unroll
      for (int rg=0;rg<4;rg++)
        xv[rt][rg]=b2f(sX[buf][rt*16+q*4+rg][col]);
    #pragma unroll
    for (int rt=0;rt<2;rt++){
      #pragma unroll
      for (int rg=0;rg<4;rg++){
        long row=r0+rt*16+q*4+rg;
        if (row<M){
          float rgate=sigmoid_f(acc[0][rt][rg]+acc[3][rt][rg]+br);
          float zgate=sigmoid_f(acc[1][rt][rg]+acc[4][rt][rg]+bz);
          float nn=tanh_f(acc[2][rt][rg]+bni + rgate*(acc[5][rt][rg]+bnh));
          float o=(1.f-zgate)*nn + zgate*xv[rt][rg];
          dest[row*128+col]=f2b(fmaxf(o,0.f));
        }
      }
    }
    if (pre){
      *(uint4*)&sA[buf^1][srow][schunk*8]=va;
      *(uint4*)&sX[buf^1][srow][schunk*8]=vx;
    }
    __syncthreads();
    buf^=1;
  }
}

// ------- scalar fused GRU (molecules, fp32 state) ----
__global__ __launch_bounds__(256) void gru_scalar_k(const float* __restrict__ A, const float* __restrict__ X,
                            const float* __restrict__ Wih, const float* __restrict__ Whh,
                            const float* __restrict__ bih, const float* __restrict__ bhh,
                            float* __restrict__ dest, int M){
  __shared__ unsigned sW[6][32*66];
  __shared__ float sA[8][132], sX[8][132];
  __shared__ float sbi[3][32], sbh[3][32];
  int c0 = blockIdx.y*32;
  for (int i=threadIdx.x; i<6*32*64; i+=256){
    int m=i>>11, r=i&2047, c=r>>6, k2=r&63;
    const float* base = (m<3)? Wih : Whh;
    int g = (m<3)? m : m-3;
    const float* wp = base + ((size_t)(g*128 + c0 + c))*128 + 2*k2;
    sW[m][c*66 + k2] = f2b_bits(wp[0]) | (f2b_bits(wp[1])<<16);
  }
  if (threadIdx.x < 96){
    int g=threadIdx.x>>5, c=threadIdx.x&31;
    sbi[g][c]=bih[g*128+c0+c]; sbh[g][c]=bhh[g*128+c0+c];
  }
  __syncthreads();
  int sub=threadIdx.x>>5, c=threadIdx.x&31;
  for (long r0=(long)blockIdx.x*8; r0<M; r0+=(long)gridDim.x*8){
    __syncthreads();
    for (int i=threadIdx.x;i<8*16;i+=256){
      int rr=i>>4, q=i&15; long row=r0+rr;
      if (row<M){
        *(float4*)&sA[rr][q*8]   = *(const float4*)(A+row*128+q*8);
        *(float4*)&sA[rr][q*8+4] = *(const float4*)(A+row*128+q*8+4);
        *(float4*)&sX[rr][q*8]   = *(const float4*)(X+row*128+q*8);
        *(float4*)&sX[rr][q*8+4] = *(const float4*)(X+row*128+q*8+4);
      } else {
        float4 z=make_float4(0,0,0,0);
        *(float4*)&sA[rr][q*8]=z; *(float4*)&sA[rr][q*8+4]=z;
        *(float4*)&sX[rr][q*8]=z; *(float4*)&sX[rr][q*8+4]=z;
      }
    }
    __syncthreads();
    long row=r0+sub;
    if (row<M){
      const unsigned* wri=&sW[0][c*66]; const unsigned* wzi=&sW[1][c*66]; const unsigned* wni=&sW[2][c*66];
      const unsigned* wrh=&sW[3][c*66]; const unsigned* wzh=&sW[4][c*66]; const unsigned* wnh=&sW[5][c*66];
      const float2* xa=(const float2*)sA[sub]; const float2* xb=(const float2*)sX[sub];
      float ari=0,azi=0,ani=0,arh=0,azh=0,anh=0;
      #pragma unroll 8
      for (int k2=0;k2<64;k2++){
        float2 av=xa[k2], bv=xb[k2];
        unsigned u;
        u=wri[k2]; ari += av.x*__uint_as_float(u<<16) + av.y*__uint_as_float(u&0xffff0000u);
        u=wzi[k2]; azi += av.x*__uint_as_float(u<<16) + av.y*__uint_as_float(u&0xffff0000u);
        u=wni[k2]; ani += av.x*__uint_as_float(u<<16) + av.y*__uint_as_float(u&0xffff0000u);
        u=wrh[k2]; arh += bv.x*__uint_as_float(u<<16) + bv.y*__uint_as_float(u&0xffff0000u);
        u=wzh[k2]; azh += bv.x*__uint_as_float(u<<16) + bv.y*__uint_as_float(u&0xffff0000u);
        u=wnh[k2]; anh += bv.x*__uint_as_float(u<<16) + bv.y*__uint_as_float(u&0xffff0000u);
      }
      float rg = sigmoid_f(ari+arh+sbi[0][c]+sbh[0][c]);
      float zg = sigmoid_f(azi+azh+sbi[1][c]+sbh[1][c]);
      float nn = tanh_f(ani+sbi[2][c] + rg*(anh+sbh[2][c]));
      float xv = sX[sub][c0+c];
      float o  = (1.f-zg)*nn + zg*xv;
      dest[row*128+c0+c] = fmaxf(o,0.f);
    }
  }
}

// ---------------- row dot(s) ----------------
template<typename TY>
__global__ void rowdot_k(const TY* __restrict__ Y, const float* __restrict__ v,
                         float* __restrict__ d, int M){
  __shared__ float sv[128];
  if (threadIdx.x<128) sv[threadIdx.x]=v[threadIdx.x];
  __syncthreads();
  int wv=threadIdx.x>>6, lane=threadIdx.x&63;
  long row=(long)blockIdx.x*4+wv;
  if (row>=M) return;
  float a=to_float(Y[row*128+lane])*sv[lane]+to_float(Y[row*128+64+lane])*sv[64+lane];
  #pragma unroll
  for (int o=32;o;o>>=1) a+=__shfl_xor(a,o);
  if (!lane) d[row]=a;
}

__global__ void rowdot2_k(const bf16* __restrict__ Y, const float* __restrict__ v1,
                          const float* __restrict__ v2, float* __restrict__ d1,
                          float* __restrict__ d2, int M){
  __shared__ float sv1[128], sv2[128];
  if (threadIdx.x<128){ sv1[threadIdx.x]=v1[threadIdx.x]; sv2[threadIdx.x]=v2[threadIdx.x]; }
  __syncthreads();
  int wv=threadIdx.x>>6, lane=threadIdx.x&63;
  long row=(long)blockIdx.x*4+wv;
  if (row>=M) return;
  float x0=b2f(Y[row*128+lane]), x1=b2f(Y[row*128+64+lane]);
  float a=x0*sv1[lane]+x1*sv1[64+lane];
  float b=x0*sv2[lane]+x1*sv2[64+lane];
  #pragma unroll
  for (int o=32;o;o>>=1){ a+=__shfl_xor(a,o); b+=__shfl_xor(b,o); }
  if (!lane){ d1[row]=a; d2[row]=b; }
}

// ---------------- GATE edge logits (writes CSR-permuted) ----------------
__global__ __launch_bounds__(256) void gate_edge_logits_k(const bf16* __restrict__ u, const float* __restrict__ ea,
                                   const float* __restrict__ gW1, const float* __restrict__ att_l,
                                   const float* __restrict__ ddst, const int* __restrict__ src,
                                   const int* __restrict__ dst, const int* __restrict__ epos,
                                   float* __restrict__ elog, int E){
  __shared__ float sWb[10][128];
  __shared__ float sal[128];
  for (int i=threadIdx.x;i<10*128;i+=256){ int k=i>>7,c=i&127; sWb[k][c]=gW1[(size_t)c*138+128+k]; }
  if (threadIdx.x<128) sal[threadIdx.x]=att_l[threadIdx.x];
  __syncthreads();
  int wv=threadIdx.x>>6, lane=threadIdx.x&63;
  for (long e=(long)blockIdx.x*4+wv; e<E; e+=(long)gridDim.x*4){
    int sj=src[e], di=dst[e];
    float eal[10];
    #pragma unroll
    for (int k=0;k<10;k++) eal[k]=ea[(size_t)e*10+k];
    float acc=0.f;
    #pragma unroll
    for (int j=0;j<2;j++){
      int cc=lane+64*j;
      float v=0.f;
      #pragma unroll
      for (int k=0;k<10;k++) v+=eal[k]*sWb[k][cc];
      v+=b2f(u[(size_t)sj*128+cc]);
      acc+=lrelu_f(v)*sal[cc];
    }
    #pragma unroll
    for (int o=32;o;o>>=1) acc+=__shfl_xor(acc,o);
    if (!lane) elog[epos[e]]=lrelu_f(acc+ddst[di]);
  }
}

// ---------------- conv edge logits (writes CSR-permuted) ----------------
__global__ void conv_logit_k(const float* __restrict__ dsrc, const float* __restrict__ ddst,
                             const int* __restrict__ src, const int* __restrict__ dst,
                             const int* __restrict__ epos, float* __restrict__ elog, int n){
  int e=blockIdx.x*256+threadIdx.x;
  if (e<n) elog[epos[e]]=lrelu_f(dsrc[src[e]]+ddst[dst[e]]);
}

// ------- per-node softmax + weighted sum; 16 lanes per node, contiguous CSR --
template<int ACT>   // 0 none, 1 relu(S+bias)
__global__ void node_gather_k(const float* __restrict__ elog, const int* __restrict__ srcp,
                              const int* __restrict__ ptr, const bf16* __restrict__ V,
                              const float* __restrict__ bias, bf16* __restrict__ S, int M){
  int wv=threadIdx.x>>6, lane=threadIdx.x&63;
  int g=lane>>4, t=lane&15;
  int node=blockIdx.x*16 + wv*4 + g;
  if (node>=M) return;
  int p0=ptr[node], p1=ptr[node+1];
  float m=-INFINITY;
  for (int p=p0+t;p<p1;p+=16) m=fmaxf(m,elog[p]);
  #pragma unroll
  for (int o=8;o;o>>=1) m=fmaxf(m,__shfl_xor(m,o));
  float ssum=0.f;
  for (int p=p0+t;p<p1;p+=16) ssum+=__expf(elog[p]-m);
  #pragma unroll
  for (int o=8;o;o>>=1) ssum+=__shfl_xor(ssum,o);
  float inv=1.f/(ssum+1e-16f);
  float acc[8]={0,0,0,0,0,0,0,0};
  for (int p=p0;p<p1;p++){
    float al=__expf(elog[p]-m)*inv;
    uint4 v=*(const uint4*)(V+(size_t)srcp[p]*128+t*8);
    float xf[8]; unp8(v,xf);
    #pragma unroll
    for (int j=0;j<8;j++) acc[j]+=al*xf[j];
  }
  if (ACT==1){
    #pragma unroll
    for (int j=0;j<8;j++) acc[j]=fmaxf(acc[j]+bias[t*8+j],0.f);
  }
  uint4 o;
  o.x=f2b_bits(acc[0])|(f2b_bits(acc[1])<<16);
  o.y=f2b_bits(acc[2])|(f2b_bits(acc[3])<<16);
  o.z=f2b_bits(acc[4])|(f2b_bits(acc[5])<<16);
  o.w=f2b_bits(acc[6])|(f2b_bits(acc[7])<<16);
  *(uint4*)(S+(size_t)node*128+t*8)=o;
}

// ---------------- molecule kernels ----------------
__global__ void mol_ptr_k(const int* __restrict__ batch, int* __restrict__ mptr, int n, int Bn){
  int b=blockIdx.x*256+threadIdx.x; if (b>Bn) return;
  if (b==Bn){ mptr[Bn]=n; return; }
  int lo=0, hi=n;
  while (lo<hi){ int mid=(lo+hi)>>1; if (batch[mid]<b) lo=mid+1; else hi=mid; }
  mptr[b]=lo;
}

__global__ void mol_sum_k(const bf16* __restrict__ x, const int* __restrict__ mptr,
                          float* __restrict__ out, int Bn){
  int wv=threadIdx.x>>6, lane=threadIdx.x&63;
  int b=blockIdx.x*4+wv; if (b>=Bn) return;
  int p0=mptr[b], p1=mptr[b+1];
  float a0=0.f,a1=0.f;
  for (int i=p0;i<p1;i++){ a0+=b2f(x[(size_t)i*128+lane]); a1+=b2f(x[(size_t)i*128+64+lane]); }
  out[(size_t)b*128+lane]=fmaxf(a0,0.f); out[(size_t)b*128+64+lane]=fmaxf(a1,0.f);
}

__global__ void fold_att_k(const float* __restrict__ W, const float* __restrict__ att,
                           float* __restrict__ wdd){
  int k=threadIdx.x; float a=0.f;
  for (int c=0;c<128;c++) a+=att[c]*W[(size_t)c*128+k];
  wdd[k]=a;
}

__global__ void mol_logit_k(const float* __restrict__ dsrc, const float* __restrict__ dd,
                            const int* __restrict__ batch, float* __restrict__ alog, int n){
  int i=blockIdx.x*256+threadIdx.x; if (i<n) alog[i]=lrelu_f(dsrc[i]+dd[batch[i]]);
}

__global__ void mol_gather_k(const float* __restrict__ alog, const int* __restrict__ mptr,
                             const bf16* __restrict__ xs, const float* __restrict__ bias,
                             float* __restrict__ hb, int Bn){
  int wv=threadIdx.x>>6, lane=threadIdx.x&63;
  int b=blockIdx.x*4+wv; if (b>=Bn) return;
  int p0=mptr[b], p1=mptr[b+1];
  float m=-INFINITY;
  for (int i=p0+lane;i<p1;i+=64) m=fmaxf(m,alog[i]);
  #pragma unroll
  for (int o=32;o;o>>=1) m=fmaxf(m,__shfl_xor(m,o));
  float ssum=0.f;
  for (int i=p0+lane;i<p1;i+=64) ssum+=__expf(alog[i]-m);
  #pragma unroll
  for (int o=32;o;o>>=1) ssum+=__shfl_xor(ssum,o);
  float inv=1.f/(ssum+1e-16f);
  float a0=0.f,a1=0.f;
  for (int i=p0;i<p1;i++){
    float al=__expf(alog[i]-m)*inv;
    a0+=al*b2f(xs[(size_t)i*128+lane]); a1+=al*b2f(xs[(size_t)i*128+64+lane]);
  }
  hb[(size_t)b*128+lane]=elu_f(a0+bias[lane]);
  hb[(size_t)b*128+64+lane]=elu_f(a1+bias[64+lane]);
}

// ---------------- final head ----------------
__global__ void final_head_k(const float* __restrict__ out, const float* __restrict__ W2,
                             const float* __restrict__ b2, const float* __restrict__ Wh,
                             const float* __restrict__ bh, float* __restrict__ y, int Bn){
  __shared__ float srow[128]; __shared__ float sred[128];
  int b=blockIdx.x, c=threadIdx.x;
  srow[c]=out[(size_t)b*128+c]; __syncthreads();
  float acc=b2[c];
  const float* wr=&W2[(size_t)c*128];
  #pragma unroll 8
  for (int k=0;k<128;k++) acc+=srow[k]*wr[k];
  sred[c]=acc*Wh[c]; __syncthreads();
  for (int o=64;o;o>>=1){ if (c<o) sred[c]+=sred[c+o]; __syncthreads(); }
  if (c==0) y[b]=sred[0]+bh[0];
}

// ---------------- CSR build ----------------
__global__ void zero_i32_k(int* p, int n){ int i=blockIdx.x*256+threadIdx.x; if (i<n) p[i]=0; }
__global__ void hist_k(const int* __restrict__ dst, int* __restrict__ deg, int n){
  int e=blockIdx.x*256+threadIdx.x; if (e<n) atomicAdd(&deg[dst[e]],1);
}
__global__ void scan1_k(const int* __restrict__ deg, int* __restrict__ ptr,
                        int* __restrict__ part, int n){
  __shared__ int sd[256];
  int base=blockIdx.x*1024, tid=threadIdx.x;
  int v[4]; int ssum=0;
  #pragma unroll
  for (int j=0;j<4;j++){ int idx=base+tid*4+j; v[j]= idx<n? deg[idx]:0; ssum+=v[j]; }
  sd[tid]=ssum; __syncthreads();
  for (int o=1;o<256;o<<=1){ int t = tid>=o? sd[tid-o]:0; __syncthreads(); sd[tid]+=t; __syncthreads(); }
  int excl=sd[tid]-ssum;
  #pragma unroll
  for (int j=0;j<4;j++){ int idx=base+tid*4+j; if (idx<n) ptr[idx]=excl; excl+=v[j]; }
  if (tid==255) part[blockIdx.x]=sd[255];
}
__global__ void scan2_k(int* part, int nb){
  __shared__ int sd[512];
  int tid=threadIdx.x;
  int v= tid<nb? part[tid]:0; sd[tid]=v; __syncthreads();
  for (int o=1;o<512;o<<=1){ int t = tid>=o? sd[tid-o]:0; __syncthreads(); sd[tid]+=t; __syncthreads(); }
  if (tid<nb) part[tid]=sd[tid]-v;
}
__global__ void scan3_k(int* __restrict__ ptr, const int* __restrict__ part,
                        int* __restrict__ wofs, int n, int total){
  int i=blockIdx.x*256+threadIdx.x;
  if (i<n){ int val=ptr[i]+part[i>>10]; ptr[i]=val; wofs[i]=val; }
  if (i==0) ptr[n]=total;
}
__global__ void fill_csr_k(const int* __restrict__ dst, const int* __restrict__ src,
                           int* __restrict__ wofs, int* __restrict__ srcp,
                           int* __restrict__ epos, int n){
  int e=blockIdx.x*256+threadIdx.x;
  if (e<n){ int p=atomicAdd(&wofs[dst[e]],1); srcp[p]=src[e]; epos[e]=p; }
}

// =====================================================================
extern "C" void kernel_launch(void* const* d_in, const int* in_sizes, int n_in,
                              void* d_out, int out_size, void* d_ws, size_t ws_size,
                              hipStream_t stream){
  (void)in_sizes; (void)n_in; (void)out_size; (void)ws_size;
  const float* x0        =(const float*)d_in[0];
  const float* edge_attr =(const float*)d_in[1];
  const float* W_lin1    =(const float*)d_in[2];
  const float* b_lin1    =(const float*)d_in[3];
  const float* gate_W1   =(const float*)d_in[4];
  const float* gate_W2   =(const float*)d_in[5];
  const float* gate_att_l=(const float*)d_in[6];
  const float* gate_att_r=(const float*)d_in[7];
  const float* gate_bias =(const float*)d_in[8];
  const float* g1_Wih=(const float*)d_in[9];  const float* g1_Whh=(const float*)d_in[10];
  const float* g1_bih=(const float*)d_in[11]; const float* g1_bhh=(const float*)d_in[12];
  const float* conv_W=(const float*)d_in[13];
  const float* conv_att_src=(const float*)d_in[14];
  const float* conv_att_dst=(const float*)d_in[15];
  const float* conv_bias   =(const float*)d_in[16];
  const float* g2_Wih=(const float*)d_in[17]; const float* g2_Whh=(const float*)d_in[18];
  const float* g2_bih=(const float*)d_in[19]; const float* g2_bhh=(const float*)d_in[20];
  const float* mol_W=(const float*)d_in[21];
  const float* mol_att_src=(const float*)d_in[22];
  const float* mol_att_dst=(const float*)d_in[23];
  const float* mol_bias   =(const float*)d_in[24];
  const float* gm_Wih=(const float*)d_in[25]; const float* gm_Whh=(const float*)d_in[26];
  const float* gm_bih=(const float*)d_in[27]; const float* gm_bhh=(const float*)d_in[28];
  const float* W_lin2=(const float*)d_in[29]; const float* b_lin2=(const float*)d_in[30];
  const float* W_head=(const float*)d_in[31]; const float* b_head=(const float*)d_in[32];
  const int* ei   =(const int*)d_in[33];
  const int* batch=(const int*)d_in[34];
  const int* src=ei; const int* dst=ei+E_;
  float* y=(float*)d_out;

  // ---- workspace layout (~222 MiB total) ----
  const size_t NH=(size_t)N_*H_, BH=(size_t)B_*H_;
  bf16* b0  =(bf16*)d_ws;           // N*H bf16
  bf16* b1  =b0+NH;                 // N*H bf16
  bf16* b2v =b1+NH;                 // N*H bf16
  float* outA=(float*)(b2v+NH);     // B*H fp32
  float* outB=outA+BH;
  float* hb  =outB+BH;
  float* elog=hb+BH;                // E
  float* dsrc=elog+E_;              // N
  float* ddst=dsrc+N_;              // N
  float* alog=ddst+N_;              // N
  float* wdd =alog+N_;              // 128
  float* dd  =wdd+128;              // B
  int* deg =(int*)(dd+B_);          // N
  int* ptr =deg+N_;                 // N+1
  int* wofs=ptr+N_+1;               // N
  int* part=wofs+N_;                // 512
  int* mptr=part+512;               // B+1
  int* srcp=mptr+B_+1;              // E
  int* epos=srcp+E_;                // E
  uintptr_t wbase=((uintptr_t)(epos+E_)+255)&~(uintptr_t)255;
  bf16* wb_gw1 =(bf16*)wbase;        // 128*128
  bf16* wb_gw2 =wb_gw1 +128*128;
  bf16* wb_conv=wb_gw2 +128*128;
  bf16* wb_mol =wb_conv+128*128;
  bf16* wb_g1i =wb_mol +128*128;     // 384*128
  bf16* wb_g1h =wb_g1i +384*128;
  bf16* wb_g2i =wb_g1h +384*128;
  bf16* wb_g2h =wb_g2i +384*128;
  bf16* wb_l1  =wb_g2h +384*128;     // 128*64 (lin1, K padded 39->64)

  // ---- weight conversions (one dispatch, 9 segments) ----
  W2B9 wp;
  wp.seg[0]={gate_W1,wb_gw1,128,138,128,128};
  wp.seg[1]={gate_W2,wb_gw2,128,128,128,128};
  wp.seg[2]={conv_W ,wb_conv,128,128,128,128};
  wp.seg[3]={mol_W  ,wb_mol ,128,128,128,128};
  wp.seg[4]={g1_Wih,wb_g1i,384,128,128,128};
  wp.seg[5]={g1_Whh,wb_g1h,384,128,128,128};
  wp.seg[6]={g2_Wih,wb_g2i,384,128,128,128};
  wp.seg[7]={g2_Whh,wb_g2h,384,128,128,128};
  wp.seg[8]={W_lin1,wb_l1 ,128, 39, 64, 39};
  w2ball_k<<<dim3(192,9),256,0,stream>>>(wp);

  // ---- CSR by dst (+ permutation arrays) + molecule ranges ----
  zero_i32_k<<<(N_+255)/256,256,0,stream>>>(deg,N_);
  hist_k<<<(E_+255)/256,256,0,stream>>>(dst,deg,E_);
  int nb=(N_+1023)/1024;
  scan1_k<<<nb,256,0,stream>>>(deg,ptr,part,N_);
  scan2_k<<<1,512,0,stream>>>(part,nb);
  scan3_k<<<(N_+255)/256,256,0,stream>>>(ptr,part,wofs,N_,E_);
  fill_csr_k<<<(E_+255)/256,256,0,stream>>>(dst,src,wofs,srcp,epos,E_);
  mol_ptr_k<<<(B_+1+255)/256,256,0,stream>>>(batch,mptr,N_,B_);

  // ---- lin1: X -> b0 (MFMA) ----
  lin1_mfma_k<<<1024,256,0,stream>>>(x0,wb_l1,b_lin1,b0,N_);

  const int GL=768, GG=1024, GN=(N_+15)/16;
  // ---- GATEConv ----
  lin_mfma_k<0><<<GL,256,0,stream>>>(b0,wb_gw1,nullptr,b1,N_);             // u -> b1
  rowdot_k<bf16><<<(N_+3)/4,256,0,stream>>>(b0,gate_att_r,ddst,N_);
  gate_edge_logits_k<<<4096,256,0,stream>>>(b1,edge_attr,gate_W1,gate_att_l,ddst,src,dst,epos,elog,E_);
  node_gather_k<0><<<GN,256,0,stream>>>(elog,srcp,ptr,b0,nullptr,b2v,N_);  // S -> b2
  lin_mfma_k<2><<<GL,256,0,stream>>>(b2v,wb_gw2,gate_bias,b1,N_);          // h=elu -> b1
  // ---- GRU1: x=relu(gru(h=b1, x=b0)) -> b2 ----
  gru_mfma_k<<<GG,512,0,stream>>>(b1,b0,wb_g1i,wb_g1h,g1_bih,g1_bhh,b2v,N_);
  // ---- atom GATConv (x lives in b2) ----
  lin_mfma_k<0><<<GL,256,0,stream>>>(b2v,wb_conv,nullptr,b0,N_);           // xl -> b0
  rowdot2_k<<<(N_+3)/4,256,0,stream>>>(b0,conv_att_src,conv_att_dst,dsrc,ddst,N_);
  conv_logit_k<<<(E_+255)/256,256,0,stream>>>(dsrc,ddst,src,dst,epos,elog,E_);
  node_gather_k<1><<<GN,256,0,stream>>>(elog,srcp,ptr,b0,conv_bias,b1,N_); // h=relu(S+bias) -> b1
  // ---- GRU2: x=relu(gru(h=b1, x=b2)) -> b0 ----
  gru_mfma_k<<<GG,512,0,stream>>>(b1,b2v,wb_g2i,wb_g2h,g2_bih,g2_bhh,b0,N_);
  // ---- readout (x lives in b0) ----
  mol_sum_k<<<(B_+3)/4,256,0,stream>>>(b0,mptr,outA,B_);
  lin_mfma_k<0><<<GL,256,0,stream>>>(b0,wb_mol,nullptr,b1,N_);             // xs -> b1
  rowdot_k<bf16><<<(N_+3)/4,256,0,stream>>>(b1,mol_att_src,dsrc,N_);
  fold_att_k<<<1,128,0,stream>>>(mol_W,mol_att_dst,wdd);
  float* out_cur=outA; float* out_nxt=outB;
  dim3 gm(157,4);
  for (int ts=0; ts<2; ts++){
    rowdot_k<float><<<(B_+3)/4,256,0,stream>>>(out_cur,wdd,dd,B_);
    mol_logit_k<<<(N_+255)/256,256,0,stream>>>(dsrc,dd,batch,alog,N_);
    mol_gather_k<<<(B_+3)/4,256,0,stream>>>(alog,mptr,b1,mol_bias,hb,B_);
    gru_scalar_k<<<gm,256,0,stream>>>(hb,out_cur,gm_Wih,gm_Whh,gm_bih,gm_bhh,out_nxt,B_);
    float* tmp=out_cur; out_cur=out_nxt; out_nxt=tmp;
  }
  final_head_k<<<B_,128,0,stream>>>(out_cur,W_lin2,b_lin2,W_head,b_head,y,B_);
}

// Round 9
// 1284.086 us; speedup vs baseline: 4.6160x; 1.0142x over previous
//
#include <hip/hip_runtime.h>
#include <hip/hip_bf16.h>
#include <type_traits>

typedef __hip_bfloat16 bf16;

constexpr int N_  = 250000;
constexpr int E_  = 500000;
constexpr int B_  = 10000;
constexpr int H_  = 128;

typedef short s8v __attribute__((ext_vector_type(8)));   // 8 bf16 in 4 VGPRs
typedef float f4v __attribute__((ext_vector_type(4)));

__device__ __forceinline__ float b2f(bf16 v){ return __bfloat162float(v); }
__device__ __forceinline__ bf16  f2b(float v){ return __float2bfloat16(v); }
__device__ __forceinline__ float to_float(float v){ return v; }
__device__ __forceinline__ float to_float(bf16 v){ return __bfloat162float(v); }
__device__ __forceinline__ float lrelu_f(float v){ return v > 0.f ? v : 0.01f*v; }
__device__ __forceinline__ float sigmoid_f(float x){ return __builtin_amdgcn_rcpf(1.f+__expf(-x)); }
__device__ __forceinline__ float tanh_f(float x){ return 1.f - 2.f*__builtin_amdgcn_rcpf(__expf(2.f*x)+1.f); }
__device__ __forceinline__ float elu_f(float v){ return v > 0.f ? v : __expf(v)-1.f; }
__device__ __forceinline__ unsigned f2b_bits(float f){
  bf16 h=__float2bfloat16(f); unsigned short s; __builtin_memcpy(&s,&h,2); return (unsigned)s;
}
__device__ __forceinline__ void unp8(uint4 v, float* o){
  o[0]=__uint_as_float(v.x<<16); o[1]=__uint_as_float(v.x&0xffff0000u);
  o[2]=__uint_as_float(v.y<<16); o[3]=__uint_as_float(v.y&0xffff0000u);
  o[4]=__uint_as_float(v.z<<16); o[5]=__uint_as_float(v.z&0xffff0000u);
  o[6]=__uint_as_float(v.w<<16); o[7]=__uint_as_float(v.w&0xffff0000u);
}

// ---------------- consolidated fp32->bf16 weight copies (9 segments) -------
struct W2B { const float* s; bf16* d; int rows, ld, ow, cw; };
struct W2B9 { W2B seg[9]; };
__global__ void w2ball_k(W2B9 p){
  W2B g=p.seg[blockIdx.y];
  int i=blockIdx.x*256+threadIdx.x;
  if (i>=g.rows*g.ow) return;
  int r=i/g.ow, k=i-r*g.ow;
  g.d[i] = f2b(k<g.cw ? g.s[(size_t)r*g.ld+k] : 0.f);
}

// ---------------- lin1 via MFMA: [N,39] fp32 -> [N,128] bf16, lrelu --------
__global__ __launch_bounds__(256) void lin1_mfma_k(const float* __restrict__ X0, const bf16* __restrict__ Wb,
                            const float* __restrict__ bias, bf16* __restrict__ Y, int M){
  __shared__ __align__(16) bf16 sx[64][72];
  int wv=threadIdx.x>>6, lane=threadIdx.x&63;
  int n=lane&15, q=lane>>4;
  int c0=wv*32;
  s8v wB[2][2];
  #pragma unroll
  for (int ct=0;ct<2;ct++)
    #pragma unroll
    for (int kk=0;kk<2;kk++)
      wB[ct][kk]=*(const s8v*)(Wb+(size_t)(c0+ct*16+n)*64+kk*32+q*8);
  float bb[2];
  #pragma unroll
  for (int ct=0;ct<2;ct++) bb[ct]=bias[c0+ct*16+n];
  for (int i=threadIdx.x;i<64*25;i+=256){ int r=i/25,k=39+(i-(i/25)*25); sx[r][k]=f2b(0.f); }
  for (long r0=(long)blockIdx.x*64; r0<M; r0+=(long)gridDim.x*64){
    __syncthreads();
    for (int f=threadIdx.x; f<64*39; f+=256){
      int r=f/39, k=f-(f/39)*39; long row=r0+r;
      sx[r][k]= f2b(row<M ? X0[row*39+k] : 0.f);
    }
    __syncthreads();
    s8v a[4][2];
    #pragma unroll
    for (int rt=0;rt<4;rt++)
      #pragma unroll
      for (int kk=0;kk<2;kk++)
        a[rt][kk]=*(const s8v*)&sx[rt*16+n][kk*32+q*8];
    f4v acc[4][2];
    #pragma unroll
    for (int rt=0;rt<4;rt++)
      #pragma unroll
      for (int ct=0;ct<2;ct++) acc[rt][ct]=(f4v){0.f,0.f,0.f,0.f};
    #pragma unroll
    for (int kk=0;kk<2;kk++)
      #pragma unroll
      for (int rt=0;rt<4;rt++)
        #pragma unroll
        for (int ct=0;ct<2;ct++)
          acc[rt][ct]=__builtin_amdgcn_mfma_f32_16x16x32_bf16(a[rt][kk],wB[ct][kk],acc[rt][ct],0,0,0);
    #pragma unroll
    for (int ct=0;ct<2;ct++){
      int col=c0+ct*16+n;
      #pragma unroll
      for (int rt=0;rt<4;rt++){
        #pragma unroll
        for (int rg=0;rg<4;rg++){
          long row=r0+rt*16+q*4+rg;
          if (row<M) Y[row*128+col]=f2b(lrelu_f(acc[rt][ct][rg]+bb[ct]));
        }
      }
    }
  }
}

// ---- MFMA linear, weights in registers, grid-stride over 64-row tiles ----
template<int ACT>   // 0 none, 2 elu
__global__ __launch_bounds__(256) void lin_mfma_k(const bf16* __restrict__ X, const bf16* __restrict__ Wb,
                            const float* __restrict__ bias, bf16* __restrict__ Y, int M){
  int wv=threadIdx.x>>6, lane=threadIdx.x&63;
  int n=lane&15, q=lane>>4;
  int c0=wv*32;
  s8v wB[2][4];
  #pragma unroll
  for (int ct=0;ct<2;ct++)
    #pragma unroll
    for (int kk=0;kk<4;kk++)
      wB[ct][kk]=*(const s8v*)(Wb+(size_t)(c0+ct*16+n)*128+kk*32+q*8);
  float bb[2];
  #pragma unroll
  for (int ct=0;ct<2;ct++) bb[ct]=bias? bias[c0+ct*16+n]:0.f;
  for (long r0=(long)blockIdx.x*64; r0<M; r0+=(long)gridDim.x*64){
    s8v a[4][4];
    #pragma unroll
    for (int rt=0;rt<4;rt++){
      long row=r0+rt*16+n; if (row>=M) row=M-1;
      #pragma unroll
      for (int kk=0;kk<4;kk++) a[rt][kk]=*(const s8v*)(X+row*128+kk*32+q*8);
    }
    f4v acc[4][2];
    #pragma unroll
    for (int rt=0;rt<4;rt++)
      #pragma unroll
      for (int ct=0;ct<2;ct++) acc[rt][ct]=(f4v){0.f,0.f,0.f,0.f};
    #pragma unroll
    for (int kk=0;kk<4;kk++)
      #pragma unroll
      for (int rt=0;rt<4;rt++)
        #pragma unroll
        for (int ct=0;ct<2;ct++)
          acc[rt][ct]=__builtin_amdgcn_mfma_f32_16x16x32_bf16(a[rt][kk],wB[ct][kk],acc[rt][ct],0,0,0);
    #pragma unroll
    for (int ct=0;ct<2;ct++){
      int col=c0+ct*16+n;
      #pragma unroll
      for (int rt=0;rt<4;rt++){
        #pragma unroll
        for (int rg=0;rg<4;rg++){
          long row=r0+rt*16+q*4+rg;
          if (row<M){
            float v=acc[rt][ct][rg]+bb[ct];
            if (ACT==2) v=elu_f(v);
            Y[row*128+col]=f2b(v);
          }
        }
      }
    }
  }
}

// ---- MFMA fused GRU (atoms): LDS-staged tiles, double-buffered, 512 thr ----
__global__ __launch_bounds__(512,1) void gru_mfma_k(const bf16* __restrict__ A, const bf16* __restrict__ X,
                            const bf16* __restrict__ Wih, const bf16* __restrict__ Whh,
                            const float* __restrict__ bih, const float* __restrict__ bhh,
                            bf16* __restrict__ dest, int M){
  __shared__ __align__(16) bf16 sA[2][32][136];
  __shared__ __align__(16) bf16 sX[2][32][136];
  int wv=threadIdx.x>>6, lane=threadIdx.x&63;
  int n=lane&15, q=lane>>4;
  int c0=wv*16;
  s8v wI[3][4], wH[3][4];
  #pragma unroll
  for (int g=0;g<3;g++)
    #pragma unroll
    for (int kk=0;kk<4;kk++){
      size_t off=((size_t)(g*128+c0+n))*128+kk*32+q*8;
      wI[g][kk]=*(const s8v*)(Wih+off);
      wH[g][kk]=*(const s8v*)(Whh+off);
    }
  int col=c0+n;
  float br =bih[col]+bhh[col];
  float bz =bih[128+col]+bhh[128+col];
  float bni=bih[256+col], bnh=bhh[256+col];

  int srow=wv*4+q;
  int schunk=n;
  long step=(long)gridDim.x*32;
  long r0=(long)blockIdx.x*32;
  int buf=0;
  {
    long rowg=r0+srow; if (rowg>=M) rowg=M-1;
    uint4 va=*(const uint4*)(A+rowg*128+schunk*8);
    uint4 vx=*(const uint4*)(X+rowg*128+schunk*8);
    *(uint4*)&sA[0][srow][schunk*8]=va;
    *(uint4*)&sX[0][srow][schunk*8]=vx;
  }
  __syncthreads();
  for (; r0<M; r0+=step){
    long rn=r0+step;
    uint4 va, vx; bool pre = rn<M;
    if (pre){
      long rowg=rn+srow; if (rowg>=M) rowg=M-1;
      va=*(const uint4*)(A+rowg*128+schunk*8);
      vx=*(const uint4*)(X+rowg*128+schunk*8);
    }
    f4v acc[6][2];
    #pragma unroll
    for (int g=0;g<6;g++)
      #pragma unroll
      for (int rt=0;rt<2;rt++) acc[g][rt]=(f4v){0.f,0.f,0.f,0.f};
    #pragma unroll
    for (int kk=0;kk<4;kk++){
      s8v aA[2], aX[2];
      #pragma unroll
      for (int rt=0;rt<2;rt++){
        aA[rt]=*(const s8v*)&sA[buf][rt*16+n][(kk*4+q)*8];
        aX[rt]=*(const s8v*)&sX[buf][rt*16+n][(kk*4+q)*8];
      }
      #pragma unroll
      for (int g=0;g<3;g++)
        #pragma unroll
        for (int rt=0;rt<2;rt++){
          acc[g  ][rt]=__builtin_amdgcn_mfma_f32_16x16x32_bf16(aA[rt],wI[g][kk],acc[g  ][rt],0,0,0);
          acc[3+g][rt]=__builtin_amdgcn_mfma_f32_16x16x32_bf16(aX[rt],wH[g][kk],acc[3+g][rt],0,0,0);
        }
    }
    float xv[2][4];
    #pragma unroll
    for (int rt=0;rt<2;rt++)
      #pragma unroll
      for (int rg=0;rg<4;rg++)
        xv[rt][rg]=b2f(sX[buf][rt*16+q*4+rg][col]);
    #pragma unroll
    for (int rt=0;rt<2;rt++){
      #pragma unroll
      for (int rg=0;rg<4;rg++){
        long row=r0+rt*16+q*4+rg;
        if (row<M){
          float rgate=sigmoid_f(acc[0][rt][rg]+acc[3][rt][rg]+br);
          float zgate=sigmoid_f(acc[1][rt][rg]+acc[4][rt][rg]+bz);
          float nn=tanh_f(acc[2][rt][rg]+bni + rgate*(acc[5][rt][rg]+bnh));
          float o=(1.f-zgate)*nn + zgate*xv[rt][rg];
          dest[row*128+col]=f2b(fmaxf(o,0.f));
        }
      }
    }
    if (pre){
      *(uint4*)&sA[buf^1][srow][schunk*8]=va;
      *(uint4*)&sX[buf^1][srow][schunk*8]=vx;
    }
    __syncthreads();
    buf^=1;
  }
}

// ------- scalar fused GRU (molecules, fp32 state) ----
__global__ __launch_bounds__(256) void gru_scalar_k(const float* __restrict__ A, const float* __restrict__ X,
                            const float* __restrict__ Wih, const float* __restrict__ Whh,
                            const float* __restrict__ bih, const float* __restrict__ bhh,
                            float* __restrict__ dest, int M){
  __shared__ unsigned sW[6][32*66];
  __shared__ float sA[8][132], sX[8][132];
  __shared__ float sbi[3][32], sbh[3][32];
  int c0 = blockIdx.y*32;
  for (int i=threadIdx.x; i<6*32*64; i+=256){
    int m=i>>11, r=i&2047, c=r>>6, k2=r&63;
    const float* base = (m<3)? Wih : Whh;
    int g = (m<3)? m : m-3;
    const float* wp = base + ((size_t)(g*128 + c0 + c))*128 + 2*k2;
    sW[m][c*66 + k2] = f2b_bits(wp[0]) | (f2b_bits(wp[1])<<16);
  }
  if (threadIdx.x < 96){
    int g=threadIdx.x>>5, c=threadIdx.x&31;
    sbi[g][c]=bih[g*128+c0+c]; sbh[g][c]=bhh[g*128+c0+c];
  }
  __syncthreads();
  int sub=threadIdx.x>>5, c=threadIdx.x&31;
  for (long r0=(long)blockIdx.x*8; r0<M; r0+=(long)gridDim.x*8){
    __syncthreads();
    for (int i=threadIdx.x;i<8*16;i+=256){
      int rr=i>>4, q=i&15; long row=r0+rr;
      if (row<M){
        *(float4*)&sA[rr][q*8]   = *(const float4*)(A+row*128+q*8);
        *(float4*)&sA[rr][q*8+4] = *(const float4*)(A+row*128+q*8+4);
        *(float4*)&sX[rr][q*8]   = *(const float4*)(X+row*128+q*8);
        *(float4*)&sX[rr][q*8+4] = *(const float4*)(X+row*128+q*8+4);
      } else {
        float4 z=make_float4(0,0,0,0);
        *(float4*)&sA[rr][q*8]=z; *(float4*)&sA[rr][q*8+4]=z;
        *(float4*)&sX[rr][q*8]=z; *(float4*)&sX[rr][q*8+4]=z;
      }
    }
    __syncthreads();
    long row=r0+sub;
    if (row<M){
      const unsigned* wri=&sW[0][c*66]; const unsigned* wzi=&sW[1][c*66]; const unsigned* wni=&sW[2][c*66];
      const unsigned* wrh=&sW[3][c*66]; const unsigned* wzh=&sW[4][c*66]; const unsigned* wnh=&sW[5][c*66];
      const float2* xa=(const float2*)sA[sub]; const float2* xb=(const float2*)sX[sub];
      float ari=0,azi=0,ani=0,arh=0,azh=0,anh=0;
      #pragma unroll 8
      for (int k2=0;k2<64;k2++){
        float2 av=xa[k2], bv=xb[k2];
        unsigned u;
        u=wri[k2]; ari += av.x*__uint_as_float(u<<16) + av.y*__uint_as_float(u&0xffff0000u);
        u=wzi[k2]; azi += av.x*__uint_as_float(u<<16) + av.y*__uint_as_float(u&0xffff0000u);
        u=wni[k2]; ani += av.x*__uint_as_float(u<<16) + av.y*__uint_as_float(u&0xffff0000u);
        u=wrh[k2]; arh += bv.x*__uint_as_float(u<<16) + bv.y*__uint_as_float(u&0xffff0000u);
        u=wzh[k2]; azh += bv.x*__uint_as_float(u<<16) + bv.y*__uint_as_float(u&0xffff0000u);
        u=wnh[k2]; anh += bv.x*__uint_as_float(u<<16) + bv.y*__uint_as_float(u&0xffff0000u);
      }
      float rg = sigmoid_f(ari+arh+sbi[0][c]+sbh[0][c]);
      float zg = sigmoid_f(azi+azh+sbi[1][c]+sbh[1][c]);
      float nn = tanh_f(ani+sbi[2][c] + rg*(anh+sbh[2][c]));
      float xv = sX[sub][c0+c];
      float o  = (1.f-zg)*nn + zg*xv;
      dest[row*128+c0+c] = fmaxf(o,0.f);
    }
  }
}

// ---------------- row dot(s) ----------------
template<typename TY>
__global__ void rowdot_k(const TY* __restrict__ Y, const float* __restrict__ v,
                         float* __restrict__ d, int M){
  __shared__ float sv[128];
  if (threadIdx.x<128) sv[threadIdx.x]=v[threadIdx.x];
  __syncthreads();
  int wv=threadIdx.x>>6, lane=threadIdx.x&63;
  long row=(long)blockIdx.x*4+wv;
  if (row>=M) return;
  float a=to_float(Y[row*128+lane])*sv[lane]+to_float(Y[row*128+64+lane])*sv[64+lane];
  #pragma unroll
  for (int o=32;o;o>>=1) a+=__shfl_xor(a,o);
  if (!lane) d[row]=a;
}

__global__ void rowdot2_k(const bf16* __restrict__ Y, const float* __restrict__ v1,
                          const float* __restrict__ v2, float* __restrict__ d1,
                          float* __restrict__ d2, int M){
  __shared__ float sv1[128], sv2[128];
  if (threadIdx.x<128){ sv1[threadIdx.x]=v1[threadIdx.x]; sv2[threadIdx.x]=v2[threadIdx.x]; }
  __syncthreads();
  int wv=threadIdx.x>>6, lane=threadIdx.x&63;
  long row=(long)blockIdx.x*4+wv;
  if (row>=M) return;
  float x0=b2f(Y[row*128+lane]), x1=b2f(Y[row*128+64+lane]);
  float a=x0*sv1[lane]+x1*sv1[64+lane];
  float b=x0*sv2[lane]+x1*sv2[64+lane];
  #pragma unroll
  for (int o=32;o;o>>=1){ a+=__shfl_xor(a,o); b+=__shfl_xor(b,o); }
  if (!lane){ d1[row]=a; d2[row]=b; }
}

// ---- GATE edge logits: 16 lanes/edge, W1b in registers, prefetch ----
__global__ __launch_bounds__(256) void gate_edge_logits_k(const bf16* __restrict__ u, const float* __restrict__ ea,
                                   const float* __restrict__ gW1, const float* __restrict__ att_l,
                                   const float* __restrict__ ddst, const int* __restrict__ src,
                                   const int* __restrict__ dst, const int* __restrict__ epos,
                                   float* __restrict__ elog, int E){
  int wv=threadIdx.x>>6, lane=threadIdx.x&63;
  int t=lane&15;
  // per-lane W1b[k][t*8+j] (fp32) and att_l slice, loaded once
  float w[10][8];
  #pragma unroll
  for (int k=0;k<10;k++)
    #pragma unroll
    for (int j=0;j<8;j++)
      w[k][j]=gW1[(size_t)(t*8+j)*138 + 128 + k];
  float al[8];
  #pragma unroll
  for (int j=0;j<8;j++) al[j]=att_l[t*8+j];

  long stride=(long)gridDim.x*16;
  long e=(long)blockIdx.x*16 + wv*4 + (lane>>4);
  if (e>=E) return;
  // first loads
  int sj=src[e];
  float eav=(t<10)? ea[(size_t)e*10+t]:0.f;
  uint4 uv=*(const uint4*)(u+(size_t)sj*128+t*8);
  while (true){
    long en=e+stride;
    bool has=en<E;
    int sjn=0; float eavn=0.f; uint4 uvn=make_uint4(0,0,0,0);
    if (has){
      sjn=src[en];
      eavn=(t<10)? ea[(size_t)en*10+t]:0.f;
      uvn=*(const uint4*)(u+(size_t)sjn*128+t*8);
    }
    // broadcast ea within the 16-lane group
    float eal[10];
    #pragma unroll
    for (int k=0;k<10;k++) eal[k]=__shfl(eav,(lane&48)+k);
    float uf[8]; unp8(uv,uf);
    float acc=0.f;
    #pragma unroll
    for (int j=0;j<8;j++){
      float v=uf[j];
      #pragma unroll
      for (int k=0;k<10;k++) v+=eal[k]*w[k][j];
      acc+=lrelu_f(v)*al[j];
    }
    #pragma unroll
    for (int o=8;o;o>>=1) acc+=__shfl_xor(acc,o);
    if (t==0) elog[epos[e]]=lrelu_f(acc+ddst[dst[e]]);
    if (!has) break;
    e=en; eav=eavn; uv=uvn;
  }
}

// ---------------- conv edge logits (writes CSR-permuted) ----------------
__global__ void conv_logit_k(const float* __restrict__ dsrc, const float* __restrict__ ddst,
                             const int* __restrict__ src, const int* __restrict__ dst,
                             const int* __restrict__ epos, float* __restrict__ elog, int n){
  int e=blockIdx.x*256+threadIdx.x;
  if (e<n) elog[epos[e]]=lrelu_f(dsrc[src[e]]+ddst[dst[e]]);
}

// ------- per-node softmax + weighted sum; 16 lanes per node, contiguous CSR --
template<int ACT>   // 0 none, 1 relu(S+bias)
__global__ void node_gather_k(const float* __restrict__ elog, const int* __restrict__ srcp,
                              const int* __restrict__ ptr, const bf16* __restrict__ V,
                              const float* __restrict__ bias, bf16* __restrict__ S, int M){
  int wv=threadIdx.x>>6, lane=threadIdx.x&63;
  int g=lane>>4, t=lane&15;
  int node=blockIdx.x*16 + wv*4 + g;
  if (node>=M) return;
  int p0=ptr[node], p1=ptr[node+1];
  float m=-INFINITY;
  for (int p=p0+t;p<p1;p+=16) m=fmaxf(m,elog[p]);
  #pragma unroll
  for (int o=8;o;o>>=1) m=fmaxf(m,__shfl_xor(m,o));
  float ssum=0.f;
  for (int p=p0+t;p<p1;p+=16) ssum+=__expf(elog[p]-m);
  #pragma unroll
  for (int o=8;o;o>>=1) ssum+=__shfl_xor(ssum,o);
  float inv=1.f/(ssum+1e-16f);
  float acc[8]={0,0,0,0,0,0,0,0};
  for (int p=p0;p<p1;p++){
    float al=__expf(elog[p]-m)*inv;
    uint4 v=*(const uint4*)(V+(size_t)srcp[p]*128+t*8);
    float xf[8]; unp8(v,xf);
    #pragma unroll
    for (int j=0;j<8;j++) acc[j]+=al*xf[j];
  }
  if (ACT==1){
    #pragma unroll
    for (int j=0;j<8;j++) acc[j]=fmaxf(acc[j]+bias[t*8+j],0.f);
  }
  uint4 o;
  o.x=f2b_bits(acc[0])|(f2b_bits(acc[1])<<16);
  o.y=f2b_bits(acc[2])|(f2b_bits(acc[3])<<16);
  o.z=f2b_bits(acc[4])|(f2b_bits(acc[5])<<16);
  o.w=f2b_bits(acc[6])|(f2b_bits(acc[7])<<16);
  *(uint4*)(S+(size_t)node*128+t*8)=o;
}

// ---------------- molecule kernels ----------------
__global__ void mol_ptr_k(const int* __restrict__ batch, int* __restrict__ mptr, int n, int Bn){
  int b=blockIdx.x*256+threadIdx.x; if (b>Bn) return;
  if (b==Bn){ mptr[Bn]=n; return; }
  int lo=0, hi=n;
  while (lo<hi){ int mid=(lo+hi)>>1; if (batch[mid]<b) lo=mid+1; else hi=mid; }
  mptr[b]=lo;
}

__global__ void mol_sum_k(const bf16* __restrict__ x, const int* __restrict__ mptr,
                          float* __restrict__ out, int Bn){
  int wv=threadIdx.x>>6, lane=threadIdx.x&63;
  int b=blockIdx.x*4+wv; if (b>=Bn) return;
  int p0=mptr[b], p1=mptr[b+1];
  float a0=0.f,a1=0.f;
  for (int i=p0;i<p1;i++){ a0+=b2f(x[(size_t)i*128+lane]); a1+=b2f(x[(size_t)i*128+64+lane]); }
  out[(size_t)b*128+lane]=fmaxf(a0,0.f); out[(size_t)b*128+64+lane]=fmaxf(a1,0.f);
}

__global__ void fold_att_k(const float* __restrict__ W, const float* __restrict__ att,
                           float* __restrict__ wdd){
  int k=threadIdx.x; float a=0.f;
  for (int c=0;c<128;c++) a+=att[c]*W[(size_t)c*128+k];
  wdd[k]=a;
}

__global__ void mol_logit_k(const float* __restrict__ dsrc, const float* __restrict__ dd,
                            const int* __restrict__ batch, float* __restrict__ alog, int n){
  int i=blockIdx.x*256+threadIdx.x; if (i<n) alog[i]=lrelu_f(dsrc[i]+dd[batch[i]]);
}

__global__ void mol_gather_k(const float* __restrict__ alog, const int* __restrict__ mptr,
                             const bf16* __restrict__ xs, const float* __restrict__ bias,
                             float* __restrict__ hb, int Bn){
  int wv=threadIdx.x>>6, lane=threadIdx.x&63;
  int b=blockIdx.x*4+wv; if (b>=Bn) return;
  int p0=mptr[b], p1=mptr[b+1];
  float m=-INFINITY;
  for (int i=p0+lane;i<p1;i+=64) m=fmaxf(m,alog[i]);
  #pragma unroll
  for (int o=32;o;o>>=1) m=fmaxf(m,__shfl_xor(m,o));
  float ssum=0.f;
  for (int i=p0+lane;i<p1;i+=64) ssum+=__expf(alog[i]-m);
  #pragma unroll
  for (int o=32;o;o>>=1) ssum+=__shfl_xor(ssum,o);
  float inv=1.f/(ssum+1e-16f);
  float a0=0.f,a1=0.f;
  for (int i=p0;i<p1;i++){
    float al=__expf(alog[i]-m)*inv;
    a0+=al*b2f(xs[(size_t)i*128+lane]); a1+=al*b2f(xs[(size_t)i*128+64+lane]);
  }
  hb[(size_t)b*128+lane]=elu_f(a0+bias[lane]);
  hb[(size_t)b*128+64+lane]=elu_f(a1+bias[64+lane]);
}

// ---------------- final head ----------------
__global__ void final_head_k(const float* __restrict__ out, const float* __restrict__ W2,
                             const float* __restrict__ b2, const float* __restrict__ Wh,
                             const float* __restrict__ bh, float* __restrict__ y, int Bn){
  __shared__ float srow[128]; __shared__ float sred[128];
  int b=blockIdx.x, c=threadIdx.x;
  srow[c]=out[(size_t)b*128+c]; __syncthreads();
  float acc=b2[c];
  const float* wr=&W2[(size_t)c*128];
  #pragma unroll 8
  for (int k=0;k<128;k++) acc+=srow[k]*wr[k];
  sred[c]=acc*Wh[c]; __syncthreads();
  for (int o=64;o;o>>=1){ if (c<o) sred[c]+=sred[c+o]; __syncthreads(); }
  if (c==0) y[b]=sred[0]+bh[0];
}

// ---------------- CSR build ----------------
__global__ void zero_i32_k(int* p, int n){ int i=blockIdx.x*256+threadIdx.x; if (i<n) p[i]=0; }
__global__ void hist_k(const int* __restrict__ dst, int* __restrict__ deg, int n){
  int e=blockIdx.x*256+threadIdx.x; if (e<n) atomicAdd(&deg[dst[e]],1);
}
__global__ void scan1_k(const int* __restrict__ deg, int* __restrict__ ptr,
                        int* __restrict__ part, int n){
  __shared__ int sd[256];
  int base=blockIdx.x*1024, tid=threadIdx.x;
  int v[4]; int ssum=0;
  #pragma unroll
  for (int j=0;j<4;j++){ int idx=base+tid*4+j; v[j]= idx<n? deg[idx]:0; ssum+=v[j]; }
  sd[tid]=ssum; __syncthreads();
  for (int o=1;o<256;o<<=1){ int t = tid>=o? sd[tid-o]:0; __syncthreads(); sd[tid]+=t; __syncthreads(); }
  int excl=sd[tid]-ssum;
  #pragma unroll
  for (int j=0;j<4;j++){ int idx=base+tid*4+j; if (idx<n) ptr[idx]=excl; excl+=v[j]; }
  if (tid==255) part[blockIdx.x]=sd[255];
}
__global__ void scan2_k(int* part, int nb){
  __shared__ int sd[512];
  int tid=threadIdx.x;
  int v= tid<nb? part[tid]:0; sd[tid]=v; __syncthreads();
  for (int o=1;o<512;o<<=1){ int t = tid>=o? sd[tid-o]:0; __syncthreads(); sd[tid]+=t; __syncthreads(); }
  if (tid<nb) part[tid]=sd[tid]-v;
}
__global__ void scan3_k(int* __restrict__ ptr, const int* __restrict__ part,
                        int* __restrict__ wofs, int n, int total){
  int i=blockIdx.x*256+threadIdx.x;
  if (i<n){ int val=ptr[i]+part[i>>10]; ptr[i]=val; wofs[i]=val; }
  if (i==0) ptr[n]=total;
}
__global__ void fill_csr_k(const int* __restrict__ dst, const int* __restrict__ src,
                           int* __restrict__ wofs, int* __restrict__ srcp,
                           int* __restrict__ epos, int n){
  int e=blockIdx.x*256+threadIdx.x;
  if (e<n){ int p=atomicAdd(&wofs[dst[e]],1); srcp[p]=src[e]; epos[e]=p; }
}

// =====================================================================
extern "C" void kernel_launch(void* const* d_in, const int* in_sizes, int n_in,
                              void* d_out, int out_size, void* d_ws, size_t ws_size,
                              hipStream_t stream){
  (void)in_sizes; (void)n_in; (void)out_size; (void)ws_size;
  const float* x0        =(const float*)d_in[0];
  const float* edge_attr =(const float*)d_in[1];
  const float* W_lin1    =(const float*)d_in[2];
  const float* b_lin1    =(const float*)d_in[3];
  const float* gate_W1   =(const float*)d_in[4];
  const float* gate_W2   =(const float*)d_in[5];
  const float* gate_att_l=(const float*)d_in[6];
  const float* gate_att_r=(const float*)d_in[7];
  const float* gate_bias =(const float*)d_in[8];
  const float* g1_Wih=(const float*)d_in[9];  const float* g1_Whh=(const float*)d_in[10];
  const float* g1_bih=(const float*)d_in[11]; const float* g1_bhh=(const float*)d_in[12];
  const float* conv_W=(const float*)d_in[13];
  const float* conv_att_src=(const float*)d_in[14];
  const float* conv_att_dst=(const float*)d_in[15];
  const float* conv_bias   =(const float*)d_in[16];
  const float* g2_Wih=(const float*)d_in[17]; const float* g2_Whh=(const float*)d_in[18];
  const float* g2_bih=(const float*)d_in[19]; const float* g2_bhh=(const float*)d_in[20];
  const float* mol_W=(const float*)d_in[21];
  const float* mol_att_src=(const float*)d_in[22];
  const float* mol_att_dst=(const float*)d_in[23];
  const float* mol_bias   =(const float*)d_in[24];
  const float* gm_Wih=(const float*)d_in[25]; const float* gm_Whh=(const float*)d_in[26];
  const float* gm_bih=(const float*)d_in[27]; const float* gm_bhh=(const float*)d_in[28];
  const float* W_lin2=(const float*)d_in[29]; const float* b_lin2=(const float*)d_in[30];
  const float* W_head=(const float*)d_in[31]; const float* b_head=(const float*)d_in[32];
  const int* ei   =(const int*)d_in[33];
  const int* batch=(const int*)d_in[34];
  const int* src=ei; const int* dst=ei+E_;
  float* y=(float*)d_out;

  // ---- workspace layout (~222 MiB total) ----
  const size_t NH=(size_t)N_*H_, BH=(size_t)B_*H_;
  bf16* b0  =(bf16*)d_ws;           // N*H bf16
  bf16* b1  =b0+NH;                 // N*H bf16
  bf16* b2v =b1+NH;                 // N*H bf16
  float* outA=(float*)(b2v+NH);     // B*H fp32
  float* outB=outA+BH;
  float* hb  =outB+BH;
  float* elog=hb+BH;                // E
  float* dsrc=elog+E_;              // N
  float* ddst=dsrc+N_;              // N
  float* alog=ddst+N_;              // N
  float* wdd =alog+N_;              // 128
  float* dd  =wdd+128;              // B
  int* deg =(int*)(dd+B_);          // N
  int* ptr =deg+N_;                 // N+1
  int* wofs=ptr+N_+1;               // N
  int* part=wofs+N_;                // 512
  int* mptr=part+512;               // B+1
  int* srcp=mptr+B_+1;              // E
  int* epos=srcp+E_;                // E
  uintptr_t wbase=((uintptr_t)(epos+E_)+255)&~(uintptr_t)255;
  bf16* wb_gw1 =(bf16*)wbase;        // 128*128
  bf16* wb_gw2 =wb_gw1 +128*128;
  bf16* wb_conv=wb_gw2 +128*128;
  bf16* wb_mol =wb_conv+128*128;
  bf16* wb_g1i =wb_mol +128*128;     // 384*128
  bf16* wb_g1h =wb_g1i +384*128;
  bf16* wb_g2i =wb_g1h +384*128;
  bf16* wb_g2h =wb_g2i +384*128;
  bf16* wb_l1  =wb_g2h +384*128;     // 128*64 (lin1, K padded 39->64)

  // ---- weight conversions (one dispatch, 9 segments) ----
  W2B9 wp;
  wp.seg[0]={gate_W1,wb_gw1,128,138,128,128};
  wp.seg[1]={gate_W2,wb_gw2,128,128,128,128};
  wp.seg[2]={conv_W ,wb_conv,128,128,128,128};
  wp.seg[3]={mol_W  ,wb_mol ,128,128,128,128};
  wp.seg[4]={g1_Wih,wb_g1i,384,128,128,128};
  wp.seg[5]={g1_Whh,wb_g1h,384,128,128,128};
  wp.seg[6]={g2_Wih,wb_g2i,384,128,128,128};
  wp.seg[7]={g2_Whh,wb_g2h,384,128,128,128};
  wp.seg[8]={W_lin1,wb_l1 ,128, 39, 64, 39};
  w2ball_k<<<dim3(192,9),256,0,stream>>>(wp);

  // ---- CSR by dst (+ permutation arrays) + molecule ranges ----
  zero_i32_k<<<(N_+255)/256,256,0,stream>>>(deg,N_);
  hist_k<<<(E_+255)/256,256,0,stream>>>(dst,deg,E_);
  int nb=(N_+1023)/1024;
  scan1_k<<<nb,256,0,stream>>>(deg,ptr,part,N_);
  scan2_k<<<1,512,0,stream>>>(part,nb);
  scan3_k<<<(N_+255)/256,256,0,stream>>>(ptr,part,wofs,N_,E_);
  fill_csr_k<<<(E_+255)/256,256,0,stream>>>(dst,src,wofs,srcp,epos,E_);
  mol_ptr_k<<<(B_+1+255)/256,256,0,stream>>>(batch,mptr,N_,B_);

  // ---- lin1: X -> b0 (MFMA) ----
  lin1_mfma_k<<<1024,256,0,stream>>>(x0,wb_l1,b_lin1,b0,N_);

  const int GL=768, GG=1024, GN=(N_+15)/16;
  // ---- GATEConv ----
  lin_mfma_k<0><<<GL,256,0,stream>>>(b0,wb_gw1,nullptr,b1,N_);             // u -> b1
  rowdot_k<bf16><<<(N_+3)/4,256,0,stream>>>(b0,gate_att_r,ddst,N_);
  gate_edge_logits_k<<<4096,256,0,stream>>>(b1,edge_attr,gate_W1,gate_att_l,ddst,src,dst,epos,elog,E_);
  node_gather_k<0><<<GN,256,0,stream>>>(elog,srcp,ptr,b0,nullptr,b2v,N_);  // S -> b2
  lin_mfma_k<2><<<GL,256,0,stream>>>(b2v,wb_gw2,gate_bias,b1,N_);          // h=elu -> b1
  // ---- GRU1: x=relu(gru(h=b1, x=b0)) -> b2 ----
  gru_mfma_k<<<GG,512,0,stream>>>(b1,b0,wb_g1i,wb_g1h,g1_bih,g1_bhh,b2v,N_);
  // ---- atom GATConv (x lives in b2) ----
  lin_mfma_k<0><<<GL,256,0,stream>>>(b2v,wb_conv,nullptr,b0,N_);           // xl -> b0
  rowdot2_k<<<(N_+3)/4,256,0,stream>>>(b0,conv_att_src,conv_att_dst,dsrc,ddst,N_);
  conv_logit_k<<<(E_+255)/256,256,0,stream>>>(dsrc,ddst,src,dst,epos,elog,E_);
  node_gather_k<1><<<GN,256,0,stream>>>(elog,srcp,ptr,b0,conv_bias,b1,N_); // h=relu(S+bias) -> b1
  // ---- GRU2: x=relu(gru(h=b1, x=b2)) -> b0 ----
  gru_mfma_k<<<GG,512,0,stream>>>(b1,b2v,wb_g2i,wb_g2h,g2_bih,g2_bhh,b0,N_);
  // ---- readout (x lives in b0) ----
  mol_sum_k<<<(B_+3)/4,256,0,stream>>>(b0,mptr,outA,B_);
  lin_mfma_k<0><<<GL,256,0,stream>>>(b0,wb_mol,nullptr,b1,N_);             // xs -> b1
  rowdot_k<bf16><<<(N_+3)/4,256,0,stream>>>(b1,mol_att_src,dsrc,N_);
  fold_att_k<<<1,128,0,stream>>>(mol_W,mol_att_dst,wdd);
  float* out_cur=outA; float* out_nxt=outB;
  dim3 gm(157,4);
  for (int ts=0; ts<2; ts++){
    rowdot_k<float><<<(B_+3)/4,256,0,stream>>>(out_cur,wdd,dd,B_);
    mol_logit_k<<<(N_+255)/256,256,0,stream>>>(dsrc,dd,batch,alog,N_);
    mol_gather_k<<<(B_+3)/4,256,0,stream>>>(alog,mptr,b1,mol_bias,hb,B_);
    gru_scalar_k<<<gm,256,0,stream>>>(hb,out_cur,gm_Wih,gm_Whh,gm_bih,gm_bhh,out_nxt,B_);
    float* tmp=out_cur; out_cur=out_nxt; out_nxt=tmp;
  }
  final_head_k<<<B_,128,0,stream>>>(out_cur,W_lin2,b_lin2,W_head,b_head,y,B_);
}